// Round 1
// baseline (4381.181 us; speedup 1.0000x reference)
//
#include <hip/hip_runtime.h>
#include <math.h>

// Problem constants
constexpr int Bn = 8, Tn = 32;
constexpr int D_INNER = 512;

// ---------------------------------------------------------------------------
// Fused Conv3D (3x3x3, stride (1,2,2), pad 1) + bias + BN affine + ReLU +
// MaxPool(1,2,2). Each thread computes one POOLED output: 4 conv outputs
// (2x2) from a 5x5 register patch per (kt, ci) plane, then maxes.
// Layouts: in (B,T,Cin,Hin,Win), out (B,T,Cout,Hp,Wp), w (Cout,Cin,3,3,3).
// Note Hin == 4*Hp at every stage, so only y<0 / x<0 need zero-pad.
// ---------------------------------------------------------------------------
__global__ void conv3d_fused(const float* __restrict__ in, const float* __restrict__ w,
                             const float* __restrict__ bias, const float* __restrict__ gam,
                             const float* __restrict__ bet, float* __restrict__ out,
                             int Cin, int Cout, int Hin, int Win, int Hp, int Wp, int total)
{
    int idx = blockIdx.x * blockDim.x + threadIdx.x;
    if (idx >= total) return;
    int px = idx % Wp; int r = idx / Wp;
    int py = r % Hp;   r /= Hp;
    int co = r % Cout; r /= Cout;
    int t  = r % Tn;   int b = r / Tn;

    float a00 = 0.f, a01 = 0.f, a10 = 0.f, a11 = 0.f;

    for (int kt = 0; kt < 3; ++kt) {
        int ts = t + kt - 1;
        if (ts < 0 || ts >= Tn) continue;
        for (int ci = 0; ci < Cin; ++ci) {
            const float* plane = in + ((size_t)(b * Tn + ts) * Cin + ci) * (size_t)(Hin * Win);
            const float* wp    = w  + ((size_t)(co * Cin + ci) * 3 + kt) * 9;
            float p[5][5];
            #pragma unroll
            for (int iy = 0; iy < 5; ++iy) {
                int y = 4 * py - 1 + iy;
                #pragma unroll
                for (int ix = 0; ix < 5; ++ix) {
                    int x = 4 * px - 1 + ix;
                    p[iy][ix] = (y >= 0 && x >= 0) ? plane[y * Win + x] : 0.f;
                }
            }
            #pragma unroll
            for (int ky = 0; ky < 3; ++ky) {
                #pragma unroll
                for (int kx = 0; kx < 3; ++kx) {
                    float wv = wp[ky * 3 + kx];
                    a00 = fmaf(wv, p[ky][kx],         a00);
                    a01 = fmaf(wv, p[ky][kx + 2],     a01);
                    a10 = fmaf(wv, p[ky + 2][kx],     a10);
                    a11 = fmaf(wv, p[ky + 2][kx + 2], a11);
                }
            }
        }
    }
    float bi = bias[co], g = gam[co], be = bet[co];
    a00 = fmaxf(fmaf(g, a00 + bi, be), 0.f);
    a01 = fmaxf(fmaf(g, a01 + bi, be), 0.f);
    a10 = fmaxf(fmaf(g, a10 + bi, be), 0.f);
    a11 = fmaxf(fmaf(g, a11 + bi, be), 0.f);
    out[idx] = fmaxf(fmaxf(a00, a01), fmaxf(a10, a11));
}

// ---------------------------------------------------------------------------
// Fused: GAP(2x2) -> ep projection, bbox MLP (4->64 relu ->256), u = ff + bf.
// One block per token (b,t), 256 threads (one per d_model channel).
// ---------------------------------------------------------------------------
__global__ void fuse_u_kernel(const float* __restrict__ buf2, const float* __restrict__ ep_w,
                              const float* __restrict__ ep_b, const float* __restrict__ bb,
                              const float* __restrict__ bp1_w, const float* __restrict__ bp1_b,
                              const float* __restrict__ bp2_w, const float* __restrict__ bp2_b,
                              float* __restrict__ u)
{
    int bt = blockIdx.x;       // 0..255 (b*T+t)
    int m  = threadIdx.x;      // 0..255
    __shared__ float hs[64];
    __shared__ float gap[96];
    if (m < 64) {
        float a = bp1_b[m];
        #pragma unroll
        for (int k = 0; k < 4; ++k) a = fmaf(bp1_w[m * 4 + k], bb[bt * 4 + k], a);
        hs[m] = fmaxf(a, 0.f);
    } else if (m < 160) {
        int c = m - 64;
        const float* p = buf2 + ((size_t)bt * 96 + c) * 4;
        gap[c] = 0.25f * (p[0] + p[1] + p[2] + p[3]);
    }
    __syncthreads();
    float ff = ep_b[m];
    for (int c = 0; c < 96; ++c) ff = fmaf(gap[c], ep_w[m * 96 + c], ff);
    float bfv = bp2_b[m];
    for (int j = 0; j < 64; ++j) bfv = fmaf(hs[j], bp2_w[m * 64 + j], bfv);
    u[(size_t)bt * 256 + m] = ff + bfv;
}

// ---------------------------------------------------------------------------
// Generic row-major linear: out[m,o] = act(in[m,:K] . w[o,:K] + bias[o]).
// ldin = row stride of in. act: 0 none, 1 relu, 2 sigmoid, 3 softplus.
// K is always a multiple of 4 and all rows 16B-aligned -> float4 loads.
// ---------------------------------------------------------------------------
__global__ void linear_kernel(const float* __restrict__ in, const float* __restrict__ w,
                              const float* __restrict__ bias, float* __restrict__ out,
                              int K, int N, int ldin, int act, int total)
{
    int idx = blockIdx.x * blockDim.x + threadIdx.x;
    if (idx >= total) return;
    int o = idx % N; int m = idx / N;
    const float4* ip = (const float4*)(in + (size_t)m * ldin);
    const float4* wp = (const float4*)(w + (size_t)o * K);
    float acc = 0.f;
    int K4 = K >> 2;
    for (int k = 0; k < K4; ++k) {
        float4 a = ip[k], b = wp[k];
        acc = fmaf(a.x, b.x, acc);
        acc = fmaf(a.y, b.y, acc);
        acc = fmaf(a.z, b.z, acc);
        acc = fmaf(a.w, b.w, acc);
    }
    if (bias) acc += bias[o];
    if (act == 1)      acc = fmaxf(acc, 0.f);
    else if (act == 2) acc = 1.f / (1.f + expf(-acc));
    else if (act == 3) acc = (acc > 20.f) ? acc : log1pf(expf(acc));
    out[idx] = acc;
}

// ---------------------------------------------------------------------------
// Causal depthwise conv1d (k=4, pad 3) over time + SiLU.
// xm = xz[...,0:512]. out xs (B,T,512).
// ---------------------------------------------------------------------------
__global__ void conv1d_silu_kernel(const float* __restrict__ xz, const float* __restrict__ cw,
                                   const float* __restrict__ cb, float* __restrict__ xs)
{
    int idx = blockIdx.x * blockDim.x + threadIdx.x;
    if (idx >= Bn * Tn * D_INNER) return;
    int d = idx % D_INNER; int r = idx / D_INNER;
    int t = r % Tn; int b = r / Tn;
    float acc = cb[d];
    #pragma unroll
    for (int k = 0; k < 4; ++k) {
        int ts = t - 3 + k;
        if (ts >= 0) acc = fmaf(cw[d * 4 + k], xz[(size_t)(b * Tn + ts) * 1024 + d], acc);
    }
    xs[idx] = acc / (1.f + expf(-acc));   // silu
}

// ---------------------------------------------------------------------------
// Selective-scan (Mamba SSM) + skip + silu(z) gate. One thread per (b,d).
// ---------------------------------------------------------------------------
__global__ void ssm_kernel(const float* __restrict__ xdbl, const float* __restrict__ dtb,
                           const float* __restrict__ xs, const float* __restrict__ xz,
                           const float* __restrict__ A_log, const float* __restrict__ Dp,
                           float* __restrict__ y)
{
    int idx = blockIdx.x * blockDim.x + threadIdx.x;
    if (idx >= Bn * D_INNER) return;
    int d = idx % D_INNER; int b = idx / D_INNER;
    float A[16], h[16];
    #pragma unroll
    for (int s = 0; s < 16; ++s) { A[s] = -expf(A_log[d * 16 + s]); h[s] = 0.f; }
    float Dv = Dp[d];
    for (int t = 0; t < Tn; ++t) {
        int bt = b * Tn + t;
        float dtv = dtb[(size_t)bt * 512 + d];
        float xv  = xs [(size_t)bt * 512 + d];
        const float* xrow = xdbl + (size_t)bt * 48;
        float acc = 0.f;
        #pragma unroll
        for (int s = 0; s < 16; ++s) {
            float dA = expf(dtv * A[s]);
            h[s] = fmaf(dA, h[s], dtv * xrow[16 + s] * xv);
            acc  = fmaf(h[s], xrow[32 + s], acc);
        }
        float zv  = xz[(size_t)bt * 1024 + 512 + d];
        float sig = 1.f / (1.f + expf(-zv));
        y[(size_t)bt * 512 + d] = (acc + Dv * xv) * (zv * sig);
    }
}

// ---------------------------------------------------------------------------
// Kalman filter scan, one thread per batch. S is SPD -> Gauss-Jordan no pivot.
// ---------------------------------------------------------------------------
__global__ void kf_kernel(const float* __restrict__ meas, const float* __restrict__ bb,
                          const float* __restrict__ Fin, const float* __restrict__ Hmin,
                          const float* __restrict__ lq, const float* __restrict__ lr,
                          float* __restrict__ pred)
{
    int b = blockIdx.x * blockDim.x + threadIdx.x;
    if (b >= Bn) return;
    float F[4][4], Hm[4][4], Qd[4], Rd[4];
    #pragma unroll
    for (int i = 0; i < 4; ++i) {
        Qd[i] = expf(lq[i]) + 1e-6f;
        Rd[i] = expf(lr[i]) + 1e-6f;
        #pragma unroll
        for (int j = 0; j < 4; ++j) { F[i][j] = Fin[i * 4 + j]; Hm[i][j] = Hmin[i * 4 + j]; }
    }
    float s[4], P[4][4];
    #pragma unroll
    for (int i = 0; i < 4; ++i) {
        s[i] = bb[(b * Tn) * 4 + i];
        #pragma unroll
        for (int j = 0; j < 4; ++j) P[i][j] = (i == j) ? 0.01f : 0.f;
    }
    for (int t = 0; t < Tn; ++t) {
        float mv[4];
        #pragma unroll
        for (int i = 0; i < 4; ++i) mv[i] = meas[(b * Tn + t) * 4 + i];
        float sp[4];
        #pragma unroll
        for (int i = 0; i < 4; ++i) { float a = 0.f;
            #pragma unroll
            for (int j = 0; j < 4; ++j) a = fmaf(F[i][j], s[j], a); sp[i] = a; }
        float FP[4][4];
        #pragma unroll
        for (int i = 0; i < 4; ++i)
            #pragma unroll
            for (int j = 0; j < 4; ++j) { float a = 0.f;
                for (int k = 0; k < 4; ++k) a = fmaf(F[i][k], P[k][j], a); FP[i][j] = a; }
        float Pp[4][4];
        #pragma unroll
        for (int i = 0; i < 4; ++i)
            #pragma unroll
            for (int j = 0; j < 4; ++j) { float a = 0.f;
                for (int k = 0; k < 4; ++k) a = fmaf(FP[i][k], F[j][k], a);
                Pp[i][j] = a + ((i == j) ? Qd[i] : 0.f); }
        float yr[4];
        #pragma unroll
        for (int i = 0; i < 4; ++i) { float a = 0.f;
            for (int j = 0; j < 4; ++j) a = fmaf(Hm[i][j], sp[j], a); yr[i] = mv[i] - a; }
        float HP[4][4];
        #pragma unroll
        for (int i = 0; i < 4; ++i)
            #pragma unroll
            for (int j = 0; j < 4; ++j) { float a = 0.f;
                for (int k = 0; k < 4; ++k) a = fmaf(Hm[i][k], Pp[k][j], a); HP[i][j] = a; }
        float S[4][8];  // augmented [S | H]
        #pragma unroll
        for (int i = 0; i < 4; ++i)
            #pragma unroll
            for (int j = 0; j < 4; ++j) { float a = 0.f;
                for (int k = 0; k < 4; ++k) a = fmaf(HP[i][k], Hm[j][k], a);
                S[i][j] = a + ((i == j) ? Rd[i] : 0.f);
                S[i][4 + j] = Hm[i][j]; }
        #pragma unroll
        for (int c = 0; c < 4; ++c) {
            float dinv = 1.f / S[c][c];
            #pragma unroll
            for (int j = 0; j < 8; ++j) S[c][j] *= dinv;
            #pragma unroll
            for (int r2 = 0; r2 < 4; ++r2) {
                if (r2 == c) continue;
                float f = S[r2][c];
                #pragma unroll
                for (int j = 0; j < 8; ++j) S[r2][j] = fmaf(-f, S[c][j], S[r2][j]);
            }
        }
        float K[4][4];   // K[i][k] = sum_j Pp[i][j] * X[k][j],  X = S^{-1}H
        #pragma unroll
        for (int i = 0; i < 4; ++i)
            #pragma unroll
            for (int k = 0; k < 4; ++k) { float a = 0.f;
                for (int j = 0; j < 4; ++j) a = fmaf(Pp[i][j], S[k][4 + j], a); K[i][k] = a; }
        float sn[4];
        #pragma unroll
        for (int i = 0; i < 4; ++i) { float a = sp[i];
            for (int j = 0; j < 4; ++j) a = fmaf(K[i][j], yr[j], a); sn[i] = a; }
        float IKH[4][4];
        #pragma unroll
        for (int i = 0; i < 4; ++i)
            #pragma unroll
            for (int j = 0; j < 4; ++j) { float a = (i == j) ? 1.f : 0.f;
                for (int k = 0; k < 4; ++k) a = fmaf(-K[i][k], Hm[k][j], a); IKH[i][j] = a; }
        float T1[4][4];
        #pragma unroll
        for (int i = 0; i < 4; ++i)
            #pragma unroll
            for (int j = 0; j < 4; ++j) { float a = 0.f;
                for (int k = 0; k < 4; ++k) a = fmaf(IKH[i][k], Pp[k][j], a); T1[i][j] = a; }
        #pragma unroll
        for (int i = 0; i < 4; ++i)
            #pragma unroll
            for (int j = 0; j < 4; ++j) { float a = 0.f;
                for (int k = 0; k < 4; ++k) a = fmaf(T1[i][k], IKH[j][k], a);
                for (int k = 0; k < 4; ++k) a = fmaf(K[i][k] * Rd[k], K[j][k], a);
                P[i][j] = a; }
        #pragma unroll
        for (int i = 0; i < 4; ++i) { s[i] = sn[i]; pred[(b * Tn + t) * 4 + i] = sn[i]; }
    }
}

// ---------------------------------------------------------------------------
extern "C" void kernel_launch(void* const* d_in, const int* in_sizes, int n_in,
                              void* d_out, int out_size, void* d_ws, size_t ws_size,
                              hipStream_t stream)
{
    const float* frames = (const float*)d_in[0];
    const float* bb     = (const float*)d_in[1];
    const float* cw0 = (const float*)d_in[2],  *cb0 = (const float*)d_in[3];
    const float* g0  = (const float*)d_in[4],  *be0 = (const float*)d_in[5];
    const float* cw1 = (const float*)d_in[6],  *cb1 = (const float*)d_in[7];
    const float* g1  = (const float*)d_in[8],  *be1 = (const float*)d_in[9];
    const float* cw2 = (const float*)d_in[10], *cb2 = (const float*)d_in[11];
    const float* g2  = (const float*)d_in[12], *be2 = (const float*)d_in[13];
    const float* ep_w  = (const float*)d_in[14], *ep_b  = (const float*)d_in[15];
    const float* bp1_w = (const float*)d_in[16], *bp1_b = (const float*)d_in[17];
    const float* bp2_w = (const float*)d_in[18], *bp2_b = (const float*)d_in[19];
    const float* in_proj_w = (const float*)d_in[20];
    const float* c1w = (const float*)d_in[21], *c1b = (const float*)d_in[22];
    const float* x_proj_w = (const float*)d_in[23];
    const float* dt_w = (const float*)d_in[24], *dt_b = (const float*)d_in[25];
    const float* A_log = (const float*)d_in[26], *Dp = (const float*)d_in[27];
    const float* out_proj_w = (const float*)d_in[28];
    const float* h1_w = (const float*)d_in[29], *h1_b = (const float*)d_in[30];
    const float* h2_w = (const float*)d_in[31], *h2_b = (const float*)d_in[32];
    const float* kfF = (const float*)d_in[33], *kfH = (const float*)d_in[34];
    const float* kfq = (const float*)d_in[35], *kfr = (const float*)d_in[36];

    // workspace layout (floats)
    float* ws   = (float*)d_ws;
    float* buf0 = ws;                                   // (8,32,32,32,32) = 8388608
    float* buf1 = buf0 + (size_t)8 * 32 * 32 * 32 * 32; // (8,32,64,8,8)   = 1048576
    float* buf2 = buf1 + (size_t)8 * 32 * 64 * 8 * 8;   // (8,32,96,2,2)   = 98304
    float* ub   = buf2 + (size_t)8 * 32 * 96 * 2 * 2;   // (256,256)
    float* xzb  = ub   + 256 * 256;                     // (256,1024)
    float* xsb  = xzb  + 256 * 1024;                    // (256,512)
    float* xdb  = xsb  + 256 * 512;                     // (256,48)
    float* dtbf = xdb  + 256 * 48;                      // (256,512)
    float* yb   = dtbf + 256 * 512;                     // (256,512)
    float* mob  = yb   + 256 * 512;                     // (256,256)
    float* hidb = mob  + 256 * 256;                     // (256,128)

    float* kf_out  = (float*)d_out;        // (8,32,4)
    float* meas_out = kf_out + Bn * Tn * 4; // (8,32,4)

    auto nblk = [](int n) { return dim3((unsigned)((n + 255) / 256)); };

    // CNN backbone (3 fused conv+bn+relu+pool stages)
    { int tot = 8 * 32 * 32 * 32 * 32;
      conv3d_fused<<<nblk(tot), 256, 0, stream>>>(frames, cw0, cb0, g0, be0, buf0,
                                                  3, 32, 128, 128, 32, 32, tot); }
    { int tot = 8 * 32 * 64 * 8 * 8;
      conv3d_fused<<<nblk(tot), 256, 0, stream>>>(buf0, cw1, cb1, g1, be1, buf1,
                                                  32, 64, 32, 32, 8, 8, tot); }
    { int tot = 8 * 32 * 96 * 2 * 2;
      conv3d_fused<<<nblk(tot), 256, 0, stream>>>(buf1, cw2, cb2, g2, be2, buf2,
                                                  64, 96, 8, 8, 2, 2, tot); }

    // GAP + embed proj + bbox MLP -> u
    fuse_u_kernel<<<256, 256, 0, stream>>>(buf2, ep_w, ep_b, bb, bp1_w, bp1_b, bp2_w, bp2_b, ub);

    // Mamba block
    linear_kernel<<<nblk(256 * 1024), 256, 0, stream>>>(ub, in_proj_w, nullptr, xzb,
                                                        256, 1024, 256, 0, 256 * 1024);
    conv1d_silu_kernel<<<nblk(256 * 512), 256, 0, stream>>>(xzb, c1w, c1b, xsb);
    linear_kernel<<<nblk(256 * 48), 256, 0, stream>>>(xsb, x_proj_w, nullptr, xdb,
                                                      512, 48, 512, 0, 256 * 48);
    linear_kernel<<<nblk(256 * 512), 256, 0, stream>>>(xdb, dt_w, dt_b, dtbf,
                                                       16, 512, 48, 3, 256 * 512);
    ssm_kernel<<<nblk(8 * 512), 256, 0, stream>>>(xdb, dtbf, xsb, xzb, A_log, Dp, yb);
    linear_kernel<<<nblk(256 * 256), 256, 0, stream>>>(yb, out_proj_w, nullptr, mob,
                                                       512, 256, 512, 0, 256 * 256);

    // Measurement head -> meas (second output)
    linear_kernel<<<nblk(256 * 128), 256, 0, stream>>>(mob, h1_w, h1_b, hidb,
                                                       256, 128, 256, 1, 256 * 128);
    linear_kernel<<<nblk(256 * 4), 256, 0, stream>>>(hidb, h2_w, h2_b, meas_out,
                                                     128, 4, 128, 2, 256 * 4);

    // Kalman filter -> kf_pred (first output)
    kf_kernel<<<1, 64, 0, stream>>>(meas_out, bb, kfF, kfH, kfq, kfr, kf_out);
}

// Round 2
// 1182.567 us; speedup vs baseline: 3.7048x; 3.7048x over previous
//
#include <hip/hip_runtime.h>
#include <math.h>

// Problem constants
constexpr int Bn = 8, Tn = 32;
constexpr int D_INNER = 512;

// ---------------------------------------------------------------------------
// Stage 0: Conv3D 3ci->32co, in 128x128, stride(1,2,2), pad 1 + BN + ReLU +
// maxpool(2,2) -> out (B,T,32,32,32). LDS-staged.
// Block: 256 threads = 32 px * 8 lpy; grid = (B*T) * 4 row-tiles.
// LDS: 3 ci planes of 33 rows x 132 cols (col c <-> gx = c-1).
// Per thread: 2 co-groups of 16; acc[16][4]; patch from LDS; weights s_load.
// ---------------------------------------------------------------------------
constexpr int S0_ROWS = 33, S0_STR = 132, S0_PLANE = S0_ROWS * S0_STR;

__global__ __launch_bounds__(256) void conv0_kernel(
    const float* __restrict__ in, const float* __restrict__ w,
    const float* __restrict__ bias, const float* __restrict__ gam,
    const float* __restrict__ bet, float* __restrict__ out)
{
    int tid = threadIdx.x;
    int px = tid & 31, lpy = tid >> 5;           // 0..31, 0..7
    int bt = blockIdx.x >> 2, tile = blockIdx.x & 3;
    int b = bt >> 5, t = bt & 31;
    int py0 = tile * 8;

    __shared__ __align__(16) float lds[3 * S0_PLANE];   // 52272 B

    for (int cog = 0; cog < 2; ++cog) {
        float acc[16][4];
        #pragma unroll
        for (int j = 0; j < 16; ++j)
            #pragma unroll
            for (int q = 0; q < 4; ++q) acc[j][q] = 0.f;

        for (int kt = 0; kt < 3; ++kt) {
            int ts = t + kt - 1;
            if (ts < 0 || ts >= Tn) continue;    // block-uniform
            __syncthreads();
            // fill 3 ci planes
            for (int idx = tid; idx < 3 * S0_PLANE; idx += 256) {
                int ci  = idx / S0_PLANE;
                int rem = idx - ci * S0_PLANE;
                int r = rem / S0_STR, c = rem - r * S0_STR;
                int gy = 4 * py0 - 1 + r, gx = c - 1;
                float v = 0.f;
                if (gy >= 0 && gx >= 0 && gx < 128)
                    v = in[((size_t)(b * Tn + ts) * 3 + ci) * 16384 + gy * 128 + gx];
                lds[idx] = v;
            }
            __syncthreads();

            for (int ci = 0; ci < 3; ++ci) {
                const float* pl = lds + ci * S0_PLANE;
                float p[5][5];
                #pragma unroll
                for (int iy = 0; iy < 5; ++iy) {
                    const float* rp = pl + (4 * lpy + iy) * S0_STR + 4 * px;
                    float4 v4 = *(const float4*)rp;
                    p[iy][0] = v4.x; p[iy][1] = v4.y; p[iy][2] = v4.z; p[iy][3] = v4.w;
                    p[iy][4] = rp[4];
                }
                #pragma unroll
                for (int j = 0; j < 16; ++j) {
                    int co = cog * 16 + j;
                    const float* wp = w + ((size_t)(co * 3 + ci) * 3 + kt) * 9;
                    #pragma unroll
                    for (int ky = 0; ky < 3; ++ky)
                        #pragma unroll
                        for (int kx = 0; kx < 3; ++kx) {
                            float wv = wp[ky * 3 + kx];
                            acc[j][0] = fmaf(wv, p[ky][kx],         acc[j][0]);
                            acc[j][1] = fmaf(wv, p[ky][kx + 2],     acc[j][1]);
                            acc[j][2] = fmaf(wv, p[ky + 2][kx],     acc[j][2]);
                            acc[j][3] = fmaf(wv, p[ky + 2][kx + 2], acc[j][3]);
                        }
                }
            }
        }
        int py = py0 + lpy;
        #pragma unroll
        for (int j = 0; j < 16; ++j) {
            int co = cog * 16 + j;
            float bi = bias[co], g = gam[co], be = bet[co];
            float a0 = fmaxf(fmaf(g, acc[j][0] + bi, be), 0.f);
            float a1 = fmaxf(fmaf(g, acc[j][1] + bi, be), 0.f);
            float a2 = fmaxf(fmaf(g, acc[j][2] + bi, be), 0.f);
            float a3 = fmaxf(fmaf(g, acc[j][3] + bi, be), 0.f);
            out[(((size_t)(b * Tn + t) * 32 + co) * 32 + py) * 32 + px] =
                fmaxf(fmaxf(a0, a1), fmaxf(a2, a3));
        }
    }
}

// ---------------------------------------------------------------------------
// Stage 1: Conv3D 32ci->64co, in 32x32 -> pooled 8x8. LDS-staged.
// Grid: (B*T)*2 co-halves. Block 256 thr = 64 spatial * 4 co-groups (wave-
// uniform via readfirstlane). Each thread: 8 co, acc[8][4].
// LDS chunk: 8 ci planes, 33 rows x 36 cols.
// ---------------------------------------------------------------------------
constexpr int S1_STR = 36, S1_PLANE = 33 * S1_STR;

__global__ __launch_bounds__(256) void conv1_kernel(
    const float* __restrict__ in, const float* __restrict__ w,
    const float* __restrict__ bias, const float* __restrict__ gam,
    const float* __restrict__ bet, float* __restrict__ out)
{
    int tid = threadIdx.x;
    int lane = tid & 63;
    int px = lane & 7, py = lane >> 3;
    int cog = __builtin_amdgcn_readfirstlane(tid >> 6);   // wave id 0..3
    int bt = blockIdx.x >> 1, half = blockIdx.x & 1;
    int b = bt >> 5, t = bt & 31;
    int coBase = half * 32 + cog * 8;

    __shared__ __align__(16) float lds[8 * S1_PLANE];     // 38016 B

    float acc[8][4];
    #pragma unroll
    for (int j = 0; j < 8; ++j)
        #pragma unroll
        for (int q = 0; q < 4; ++q) acc[j][q] = 0.f;

    for (int kt = 0; kt < 3; ++kt) {
        int ts = t + kt - 1;
        if (ts < 0 || ts >= Tn) continue;                 // block-uniform
        for (int chunk = 0; chunk < 4; ++chunk) {
            __syncthreads();
            for (int idx = tid; idx < 8 * S1_PLANE; idx += 256) {
                int ci  = idx / S1_PLANE;
                int rem = idx - ci * S1_PLANE;
                int r = rem / S1_STR, c = rem - r * S1_STR;
                int gy = r - 1, gx = c - 1;
                float v = 0.f;
                if (gy >= 0 && gy < 32 && gx >= 0 && gx < 32)
                    v = in[((size_t)(b * Tn + ts) * 32 + chunk * 8 + ci) * 1024 + gy * 32 + gx];
                lds[idx] = v;
            }
            __syncthreads();

            for (int ci8 = 0; ci8 < 8; ++ci8) {
                int ci = chunk * 8 + ci8;
                const float* pl = lds + ci8 * S1_PLANE;
                float p[5][5];
                #pragma unroll
                for (int iy = 0; iy < 5; ++iy) {
                    const float* rp = pl + (4 * py + iy) * S1_STR + 4 * px;
                    float4 v4 = *(const float4*)rp;
                    p[iy][0] = v4.x; p[iy][1] = v4.y; p[iy][2] = v4.z; p[iy][3] = v4.w;
                    p[iy][4] = rp[4];
                }
                #pragma unroll
                for (int j = 0; j < 8; ++j) {
                    int co = coBase + j;
                    const float* wp = w + ((size_t)(co * 32 + ci) * 3 + kt) * 9;
                    #pragma unroll
                    for (int ky = 0; ky < 3; ++ky)
                        #pragma unroll
                        for (int kx = 0; kx < 3; ++kx) {
                            float wv = wp[ky * 3 + kx];
                            acc[j][0] = fmaf(wv, p[ky][kx],         acc[j][0]);
                            acc[j][1] = fmaf(wv, p[ky][kx + 2],     acc[j][1]);
                            acc[j][2] = fmaf(wv, p[ky + 2][kx],     acc[j][2]);
                            acc[j][3] = fmaf(wv, p[ky + 2][kx + 2], acc[j][3]);
                        }
                }
            }
        }
    }
    #pragma unroll
    for (int j = 0; j < 8; ++j) {
        int co = coBase + j;
        float bi = bias[co], g = gam[co], be = bet[co];
        float a0 = fmaxf(fmaf(g, acc[j][0] + bi, be), 0.f);
        float a1 = fmaxf(fmaf(g, acc[j][1] + bi, be), 0.f);
        float a2 = fmaxf(fmaf(g, acc[j][2] + bi, be), 0.f);
        float a3 = fmaxf(fmaf(g, acc[j][3] + bi, be), 0.f);
        out[((size_t)(b * Tn + t) * 64 + co) * 64 + py * 8 + px] =
            fmaxf(fmaxf(a0, a1), fmaxf(a2, a3));
    }
}

// ---------------------------------------------------------------------------
// Generic naive fused conv (kept for stage 2 only: 64ci->96co on 8x8).
// ---------------------------------------------------------------------------
__global__ void conv3d_fused(const float* __restrict__ in, const float* __restrict__ w,
                             const float* __restrict__ bias, const float* __restrict__ gam,
                             const float* __restrict__ bet, float* __restrict__ out,
                             int Cin, int Cout, int Hin, int Win, int Hp, int Wp, int total)
{
    int idx = blockIdx.x * blockDim.x + threadIdx.x;
    if (idx >= total) return;
    int px = idx % Wp; int r = idx / Wp;
    int py = r % Hp;   r /= Hp;
    int co = r % Cout; r /= Cout;
    int t  = r % Tn;   int b = r / Tn;

    float a00 = 0.f, a01 = 0.f, a10 = 0.f, a11 = 0.f;
    for (int kt = 0; kt < 3; ++kt) {
        int ts = t + kt - 1;
        if (ts < 0 || ts >= Tn) continue;
        for (int ci = 0; ci < Cin; ++ci) {
            const float* plane = in + ((size_t)(b * Tn + ts) * Cin + ci) * (size_t)(Hin * Win);
            const float* wp    = w  + ((size_t)(co * Cin + ci) * 3 + kt) * 9;
            float p[5][5];
            #pragma unroll
            for (int iy = 0; iy < 5; ++iy) {
                int y = 4 * py - 1 + iy;
                #pragma unroll
                for (int ix = 0; ix < 5; ++ix) {
                    int x = 4 * px - 1 + ix;
                    p[iy][ix] = (y >= 0 && x >= 0) ? plane[y * Win + x] : 0.f;
                }
            }
            #pragma unroll
            for (int ky = 0; ky < 3; ++ky)
                #pragma unroll
                for (int kx = 0; kx < 3; ++kx) {
                    float wv = wp[ky * 3 + kx];
                    a00 = fmaf(wv, p[ky][kx],         a00);
                    a01 = fmaf(wv, p[ky][kx + 2],     a01);
                    a10 = fmaf(wv, p[ky + 2][kx],     a10);
                    a11 = fmaf(wv, p[ky + 2][kx + 2], a11);
                }
        }
    }
    float bi = bias[co], g = gam[co], be = bet[co];
    a00 = fmaxf(fmaf(g, a00 + bi, be), 0.f);
    a01 = fmaxf(fmaf(g, a01 + bi, be), 0.f);
    a10 = fmaxf(fmaf(g, a10 + bi, be), 0.f);
    a11 = fmaxf(fmaf(g, a11 + bi, be), 0.f);
    out[idx] = fmaxf(fmaxf(a00, a01), fmaxf(a10, a11));
}

// ---------------------------------------------------------------------------
// Fused: GAP(2x2) -> ep projection, bbox MLP, u = ff + bf.
// ---------------------------------------------------------------------------
__global__ void fuse_u_kernel(const float* __restrict__ buf2, const float* __restrict__ ep_w,
                              const float* __restrict__ ep_b, const float* __restrict__ bb,
                              const float* __restrict__ bp1_w, const float* __restrict__ bp1_b,
                              const float* __restrict__ bp2_w, const float* __restrict__ bp2_b,
                              float* __restrict__ u)
{
    int bt = blockIdx.x;
    int m  = threadIdx.x;
    __shared__ float hs[64];
    __shared__ float gap[96];
    if (m < 64) {
        float a = bp1_b[m];
        #pragma unroll
        for (int k = 0; k < 4; ++k) a = fmaf(bp1_w[m * 4 + k], bb[bt * 4 + k], a);
        hs[m] = fmaxf(a, 0.f);
    } else if (m < 160) {
        int c = m - 64;
        const float* p = buf2 + ((size_t)bt * 96 + c) * 4;
        gap[c] = 0.25f * (p[0] + p[1] + p[2] + p[3]);
    }
    __syncthreads();
    float ff = ep_b[m];
    for (int c = 0; c < 96; ++c) ff = fmaf(gap[c], ep_w[m * 96 + c], ff);
    float bfv = bp2_b[m];
    for (int j = 0; j < 64; ++j) bfv = fmaf(hs[j], bp2_w[m * 64 + j], bfv);
    u[(size_t)bt * 256 + m] = ff + bfv;
}

// ---------------------------------------------------------------------------
// Linear with 4-token m-tiling: out[m0+r, o] = act(in[m0+r,:K].w[o,:K]+b[o]).
// total = (M/4)*N. Reuses each weight float4 across 4 tokens.
// ---------------------------------------------------------------------------
__global__ void linear_kernel(const float* __restrict__ in, const float* __restrict__ w,
                              const float* __restrict__ bias, float* __restrict__ out,
                              int K, int N, int ldin, int act, int total)
{
    int idx = blockIdx.x * blockDim.x + threadIdx.x;
    if (idx >= total) return;
    int o = idx % N; int m0 = (idx / N) * 4;
    const float4* wp = (const float4*)(w + (size_t)o * K);
    const float4* i0 = (const float4*)(in + (size_t)(m0 + 0) * ldin);
    const float4* i1 = (const float4*)(in + (size_t)(m0 + 1) * ldin);
    const float4* i2 = (const float4*)(in + (size_t)(m0 + 2) * ldin);
    const float4* i3 = (const float4*)(in + (size_t)(m0 + 3) * ldin);
    float a0 = 0.f, a1 = 0.f, a2 = 0.f, a3 = 0.f;
    int K4 = K >> 2;
    for (int k = 0; k < K4; ++k) {
        float4 wv = wp[k];
        float4 x0 = i0[k], x1 = i1[k], x2 = i2[k], x3 = i3[k];
        a0 = fmaf(x0.x, wv.x, a0); a0 = fmaf(x0.y, wv.y, a0);
        a0 = fmaf(x0.z, wv.z, a0); a0 = fmaf(x0.w, wv.w, a0);
        a1 = fmaf(x1.x, wv.x, a1); a1 = fmaf(x1.y, wv.y, a1);
        a1 = fmaf(x1.z, wv.z, a1); a1 = fmaf(x1.w, wv.w, a1);
        a2 = fmaf(x2.x, wv.x, a2); a2 = fmaf(x2.y, wv.y, a2);
        a2 = fmaf(x2.z, wv.z, a2); a2 = fmaf(x2.w, wv.w, a2);
        a3 = fmaf(x3.x, wv.x, a3); a3 = fmaf(x3.y, wv.y, a3);
        a3 = fmaf(x3.z, wv.z, a3); a3 = fmaf(x3.w, wv.w, a3);
    }
    float av[4] = {a0, a1, a2, a3};
    float bv = bias ? bias[o] : 0.f;
    #pragma unroll
    for (int r = 0; r < 4; ++r) {
        float a = av[r] + bv;
        if (act == 1)      a = fmaxf(a, 0.f);
        else if (act == 2) a = 1.f / (1.f + expf(-a));
        else if (act == 3) a = (a > 20.f) ? a : log1pf(expf(a));
        out[(size_t)(m0 + r) * N + o] = a;
    }
}

// ---------------------------------------------------------------------------
// Causal depthwise conv1d (k=4) + SiLU.
// ---------------------------------------------------------------------------
__global__ void conv1d_silu_kernel(const float* __restrict__ xz, const float* __restrict__ cw,
                                   const float* __restrict__ cb, float* __restrict__ xs)
{
    int idx = blockIdx.x * blockDim.x + threadIdx.x;
    if (idx >= Bn * Tn * D_INNER) return;
    int d = idx % D_INNER; int r = idx / D_INNER;
    int t = r % Tn; int b = r / Tn;
    float acc = cb[d];
    #pragma unroll
    for (int k = 0; k < 4; ++k) {
        int ts = t - 3 + k;
        if (ts >= 0) acc = fmaf(cw[d * 4 + k], xz[(size_t)(b * Tn + ts) * 1024 + d], acc);
    }
    xs[idx] = acc / (1.f + expf(-acc));
}

// ---------------------------------------------------------------------------
// Selective-scan (Mamba SSM) + skip + silu(z) gate. One thread per (b,d).
// ---------------------------------------------------------------------------
__global__ void ssm_kernel(const float* __restrict__ xdbl, const float* __restrict__ dtb,
                           const float* __restrict__ xs, const float* __restrict__ xz,
                           const float* __restrict__ A_log, const float* __restrict__ Dp,
                           float* __restrict__ y)
{
    int idx = blockIdx.x * blockDim.x + threadIdx.x;
    if (idx >= Bn * D_INNER) return;
    int d = idx % D_INNER; int b = idx / D_INNER;
    float A[16], h[16];
    #pragma unroll
    for (int s = 0; s < 16; ++s) { A[s] = -expf(A_log[d * 16 + s]); h[s] = 0.f; }
    float Dv = Dp[d];
    for (int t = 0; t < Tn; ++t) {
        int bt = b * Tn + t;
        float dtv = dtb[(size_t)bt * 512 + d];
        float xv  = xs [(size_t)bt * 512 + d];
        const float* xrow = xdbl + (size_t)bt * 48;
        float acc = 0.f;
        #pragma unroll
        for (int s = 0; s < 16; ++s) {
            float dA = expf(dtv * A[s]);
            h[s] = fmaf(dA, h[s], dtv * xrow[16 + s] * xv);
            acc  = fmaf(h[s], xrow[32 + s], acc);
        }
        float zv  = xz[(size_t)bt * 1024 + 512 + d];
        float sig = 1.f / (1.f + expf(-zv));
        y[(size_t)bt * 512 + d] = (acc + Dv * xv) * (zv * sig);
    }
}

// ---------------------------------------------------------------------------
// Kalman filter scan, one thread per batch.
// ---------------------------------------------------------------------------
__global__ void kf_kernel(const float* __restrict__ meas, const float* __restrict__ bb,
                          const float* __restrict__ Fin, const float* __restrict__ Hmin,
                          const float* __restrict__ lq, const float* __restrict__ lr,
                          float* __restrict__ pred)
{
    int b = blockIdx.x * blockDim.x + threadIdx.x;
    if (b >= Bn) return;
    float F[4][4], Hm[4][4], Qd[4], Rd[4];
    #pragma unroll
    for (int i = 0; i < 4; ++i) {
        Qd[i] = expf(lq[i]) + 1e-6f;
        Rd[i] = expf(lr[i]) + 1e-6f;
        #pragma unroll
        for (int j = 0; j < 4; ++j) { F[i][j] = Fin[i * 4 + j]; Hm[i][j] = Hmin[i * 4 + j]; }
    }
    float s[4], P[4][4];
    #pragma unroll
    for (int i = 0; i < 4; ++i) {
        s[i] = bb[(b * Tn) * 4 + i];
        #pragma unroll
        for (int j = 0; j < 4; ++j) P[i][j] = (i == j) ? 0.01f : 0.f;
    }
    for (int t = 0; t < Tn; ++t) {
        float mv[4];
        #pragma unroll
        for (int i = 0; i < 4; ++i) mv[i] = meas[(b * Tn + t) * 4 + i];
        float sp[4];
        #pragma unroll
        for (int i = 0; i < 4; ++i) { float a = 0.f;
            #pragma unroll
            for (int j = 0; j < 4; ++j) a = fmaf(F[i][j], s[j], a); sp[i] = a; }
        float FP[4][4];
        #pragma unroll
        for (int i = 0; i < 4; ++i)
            #pragma unroll
            for (int j = 0; j < 4; ++j) { float a = 0.f;
                for (int k = 0; k < 4; ++k) a = fmaf(F[i][k], P[k][j], a); FP[i][j] = a; }
        float Pp[4][4];
        #pragma unroll
        for (int i = 0; i < 4; ++i)
            #pragma unroll
            for (int j = 0; j < 4; ++j) { float a = 0.f;
                for (int k = 0; k < 4; ++k) a = fmaf(FP[i][k], F[j][k], a);
                Pp[i][j] = a + ((i == j) ? Qd[i] : 0.f); }
        float yr[4];
        #pragma unroll
        for (int i = 0; i < 4; ++i) { float a = 0.f;
            for (int j = 0; j < 4; ++j) a = fmaf(Hm[i][j], sp[j], a); yr[i] = mv[i] - a; }
        float HP[4][4];
        #pragma unroll
        for (int i = 0; i < 4; ++i)
            #pragma unroll
            for (int j = 0; j < 4; ++j) { float a = 0.f;
                for (int k = 0; k < 4; ++k) a = fmaf(Hm[i][k], Pp[k][j], a); HP[i][j] = a; }
        float S[4][8];
        #pragma unroll
        for (int i = 0; i < 4; ++i)
            #pragma unroll
            for (int j = 0; j < 4; ++j) { float a = 0.f;
                for (int k = 0; k < 4; ++k) a = fmaf(HP[i][k], Hm[j][k], a);
                S[i][j] = a + ((i == j) ? Rd[i] : 0.f);
                S[i][4 + j] = Hm[i][j]; }
        #pragma unroll
        for (int c = 0; c < 4; ++c) {
            float dinv = 1.f / S[c][c];
            #pragma unroll
            for (int j = 0; j < 8; ++j) S[c][j] *= dinv;
            #pragma unroll
            for (int r2 = 0; r2 < 4; ++r2) {
                if (r2 == c) continue;
                float f = S[r2][c];
                #pragma unroll
                for (int j = 0; j < 8; ++j) S[r2][j] = fmaf(-f, S[c][j], S[r2][j]);
            }
        }
        float K[4][4];
        #pragma unroll
        for (int i = 0; i < 4; ++i)
            #pragma unroll
            for (int k = 0; k < 4; ++k) { float a = 0.f;
                for (int j = 0; j < 4; ++j) a = fmaf(Pp[i][j], S[k][4 + j], a); K[i][k] = a; }
        float sn[4];
        #pragma unroll
        for (int i = 0; i < 4; ++i) { float a = sp[i];
            for (int j = 0; j < 4; ++j) a = fmaf(K[i][j], yr[j], a); sn[i] = a; }
        float IKH[4][4];
        #pragma unroll
        for (int i = 0; i < 4; ++i)
            #pragma unroll
            for (int j = 0; j < 4; ++j) { float a = (i == j) ? 1.f : 0.f;
                for (int k = 0; k < 4; ++k) a = fmaf(-K[i][k], Hm[k][j], a); IKH[i][j] = a; }
        float T1[4][4];
        #pragma unroll
        for (int i = 0; i < 4; ++i)
            #pragma unroll
            for (int j = 0; j < 4; ++j) { float a = 0.f;
                for (int k = 0; k < 4; ++k) a = fmaf(IKH[i][k], Pp[k][j], a); T1[i][j] = a; }
        #pragma unroll
        for (int i = 0; i < 4; ++i)
            #pragma unroll
            for (int j = 0; j < 4; ++j) { float a = 0.f;
                for (int k = 0; k < 4; ++k) a = fmaf(T1[i][k], IKH[j][k], a);
                for (int k = 0; k < 4; ++k) a = fmaf(K[i][k] * Rd[k], K[j][k], a);
                P[i][j] = a; }
        #pragma unroll
        for (int i = 0; i < 4; ++i) { s[i] = sn[i]; pred[(b * Tn + t) * 4 + i] = sn[i]; }
    }
}

// ---------------------------------------------------------------------------
extern "C" void kernel_launch(void* const* d_in, const int* in_sizes, int n_in,
                              void* d_out, int out_size, void* d_ws, size_t ws_size,
                              hipStream_t stream)
{
    const float* frames = (const float*)d_in[0];
    const float* bb     = (const float*)d_in[1];
    const float* cw0 = (const float*)d_in[2],  *cb0 = (const float*)d_in[3];
    const float* g0  = (const float*)d_in[4],  *be0 = (const float*)d_in[5];
    const float* cw1 = (const float*)d_in[6],  *cb1 = (const float*)d_in[7];
    const float* g1  = (const float*)d_in[8],  *be1 = (const float*)d_in[9];
    const float* cw2 = (const float*)d_in[10], *cb2 = (const float*)d_in[11];
    const float* g2  = (const float*)d_in[12], *be2 = (const float*)d_in[13];
    const float* ep_w  = (const float*)d_in[14], *ep_b  = (const float*)d_in[15];
    const float* bp1_w = (const float*)d_in[16], *bp1_b = (const float*)d_in[17];
    const float* bp2_w = (const float*)d_in[18], *bp2_b = (const float*)d_in[19];
    const float* in_proj_w = (const float*)d_in[20];
    const float* c1w = (const float*)d_in[21], *c1b = (const float*)d_in[22];
    const float* x_proj_w = (const float*)d_in[23];
    const float* dt_w = (const float*)d_in[24], *dt_b = (const float*)d_in[25];
    const float* A_log = (const float*)d_in[26], *Dp = (const float*)d_in[27];
    const float* out_proj_w = (const float*)d_in[28];
    const float* h1_w = (const float*)d_in[29], *h1_b = (const float*)d_in[30];
    const float* h2_w = (const float*)d_in[31], *h2_b = (const float*)d_in[32];
    const float* kfF = (const float*)d_in[33], *kfH = (const float*)d_in[34];
    const float* kfq = (const float*)d_in[35], *kfr = (const float*)d_in[36];

    // workspace layout (floats)
    float* ws   = (float*)d_ws;
    float* buf0 = ws;                                   // (8,32,32,32,32)
    float* buf1 = buf0 + (size_t)8 * 32 * 32 * 32 * 32; // (8,32,64,8,8)
    float* buf2 = buf1 + (size_t)8 * 32 * 64 * 8 * 8;   // (8,32,96,2,2)
    float* ub   = buf2 + (size_t)8 * 32 * 96 * 2 * 2;   // (256,256)
    float* xzb  = ub   + 256 * 256;                     // (256,1024)
    float* xsb  = xzb  + 256 * 1024;                    // (256,512)
    float* xdb  = xsb  + 256 * 512;                     // (256,48)
    float* dtbf = xdb  + 256 * 48;                      // (256,512)
    float* yb   = dtbf + 256 * 512;                     // (256,512)
    float* mob  = yb   + 256 * 512;                     // (256,256)
    float* hidb = mob  + 256 * 256;                     // (256,128)

    float* kf_out   = (float*)d_out;          // (8,32,4)
    float* meas_out = kf_out + Bn * Tn * 4;   // (8,32,4)

    auto nblk = [](int n) { return dim3((unsigned)((n + 255) / 256)); };

    // CNN backbone
    conv0_kernel<<<dim3(256 * 4), 256, 0, stream>>>(frames, cw0, cb0, g0, be0, buf0);
    conv1_kernel<<<dim3(256 * 2), 256, 0, stream>>>(buf0, cw1, cb1, g1, be1, buf1);
    { int tot = 8 * 32 * 96 * 2 * 2;
      conv3d_fused<<<nblk(tot), 256, 0, stream>>>(buf1, cw2, cb2, g2, be2, buf2,
                                                  64, 96, 8, 8, 2, 2, tot); }

    // GAP + embed proj + bbox MLP -> u
    fuse_u_kernel<<<256, 256, 0, stream>>>(buf2, ep_w, ep_b, bb, bp1_w, bp1_b, bp2_w, bp2_b, ub);

    // Mamba block (linear kernels use 4-token m-tiling: total = (256/4)*N)
    linear_kernel<<<nblk(64 * 1024), 256, 0, stream>>>(ub, in_proj_w, nullptr, xzb,
                                                       256, 1024, 256, 0, 64 * 1024);
    conv1d_silu_kernel<<<nblk(256 * 512), 256, 0, stream>>>(xzb, c1w, c1b, xsb);
    linear_kernel<<<nblk(64 * 48), 256, 0, stream>>>(xsb, x_proj_w, nullptr, xdb,
                                                     512, 48, 512, 0, 64 * 48);
    linear_kernel<<<nblk(64 * 512), 256, 0, stream>>>(xdb, dt_w, dt_b, dtbf,
                                                      16, 512, 48, 3, 64 * 512);
    ssm_kernel<<<nblk(8 * 512), 256, 0, stream>>>(xdb, dtbf, xsb, xzb, A_log, Dp, yb);
    linear_kernel<<<nblk(64 * 256), 256, 0, stream>>>(yb, out_proj_w, nullptr, mob,
                                                      512, 256, 512, 0, 64 * 256);

    // Measurement head -> meas (second output)
    linear_kernel<<<nblk(64 * 128), 256, 0, stream>>>(mob, h1_w, h1_b, hidb,
                                                      256, 128, 256, 1, 64 * 128);
    linear_kernel<<<nblk(64 * 4), 256, 0, stream>>>(hidb, h2_w, h2_b, meas_out,
                                                    128, 4, 128, 2, 64 * 4);

    // Kalman filter -> kf_pred (first output)
    kf_kernel<<<1, 64, 0, stream>>>(meas_out, bb, kfF, kfH, kfq, kfr, kf_out);
}

// Round 3
// 994.223 us; speedup vs baseline: 4.4066x; 1.1894x over previous
//
#include <hip/hip_runtime.h>
#include <math.h>

// Problem constants
constexpr int Bn = 8, Tn = 32;
constexpr int D_INNER = 512;

// ---------------------------------------------------------------------------
// Stage 0: Conv3D 3ci->32co, in 128x128, stride(1,2,2), pad 1 + BN + ReLU +
// maxpool(2,2) -> out (B,T,32,32,32). LDS-staged.
// ---------------------------------------------------------------------------
constexpr int S0_ROWS = 33, S0_STR = 132, S0_PLANE = S0_ROWS * S0_STR;

__global__ __launch_bounds__(256) void conv0_kernel(
    const float* __restrict__ in, const float* __restrict__ w,
    const float* __restrict__ bias, const float* __restrict__ gam,
    const float* __restrict__ bet, float* __restrict__ out)
{
    int tid = threadIdx.x;
    int px = tid & 31, lpy = tid >> 5;           // 0..31, 0..7
    int bt = blockIdx.x >> 2, tile = blockIdx.x & 3;
    int b = bt >> 5, t = bt & 31;
    int py0 = tile * 8;

    __shared__ __align__(16) float lds[3 * S0_PLANE];   // 52272 B

    for (int cog = 0; cog < 2; ++cog) {
        float acc[16][4];
        #pragma unroll
        for (int j = 0; j < 16; ++j)
            #pragma unroll
            for (int q = 0; q < 4; ++q) acc[j][q] = 0.f;

        for (int kt = 0; kt < 3; ++kt) {
            int ts = t + kt - 1;
            if (ts < 0 || ts >= Tn) continue;    // block-uniform
            __syncthreads();
            for (int idx = tid; idx < 3 * S0_PLANE; idx += 256) {
                int ci  = idx / S0_PLANE;
                int rem = idx - ci * S0_PLANE;
                int r = rem / S0_STR, c = rem - r * S0_STR;
                int gy = 4 * py0 - 1 + r, gx = c - 1;
                float v = 0.f;
                if (gy >= 0 && gx >= 0 && gx < 128)
                    v = in[((size_t)(b * Tn + ts) * 3 + ci) * 16384 + gy * 128 + gx];
                lds[idx] = v;
            }
            __syncthreads();

            for (int ci = 0; ci < 3; ++ci) {
                const float* pl = lds + ci * S0_PLANE;
                float p[5][5];
                #pragma unroll
                for (int iy = 0; iy < 5; ++iy) {
                    const float* rp = pl + (4 * lpy + iy) * S0_STR + 4 * px;
                    float4 v4 = *(const float4*)rp;
                    p[iy][0] = v4.x; p[iy][1] = v4.y; p[iy][2] = v4.z; p[iy][3] = v4.w;
                    p[iy][4] = rp[4];
                }
                #pragma unroll
                for (int j = 0; j < 16; ++j) {
                    int co = cog * 16 + j;
                    const float* wp = w + ((size_t)(co * 3 + ci) * 3 + kt) * 9;
                    #pragma unroll
                    for (int ky = 0; ky < 3; ++ky)
                        #pragma unroll
                        for (int kx = 0; kx < 3; ++kx) {
                            float wv = wp[ky * 3 + kx];
                            acc[j][0] = fmaf(wv, p[ky][kx],         acc[j][0]);
                            acc[j][1] = fmaf(wv, p[ky][kx + 2],     acc[j][1]);
                            acc[j][2] = fmaf(wv, p[ky + 2][kx],     acc[j][2]);
                            acc[j][3] = fmaf(wv, p[ky + 2][kx + 2], acc[j][3]);
                        }
                }
            }
        }
        int py = py0 + lpy;
        #pragma unroll
        for (int j = 0; j < 16; ++j) {
            int co = cog * 16 + j;
            float bi = bias[co], g = gam[co], be = bet[co];
            float a0 = fmaxf(fmaf(g, acc[j][0] + bi, be), 0.f);
            float a1 = fmaxf(fmaf(g, acc[j][1] + bi, be), 0.f);
            float a2 = fmaxf(fmaf(g, acc[j][2] + bi, be), 0.f);
            float a3 = fmaxf(fmaf(g, acc[j][3] + bi, be), 0.f);
            out[(((size_t)(b * Tn + t) * 32 + co) * 32 + py) * 32 + px] =
                fmaxf(fmaxf(a0, a1), fmaxf(a2, a3));
        }
    }
}

// ---------------------------------------------------------------------------
// Stage 1: Conv3D 32ci->64co, in 32x32 -> pooled 8x8. LDS-staged.
// ---------------------------------------------------------------------------
constexpr int S1_STR = 36, S1_PLANE = 33 * S1_STR;

__global__ __launch_bounds__(256) void conv1_kernel(
    const float* __restrict__ in, const float* __restrict__ w,
    const float* __restrict__ bias, const float* __restrict__ gam,
    const float* __restrict__ bet, float* __restrict__ out)
{
    int tid = threadIdx.x;
    int lane = tid & 63;
    int px = lane & 7, py = lane >> 3;
    int cog = __builtin_amdgcn_readfirstlane(tid >> 6);   // wave id 0..3
    int bt = blockIdx.x >> 1, half = blockIdx.x & 1;
    int b = bt >> 5, t = bt & 31;
    int coBase = half * 32 + cog * 8;

    __shared__ __align__(16) float lds[8 * S1_PLANE];     // 38016 B

    float acc[8][4];
    #pragma unroll
    for (int j = 0; j < 8; ++j)
        #pragma unroll
        for (int q = 0; q < 4; ++q) acc[j][q] = 0.f;

    for (int kt = 0; kt < 3; ++kt) {
        int ts = t + kt - 1;
        if (ts < 0 || ts >= Tn) continue;                 // block-uniform
        for (int chunk = 0; chunk < 4; ++chunk) {
            __syncthreads();
            for (int idx = tid; idx < 8 * S1_PLANE; idx += 256) {
                int ci  = idx / S1_PLANE;
                int rem = idx - ci * S1_PLANE;
                int r = rem / S1_STR, c = rem - r * S1_STR;
                int gy = r - 1, gx = c - 1;
                float v = 0.f;
                if (gy >= 0 && gy < 32 && gx >= 0 && gx < 32)
                    v = in[((size_t)(b * Tn + ts) * 32 + chunk * 8 + ci) * 1024 + gy * 32 + gx];
                lds[idx] = v;
            }
            __syncthreads();

            for (int ci8 = 0; ci8 < 8; ++ci8) {
                int ci = chunk * 8 + ci8;
                const float* pl = lds + ci8 * S1_PLANE;
                float p[5][5];
                #pragma unroll
                for (int iy = 0; iy < 5; ++iy) {
                    const float* rp = pl + (4 * py + iy) * S1_STR + 4 * px;
                    float4 v4 = *(const float4*)rp;
                    p[iy][0] = v4.x; p[iy][1] = v4.y; p[iy][2] = v4.z; p[iy][3] = v4.w;
                    p[iy][4] = rp[4];
                }
                #pragma unroll
                for (int j = 0; j < 8; ++j) {
                    int co = coBase + j;
                    const float* wp = w + ((size_t)(co * 32 + ci) * 3 + kt) * 9;
                    #pragma unroll
                    for (int ky = 0; ky < 3; ++ky)
                        #pragma unroll
                        for (int kx = 0; kx < 3; ++kx) {
                            float wv = wp[ky * 3 + kx];
                            acc[j][0] = fmaf(wv, p[ky][kx],         acc[j][0]);
                            acc[j][1] = fmaf(wv, p[ky][kx + 2],     acc[j][1]);
                            acc[j][2] = fmaf(wv, p[ky + 2][kx],     acc[j][2]);
                            acc[j][3] = fmaf(wv, p[ky + 2][kx + 2], acc[j][3]);
                        }
                }
            }
        }
    }
    #pragma unroll
    for (int j = 0; j < 8; ++j) {
        int co = coBase + j;
        float bi = bias[co], g = gam[co], be = bet[co];
        float a0 = fmaxf(fmaf(g, acc[j][0] + bi, be), 0.f);
        float a1 = fmaxf(fmaf(g, acc[j][1] + bi, be), 0.f);
        float a2 = fmaxf(fmaf(g, acc[j][2] + bi, be), 0.f);
        float a3 = fmaxf(fmaf(g, acc[j][3] + bi, be), 0.f);
        out[((size_t)(b * Tn + t) * 64 + co) * 64 + py * 8 + px] =
            fmaxf(fmaxf(a0, a1), fmaxf(a2, a3));
    }
}

// ---------------------------------------------------------------------------
// One-time weight transpose for stage 2: w (96,64,3,9) -> w2[kt][ci][k9][co].
// Coalesced writes; makes conv2's LDS fill a contiguous copy.
// ---------------------------------------------------------------------------
__global__ void conv2_wt_kernel(const float* __restrict__ w, float* __restrict__ w2)
{
    int idx = blockIdx.x * blockDim.x + threadIdx.x;
    if (idx >= 96 * 64 * 27) return;
    int co = idx % 96; int r = idx / 96;
    int k9 = r % 9;    r /= 9;
    int ci = r % 64;   int kt = r / 64;
    w2[idx] = w[(((size_t)co * 64 + ci) * 3 + kt) * 9 + k9];
}

// ---------------------------------------------------------------------------
// Stage 2: Conv3D 64ci->96co on 8x8 -> pooled 2x2. LDS-staged.
// One block per (b,t); 384 thr = 96 co x 4 pooled quads. Per (kt, 8-ci chunk):
// stage input planes (10x12) + weights [ci8][k9][co] in LDS.
// ---------------------------------------------------------------------------
__global__ __launch_bounds__(384) void conv2_kernel(
    const float* __restrict__ in, const float* __restrict__ w2,
    const float* __restrict__ bias, const float* __restrict__ gam,
    const float* __restrict__ bet, float* __restrict__ out)
{
    int tid = threadIdx.x;                 // 0..383
    int co = tid >> 2, quad = tid & 3;     // co 0..95
    int qy = quad >> 1, qx = quad & 1;
    int bt = blockIdx.x;
    int b = bt >> 5, t = bt & 31;

    __shared__ __align__(16) float lin[8 * 120];    // 3840 B
    __shared__ __align__(16) float lw[8 * 9 * 96];  // 27648 B

    float acc[4] = {0.f, 0.f, 0.f, 0.f};

    for (int kt = 0; kt < 3; ++kt) {
        int ts = t + kt - 1;
        if (ts < 0 || ts >= Tn) continue;          // block-uniform
        for (int chunk = 0; chunk < 8; ++chunk) {
            __syncthreads();
            // input: 8 ci planes of 10x12 (row r <-> gy=r-1, col c <-> gx=c-1)
            for (int idx = tid; idx < 8 * 120; idx += 384) {
                int ci  = idx / 120;
                int rem = idx - ci * 120;
                int r = rem / 12, c = rem - r * 12;
                int gy = r - 1, gx = c - 1;
                float v = 0.f;
                if (gy >= 0 && gy < 8 && gx >= 0 && gx < 8)
                    v = in[((size_t)(b * Tn + ts) * 64 + chunk * 8 + ci) * 64 + gy * 8 + gx];
                lin[idx] = v;
            }
            // weights: contiguous 6912-float copy from w2
            const float* wsrc = w2 + ((size_t)(kt * 64 + chunk * 8) * 9) * 96;
            for (int idx = tid; idx < 6912; idx += 384) lw[idx] = wsrc[idx];
            __syncthreads();

            #pragma unroll
            for (int ci8 = 0; ci8 < 8; ++ci8) {
                const float* pl = lin + ci8 * 120;
                float p[5][5];
                #pragma unroll
                for (int iy = 0; iy < 5; ++iy) {
                    const float* rp = pl + (4 * qy + iy) * 12 + 4 * qx;
                    float4 v4 = *(const float4*)rp;
                    p[iy][0] = v4.x; p[iy][1] = v4.y; p[iy][2] = v4.z; p[iy][3] = v4.w;
                    p[iy][4] = rp[4];
                }
                const float* wp = lw + ci8 * 9 * 96 + co;
                #pragma unroll
                for (int ky = 0; ky < 3; ++ky)
                    #pragma unroll
                    for (int kx = 0; kx < 3; ++kx) {
                        float wv = wp[(ky * 3 + kx) * 96];
                        acc[0] = fmaf(wv, p[ky][kx],         acc[0]);
                        acc[1] = fmaf(wv, p[ky][kx + 2],     acc[1]);
                        acc[2] = fmaf(wv, p[ky + 2][kx],     acc[2]);
                        acc[3] = fmaf(wv, p[ky + 2][kx + 2], acc[3]);
                    }
            }
        }
    }
    float bi = bias[co], g = gam[co], be = bet[co];
    float a0 = fmaxf(fmaf(g, acc[0] + bi, be), 0.f);
    float a1 = fmaxf(fmaf(g, acc[1] + bi, be), 0.f);
    float a2 = fmaxf(fmaf(g, acc[2] + bi, be), 0.f);
    float a3 = fmaxf(fmaf(g, acc[3] + bi, be), 0.f);
    out[((size_t)bt * 96 + co) * 4 + qy * 2 + qx] = fmaxf(fmaxf(a0, a1), fmaxf(a2, a3));
}

// ---------------------------------------------------------------------------
// Fused: GAP(2x2) -> ep projection, bbox MLP, u = ff + bf.
// ---------------------------------------------------------------------------
__global__ void fuse_u_kernel(const float* __restrict__ buf2, const float* __restrict__ ep_w,
                              const float* __restrict__ ep_b, const float* __restrict__ bb,
                              const float* __restrict__ bp1_w, const float* __restrict__ bp1_b,
                              const float* __restrict__ bp2_w, const float* __restrict__ bp2_b,
                              float* __restrict__ u)
{
    int bt = blockIdx.x;
    int m  = threadIdx.x;
    __shared__ float hs[64];
    __shared__ float gap[96];
    if (m < 64) {
        float a = bp1_b[m];
        #pragma unroll
        for (int k = 0; k < 4; ++k) a = fmaf(bp1_w[m * 4 + k], bb[bt * 4 + k], a);
        hs[m] = fmaxf(a, 0.f);
    } else if (m < 160) {
        int c = m - 64;
        const float* p = buf2 + ((size_t)bt * 96 + c) * 4;
        gap[c] = 0.25f * (p[0] + p[1] + p[2] + p[3]);
    }
    __syncthreads();
    float ff = ep_b[m];
    for (int c = 0; c < 96; ++c) ff = fmaf(gap[c], ep_w[m * 96 + c], ff);
    float bfv = bp2_b[m];
    for (int j = 0; j < 64; ++j) bfv = fmaf(hs[j], bp2_w[m * 64 + j], bfv);
    u[(size_t)bt * 256 + m] = ff + bfv;
}

// ---------------------------------------------------------------------------
// Linear with 4-token m-tiling.
// ---------------------------------------------------------------------------
__global__ void linear_kernel(const float* __restrict__ in, const float* __restrict__ w,
                              const float* __restrict__ bias, float* __restrict__ out,
                              int K, int N, int ldin, int act, int total)
{
    int idx = blockIdx.x * blockDim.x + threadIdx.x;
    if (idx >= total) return;
    int o = idx % N; int m0 = (idx / N) * 4;
    const float4* wp = (const float4*)(w + (size_t)o * K);
    const float4* i0 = (const float4*)(in + (size_t)(m0 + 0) * ldin);
    const float4* i1 = (const float4*)(in + (size_t)(m0 + 1) * ldin);
    const float4* i2 = (const float4*)(in + (size_t)(m0 + 2) * ldin);
    const float4* i3 = (const float4*)(in + (size_t)(m0 + 3) * ldin);
    float a0 = 0.f, a1 = 0.f, a2 = 0.f, a3 = 0.f;
    int K4 = K >> 2;
    for (int k = 0; k < K4; ++k) {
        float4 wv = wp[k];
        float4 x0 = i0[k], x1 = i1[k], x2 = i2[k], x3 = i3[k];
        a0 = fmaf(x0.x, wv.x, a0); a0 = fmaf(x0.y, wv.y, a0);
        a0 = fmaf(x0.z, wv.z, a0); a0 = fmaf(x0.w, wv.w, a0);
        a1 = fmaf(x1.x, wv.x, a1); a1 = fmaf(x1.y, wv.y, a1);
        a1 = fmaf(x1.z, wv.z, a1); a1 = fmaf(x1.w, wv.w, a1);
        a2 = fmaf(x2.x, wv.x, a2); a2 = fmaf(x2.y, wv.y, a2);
        a2 = fmaf(x2.z, wv.z, a2); a2 = fmaf(x2.w, wv.w, a2);
        a3 = fmaf(x3.x, wv.x, a3); a3 = fmaf(x3.y, wv.y, a3);
        a3 = fmaf(x3.z, wv.z, a3); a3 = fmaf(x3.w, wv.w, a3);
    }
    float av[4] = {a0, a1, a2, a3};
    float bv = bias ? bias[o] : 0.f;
    #pragma unroll
    for (int r = 0; r < 4; ++r) {
        float a = av[r] + bv;
        if (act == 1)      a = fmaxf(a, 0.f);
        else if (act == 2) a = 1.f / (1.f + expf(-a));
        else if (act == 3) a = (a > 20.f) ? a : log1pf(expf(a));
        out[(size_t)(m0 + r) * N + o] = a;
    }
}

// ---------------------------------------------------------------------------
// Causal depthwise conv1d (k=4) + SiLU.
// ---------------------------------------------------------------------------
__global__ void conv1d_silu_kernel(const float* __restrict__ xz, const float* __restrict__ cw,
                                   const float* __restrict__ cb, float* __restrict__ xs)
{
    int idx = blockIdx.x * blockDim.x + threadIdx.x;
    if (idx >= Bn * Tn * D_INNER) return;
    int d = idx % D_INNER; int r = idx / D_INNER;
    int t = r % Tn; int b = r / Tn;
    float acc = cb[d];
    #pragma unroll
    for (int k = 0; k < 4; ++k) {
        int ts = t - 3 + k;
        if (ts >= 0) acc = fmaf(cw[d * 4 + k], xz[(size_t)(b * Tn + ts) * 1024 + d], acc);
    }
    xs[idx] = acc / (1.f + expf(-acc));
}

// ---------------------------------------------------------------------------
// Wave-parallel selective scan: lane = (s 0..15, dsub 0..3). One wave handles
// 4 d-channels; h state lives in one register per lane; y via width-16
// shuffle reduction. 1024 waves total.
// ---------------------------------------------------------------------------
__global__ __launch_bounds__(256) void ssm_kernel(
    const float* __restrict__ xdbl, const float* __restrict__ dtb,
    const float* __restrict__ xs, const float* __restrict__ xz,
    const float* __restrict__ A_log, const float* __restrict__ Dp,
    float* __restrict__ y)
{
    int tid = threadIdx.x;
    int lane = tid & 63;
    int s = lane & 15, dsub = lane >> 4;
    int gid = blockIdx.x * 4 + (tid >> 6);      // global wave id 0..1023
    int b = gid >> 7;                           // 128 waves per batch
    int d = ((gid & 127) << 2) + dsub;          // 0..511

    float A = -expf(A_log[d * 16 + s]);
    float Dv = Dp[d];
    float h = 0.f;
    for (int t = 0; t < Tn; ++t) {
        int bt = b * Tn + t;
        float dtv = dtb[(size_t)bt * 512 + d];
        float xv  = xs [(size_t)bt * 512 + d];
        float Bs  = xdbl[(size_t)bt * 48 + 16 + s];
        float Cs  = xdbl[(size_t)bt * 48 + 32 + s];
        float dA = expf(dtv * A);
        h = fmaf(dA, h, dtv * Bs * xv);
        float c = h * Cs;
        c += __shfl_xor(c, 8, 16);
        c += __shfl_xor(c, 4, 16);
        c += __shfl_xor(c, 2, 16);
        c += __shfl_xor(c, 1, 16);
        if (s == 0) {
            float zv = xz[(size_t)bt * 1024 + 512 + d];
            float sig = 1.f / (1.f + expf(-zv));
            y[(size_t)bt * 512 + d] = (c + Dv * xv) * (zv * sig);
        }
    }
}

// ---------------------------------------------------------------------------
// Kalman filter scan, one thread per batch.
// ---------------------------------------------------------------------------
__global__ void kf_kernel(const float* __restrict__ meas, const float* __restrict__ bb,
                          const float* __restrict__ Fin, const float* __restrict__ Hmin,
                          const float* __restrict__ lq, const float* __restrict__ lr,
                          float* __restrict__ pred)
{
    int b = blockIdx.x * blockDim.x + threadIdx.x;
    if (b >= Bn) return;
    float F[4][4], Hm[4][4], Qd[4], Rd[4];
    #pragma unroll
    for (int i = 0; i < 4; ++i) {
        Qd[i] = expf(lq[i]) + 1e-6f;
        Rd[i] = expf(lr[i]) + 1e-6f;
        #pragma unroll
        for (int j = 0; j < 4; ++j) { F[i][j] = Fin[i * 4 + j]; Hm[i][j] = Hmin[i * 4 + j]; }
    }
    float s[4], P[4][4];
    #pragma unroll
    for (int i = 0; i < 4; ++i) {
        s[i] = bb[(b * Tn) * 4 + i];
        #pragma unroll
        for (int j = 0; j < 4; ++j) P[i][j] = (i == j) ? 0.01f : 0.f;
    }
    for (int t = 0; t < Tn; ++t) {
        float mv[4];
        #pragma unroll
        for (int i = 0; i < 4; ++i) mv[i] = meas[(b * Tn + t) * 4 + i];
        float sp[4];
        #pragma unroll
        for (int i = 0; i < 4; ++i) { float a = 0.f;
            #pragma unroll
            for (int j = 0; j < 4; ++j) a = fmaf(F[i][j], s[j], a); sp[i] = a; }
        float FP[4][4];
        #pragma unroll
        for (int i = 0; i < 4; ++i)
            #pragma unroll
            for (int j = 0; j < 4; ++j) { float a = 0.f;
                for (int k = 0; k < 4; ++k) a = fmaf(F[i][k], P[k][j], a); FP[i][j] = a; }
        float Pp[4][4];
        #pragma unroll
        for (int i = 0; i < 4; ++i)
            #pragma unroll
            for (int j = 0; j < 4; ++j) { float a = 0.f;
                for (int k = 0; k < 4; ++k) a = fmaf(FP[i][k], F[j][k], a);
                Pp[i][j] = a + ((i == j) ? Qd[i] : 0.f); }
        float yr[4];
        #pragma unroll
        for (int i = 0; i < 4; ++i) { float a = 0.f;
            for (int j = 0; j < 4; ++j) a = fmaf(Hm[i][j], sp[j], a); yr[i] = mv[i] - a; }
        float HP[4][4];
        #pragma unroll
        for (int i = 0; i < 4; ++i)
            #pragma unroll
            for (int j = 0; j < 4; ++j) { float a = 0.f;
                for (int k = 0; k < 4; ++k) a = fmaf(Hm[i][k], Pp[k][j], a); HP[i][j] = a; }
        float S[4][8];
        #pragma unroll
        for (int i = 0; i < 4; ++i)
            #pragma unroll
            for (int j = 0; j < 4; ++j) { float a = 0.f;
                for (int k = 0; k < 4; ++k) a = fmaf(HP[i][k], Hm[j][k], a);
                S[i][j] = a + ((i == j) ? Rd[i] : 0.f);
                S[i][4 + j] = Hm[i][j]; }
        #pragma unroll
        for (int c = 0; c < 4; ++c) {
            float dinv = 1.f / S[c][c];
            #pragma unroll
            for (int j = 0; j < 8; ++j) S[c][j] *= dinv;
            #pragma unroll
            for (int r2 = 0; r2 < 4; ++r2) {
                if (r2 == c) continue;
                float f = S[r2][c];
                #pragma unroll
                for (int j = 0; j < 8; ++j) S[r2][j] = fmaf(-f, S[c][j], S[r2][j]);
            }
        }
        float K[4][4];
        #pragma unroll
        for (int i = 0; i < 4; ++i)
            #pragma unroll
            for (int k = 0; k < 4; ++k) { float a = 0.f;
                for (int j = 0; j < 4; ++j) a = fmaf(Pp[i][j], S[k][4 + j], a); K[i][k] = a; }
        float sn[4];
        #pragma unroll
        for (int i = 0; i < 4; ++i) { float a = sp[i];
            for (int j = 0; j < 4; ++j) a = fmaf(K[i][j], yr[j], a); sn[i] = a; }
        float IKH[4][4];
        #pragma unroll
        for (int i = 0; i < 4; ++i)
            #pragma unroll
            for (int j = 0; j < 4; ++j) { float a = (i == j) ? 1.f : 0.f;
                for (int k = 0; k < 4; ++k) a = fmaf(-K[i][k], Hm[k][j], a); IKH[i][j] = a; }
        float T1[4][4];
        #pragma unroll
        for (int i = 0; i < 4; ++i)
            #pragma unroll
            for (int j = 0; j < 4; ++j) { float a = 0.f;
                for (int k = 0; k < 4; ++k) a = fmaf(IKH[i][k], Pp[k][j], a); T1[i][j] = a; }
        #pragma unroll
        for (int i = 0; i < 4; ++i)
            #pragma unroll
            for (int j = 0; j < 4; ++j) { float a = 0.f;
                for (int k = 0; k < 4; ++k) a = fmaf(T1[i][k], IKH[j][k], a);
                for (int k = 0; k < 4; ++k) a = fmaf(K[i][k] * Rd[k], K[j][k], a);
                P[i][j] = a; }
        #pragma unroll
        for (int i = 0; i < 4; ++i) { s[i] = sn[i]; pred[(b * Tn + t) * 4 + i] = sn[i]; }
    }
}

// ---------------------------------------------------------------------------
extern "C" void kernel_launch(void* const* d_in, const int* in_sizes, int n_in,
                              void* d_out, int out_size, void* d_ws, size_t ws_size,
                              hipStream_t stream)
{
    const float* frames = (const float*)d_in[0];
    const float* bb     = (const float*)d_in[1];
    const float* cw0 = (const float*)d_in[2],  *cb0 = (const float*)d_in[3];
    const float* g0  = (const float*)d_in[4],  *be0 = (const float*)d_in[5];
    const float* cw1 = (const float*)d_in[6],  *cb1 = (const float*)d_in[7];
    const float* g1  = (const float*)d_in[8],  *be1 = (const float*)d_in[9];
    const float* cw2 = (const float*)d_in[10], *cb2 = (const float*)d_in[11];
    const float* g2  = (const float*)d_in[12], *be2 = (const float*)d_in[13];
    const float* ep_w  = (const float*)d_in[14], *ep_b  = (const float*)d_in[15];
    const float* bp1_w = (const float*)d_in[16], *bp1_b = (const float*)d_in[17];
    const float* bp2_w = (const float*)d_in[18], *bp2_b = (const float*)d_in[19];
    const float* in_proj_w = (const float*)d_in[20];
    const float* c1w = (const float*)d_in[21], *c1b = (const float*)d_in[22];
    const float* x_proj_w = (const float*)d_in[23];
    const float* dt_w = (const float*)d_in[24], *dt_b = (const float*)d_in[25];
    const float* A_log = (const float*)d_in[26], *Dp = (const float*)d_in[27];
    const float* out_proj_w = (const float*)d_in[28];
    const float* h1_w = (const float*)d_in[29], *h1_b = (const float*)d_in[30];
    const float* h2_w = (const float*)d_in[31], *h2_b = (const float*)d_in[32];
    const float* kfF = (const float*)d_in[33], *kfH = (const float*)d_in[34];
    const float* kfq = (const float*)d_in[35], *kfr = (const float*)d_in[36];

    // workspace layout (floats)
    float* ws   = (float*)d_ws;
    float* buf0 = ws;                                   // (8,32,32,32,32)
    float* buf1 = buf0 + (size_t)8 * 32 * 32 * 32 * 32; // (8,32,64,8,8)
    float* buf2 = buf1 + (size_t)8 * 32 * 64 * 8 * 8;   // (8,32,96,2,2)
    float* ub   = buf2 + (size_t)8 * 32 * 96 * 2 * 2;   // (256,256)
    float* xzb  = ub   + 256 * 256;                     // (256,1024)
    float* xsb  = xzb  + 256 * 1024;                    // (256,512)
    float* xdb  = xsb  + 256 * 512;                     // (256,48)
    float* dtbf = xdb  + 256 * 48;                      // (256,512)
    float* yb   = dtbf + 256 * 512;                     // (256,512)
    float* mob  = yb   + 256 * 512;                     // (256,256)
    float* hidb = mob  + 256 * 256;                     // (256,128)
    float* w2b  = hidb + 256 * 128;                     // (27,64? ->) 165888 transposed conv2 weights

    float* kf_out   = (float*)d_out;          // (8,32,4)
    float* meas_out = kf_out + Bn * Tn * 4;   // (8,32,4)

    auto nblk = [](int n) { return dim3((unsigned)((n + 255) / 256)); };

    // CNN backbone
    conv2_wt_kernel<<<nblk(96 * 64 * 27), 256, 0, stream>>>(cw2, w2b);
    conv0_kernel<<<dim3(256 * 4), 256, 0, stream>>>(frames, cw0, cb0, g0, be0, buf0);
    conv1_kernel<<<dim3(256 * 2), 256, 0, stream>>>(buf0, cw1, cb1, g1, be1, buf1);
    conv2_kernel<<<dim3(256), 384, 0, stream>>>(buf1, w2b, cb2, g2, be2, buf2);

    // GAP + embed proj + bbox MLP -> u
    fuse_u_kernel<<<256, 256, 0, stream>>>(buf2, ep_w, ep_b, bb, bp1_w, bp1_b, bp2_w, bp2_b, ub);

    // Mamba block
    linear_kernel<<<nblk(64 * 1024), 256, 0, stream>>>(ub, in_proj_w, nullptr, xzb,
                                                       256, 1024, 256, 0, 64 * 1024);
    conv1d_silu_kernel<<<nblk(256 * 512), 256, 0, stream>>>(xzb, c1w, c1b, xsb);
    linear_kernel<<<nblk(64 * 48), 256, 0, stream>>>(xsb, x_proj_w, nullptr, xdb,
                                                     512, 48, 512, 0, 64 * 48);
    linear_kernel<<<nblk(64 * 512), 256, 0, stream>>>(xdb, dt_w, dt_b, dtbf,
                                                      16, 512, 48, 3, 64 * 512);
    ssm_kernel<<<dim3(256), 256, 0, stream>>>(xdb, dtbf, xsb, xzb, A_log, Dp, yb);
    linear_kernel<<<nblk(64 * 256), 256, 0, stream>>>(yb, out_proj_w, nullptr, mob,
                                                      512, 256, 512, 0, 64 * 256);

    // Measurement head -> meas (second output)
    linear_kernel<<<nblk(64 * 128), 256, 0, stream>>>(mob, h1_w, h1_b, hidb,
                                                      256, 128, 256, 1, 64 * 128);
    linear_kernel<<<nblk(64 * 4), 256, 0, stream>>>(hidb, h2_w, h2_b, meas_out,
                                                    128, 4, 128, 2, 64 * 4);

    // Kalman filter -> kf_pred (first output)
    kf_kernel<<<1, 64, 0, stream>>>(meas_out, bb, kfF, kfH, kfq, kfr, kf_out);
}

// Round 4
// 980.957 us; speedup vs baseline: 4.4662x; 1.0135x over previous
//
#include <hip/hip_runtime.h>
#include <math.h>

// Problem constants
constexpr int Bn = 8, Tn = 32;
constexpr int D_INNER = 512;

// ---------------------------------------------------------------------------
// Stage 0: Conv3D 3ci->32co, 128x128 in, stride(1,2,2), pad 1 + BN + ReLU +
// maxpool(2,2) -> (B,T,32,32,32).
// Grid: (b,t) x 16 row-tiles (2 pooled rows each). Block 256 = 4 waves.
// Wave w computes co [8w, 8w+8); lane = 32 px x 2 pooled rows.
// LDS double-buffered over kt stages: 3 ci planes of 9 rows x 132.
// Weights are wave-uniform -> s_load (scalar pipe), zero VALU cost.
// ---------------------------------------------------------------------------
constexpr int C0_PLANE = 9 * 132;          // 1188
constexpr int C0_FILL  = 3 * C0_PLANE;     // 3564

__global__ __launch_bounds__(256) void conv0_kernel(
    const float* __restrict__ in, const float* __restrict__ w,
    const float* __restrict__ bias, const float* __restrict__ gam,
    const float* __restrict__ bet, float* __restrict__ out)
{
    int tid = threadIdx.x;
    int lane = tid & 63;
    int px = lane & 31, lpy = lane >> 5;                 // 0..31, 0..1
    int wv_ = __builtin_amdgcn_readfirstlane(tid >> 6);  // wave 0..3
    int coBase = wv_ * 8;
    int bt = blockIdx.x >> 4, ytile = blockIdx.x & 15;
    int b = bt >> 5, t = bt & 31;
    int gy0 = 8 * ytile - 1;                             // first staged input row

    __shared__ __align__(16) float lds[2][C0_FILL];      // 2 x 14256 B

    float acc[8][4];
    #pragma unroll
    for (int j = 0; j < 8; ++j)
        #pragma unroll
        for (int q = 0; q < 4; ++q) acc[j][q] = 0.f;

    // ---- fill stage 0 ----
    {
        int ts = t - 1;
        bool tok = (ts >= 0);
        const float* src = in + (size_t)(b * Tn + (tok ? ts : 0)) * 3 * 16384;
        for (int idx = tid; idx < C0_FILL; idx += 256) {
            int ci = idx / C0_PLANE;
            int rem = idx - ci * C0_PLANE;
            int r = rem / 132, c = rem - r * 132;
            int gy = gy0 + r, gx = c - 1;
            float v = 0.f;
            if (tok && gy >= 0 && gy < 128 && gx >= 0 && gx < 128)
                v = src[ci * 16384 + gy * 128 + gx];
            lds[0][idx] = v;
        }
    }
    __syncthreads();

    #pragma unroll
    for (int s = 0; s < 3; ++s) {
        // prefetch next stage into the other buffer
        if (s < 2) {
            int ts = t + s;                               // (s+1) - 1
            bool tok = (ts < Tn);                         // ts >= 0 always here
            const float* src = in + (size_t)(b * Tn + (tok ? ts : 0)) * 3 * 16384;
            float* dst = lds[(s + 1) & 1];
            for (int idx = tid; idx < C0_FILL; idx += 256) {
                int ci = idx / C0_PLANE;
                int rem = idx - ci * C0_PLANE;
                int r = rem / 132, c = rem - r * 132;
                int gy = gy0 + r, gx = c - 1;
                float v = 0.f;
                if (tok && gy >= 0 && gy < 128 && gx >= 0 && gx < 128)
                    v = src[ci * 16384 + gy * 128 + gx];
                dst[idx] = v;
            }
        }
        // compute current stage
        const float* buf = lds[s & 1];
        #pragma unroll
        for (int ci = 0; ci < 3; ++ci) {
            const float* pl = buf + ci * C0_PLANE;
            float p[5][5];
            #pragma unroll
            for (int iy = 0; iy < 5; ++iy) {
                const float* rp = pl + (4 * lpy + iy) * 132 + 4 * px;
                float4 v4 = *(const float4*)rp;
                p[iy][0] = v4.x; p[iy][1] = v4.y; p[iy][2] = v4.z; p[iy][3] = v4.w;
                p[iy][4] = rp[4];
            }
            #pragma unroll
            for (int j = 0; j < 8; ++j) {
                const float* wp = w + ((size_t)((coBase + j) * 3 + ci) * 3 + s) * 9;
                #pragma unroll
                for (int ky = 0; ky < 3; ++ky)
                    #pragma unroll
                    for (int kx = 0; kx < 3; ++kx) {
                        float wvv = wp[ky * 3 + kx];
                        acc[j][0] = fmaf(wvv, p[ky][kx],         acc[j][0]);
                        acc[j][1] = fmaf(wvv, p[ky][kx + 2],     acc[j][1]);
                        acc[j][2] = fmaf(wvv, p[ky + 2][kx],     acc[j][2]);
                        acc[j][3] = fmaf(wvv, p[ky + 2][kx + 2], acc[j][3]);
                    }
            }
        }
        __syncthreads();
    }

    int py = ytile * 2 + lpy;
    #pragma unroll
    for (int j = 0; j < 8; ++j) {
        int co = coBase + j;
        float bi = bias[co], g = gam[co], be = bet[co];
        float a0 = fmaxf(fmaf(g, acc[j][0] + bi, be), 0.f);
        float a1 = fmaxf(fmaf(g, acc[j][1] + bi, be), 0.f);
        float a2 = fmaxf(fmaf(g, acc[j][2] + bi, be), 0.f);
        float a3 = fmaxf(fmaf(g, acc[j][3] + bi, be), 0.f);
        out[(((size_t)bt * 32 + co) * 32 + py) * 32 + px] =
            fmaxf(fmaxf(a0, a1), fmaxf(a2, a3));
    }
}

// ---------------------------------------------------------------------------
// Stage 1: Conv3D 32ci->64co, 32x32 in -> pooled 8x8.
// One block per (b,t), 512 thr = 8 waves; wave w -> co [8w, 8w+8); lane =
// full 8x8 pooled spatial. 12 dbuf stages (3 kt x 4 ci-chunks of 8).
// LDS: 2 x (8 ci x 33 x 36). Weights wave-uniform -> s_load.
// ---------------------------------------------------------------------------
constexpr int C1_PLANE = 33 * 36;          // 1188
constexpr int C1_FILL  = 8 * C1_PLANE;     // 9504

__global__ __launch_bounds__(512) void conv1_kernel(
    const float* __restrict__ in, const float* __restrict__ w,
    const float* __restrict__ bias, const float* __restrict__ gam,
    const float* __restrict__ bet, float* __restrict__ out)
{
    int tid = threadIdx.x;
    int lane = tid & 63;
    int px = lane & 7, py = lane >> 3;                   // 0..7, 0..7
    int wv_ = __builtin_amdgcn_readfirstlane(tid >> 6);  // wave 0..7
    int coBase = wv_ * 8;
    int bt = blockIdx.x;
    int b = bt >> 5, t = bt & 31;

    __shared__ __align__(16) float lds[2][C1_FILL];      // 2 x 38016 B

    float acc[8][4];
    #pragma unroll
    for (int j = 0; j < 8; ++j)
        #pragma unroll
        for (int q = 0; q < 4; ++q) acc[j][q] = 0.f;

    // ---- fill stage 0 (kt=0, chunk=0) ----
    {
        int ts = t - 1;
        bool tok = (ts >= 0);
        const float* src = in + (size_t)(b * Tn + (tok ? ts : 0)) * 32 * 1024;
        for (int idx = tid; idx < C1_FILL; idx += 512) {
            int ci = idx / C1_PLANE;
            int rem = idx - ci * C1_PLANE;
            int r = rem / 36, c = rem - r * 36;
            int gy = r - 1, gx = c - 1;
            float v = 0.f;
            if (tok && gy >= 0 && gy < 32 && gx >= 0 && gx < 32)
                v = src[ci * 1024 + gy * 32 + gx];
            lds[0][idx] = v;
        }
    }
    __syncthreads();

    for (int s = 0; s < 12; ++s) {
        if (s < 11) {
            int sn = s + 1;
            int kt = sn >> 2, chunk = sn & 3;
            int ts = t + kt - 1;
            bool tok = (ts >= 0 && ts < Tn);
            const float* src = in + ((size_t)(b * Tn + (tok ? ts : 0)) * 32 + chunk * 8) * 1024;
            float* dst = lds[sn & 1];
            for (int idx = tid; idx < C1_FILL; idx += 512) {
                int ci = idx / C1_PLANE;
                int rem = idx - ci * C1_PLANE;
                int r = rem / 36, c = rem - r * 36;
                int gy = r - 1, gx = c - 1;
                float v = 0.f;
                if (tok && gy >= 0 && gy < 32 && gx >= 0 && gx < 32)
                    v = src[ci * 1024 + gy * 32 + gx];
                dst[idx] = v;
            }
        }
        {
            int kt = s >> 2, chunk = s & 3;
            const float* buf = lds[s & 1];
            #pragma unroll
            for (int ci8 = 0; ci8 < 8; ++ci8) {
                const float* pl = buf + ci8 * C1_PLANE;
                float p[5][5];
                #pragma unroll
                for (int iy = 0; iy < 5; ++iy) {
                    const float* rp = pl + (4 * py + iy) * 36 + 4 * px;
                    float4 v4 = *(const float4*)rp;
                    p[iy][0] = v4.x; p[iy][1] = v4.y; p[iy][2] = v4.z; p[iy][3] = v4.w;
                    p[iy][4] = rp[4];
                }
                #pragma unroll
                for (int j = 0; j < 8; ++j) {
                    const float* wp = w + ((size_t)((coBase + j) * 32 + chunk * 8 + ci8) * 3 + kt) * 9;
                    #pragma unroll
                    for (int ky = 0; ky < 3; ++ky)
                        #pragma unroll
                        for (int kx = 0; kx < 3; ++kx) {
                            float wvv = wp[ky * 3 + kx];
                            acc[j][0] = fmaf(wvv, p[ky][kx],         acc[j][0]);
                            acc[j][1] = fmaf(wvv, p[ky][kx + 2],     acc[j][1]);
                            acc[j][2] = fmaf(wvv, p[ky + 2][kx],     acc[j][2]);
                            acc[j][3] = fmaf(wvv, p[ky + 2][kx + 2], acc[j][3]);
                        }
                }
            }
        }
        __syncthreads();
    }

    #pragma unroll
    for (int j = 0; j < 8; ++j) {
        int co = coBase + j;
        float bi = bias[co], g = gam[co], be = bet[co];
        float a0 = fmaxf(fmaf(g, acc[j][0] + bi, be), 0.f);
        float a1 = fmaxf(fmaf(g, acc[j][1] + bi, be), 0.f);
        float a2 = fmaxf(fmaf(g, acc[j][2] + bi, be), 0.f);
        float a3 = fmaxf(fmaf(g, acc[j][3] + bi, be), 0.f);
        out[((size_t)bt * 64 + co) * 64 + py * 8 + px] =
            fmaxf(fmaxf(a0, a1), fmaxf(a2, a3));
    }
}

// ---------------------------------------------------------------------------
// One-time weight transpose for stage 2: w (96,64,3,9) -> w2[kt][ci][k9][co].
// ---------------------------------------------------------------------------
__global__ void conv2_wt_kernel(const float* __restrict__ w, float* __restrict__ w2)
{
    int idx = blockIdx.x * blockDim.x + threadIdx.x;
    if (idx >= 96 * 64 * 27) return;
    int co = idx % 96; int r = idx / 96;
    int k9 = r % 9;    r /= 9;
    int ci = r % 64;   int kt = r / 64;
    w2[idx] = w[(((size_t)co * 64 + ci) * 3 + kt) * 9 + k9];
}

// ---------------------------------------------------------------------------
// Stage 2: Conv3D 64ci->96co on 8x8 -> pooled 2x2. LDS-staged.
// ---------------------------------------------------------------------------
__global__ __launch_bounds__(384) void conv2_kernel(
    const float* __restrict__ in, const float* __restrict__ w2,
    const float* __restrict__ bias, const float* __restrict__ gam,
    const float* __restrict__ bet, float* __restrict__ out)
{
    int tid = threadIdx.x;                 // 0..383
    int co = tid >> 2, quad = tid & 3;     // co 0..95
    int qy = quad >> 1, qx = quad & 1;
    int bt = blockIdx.x;
    int b = bt >> 5, t = bt & 31;

    __shared__ __align__(16) float lin[8 * 120];
    __shared__ __align__(16) float lw[8 * 9 * 96];

    float acc[4] = {0.f, 0.f, 0.f, 0.f};

    for (int kt = 0; kt < 3; ++kt) {
        int ts = t + kt - 1;
        if (ts < 0 || ts >= Tn) continue;          // block-uniform
        for (int chunk = 0; chunk < 8; ++chunk) {
            __syncthreads();
            for (int idx = tid; idx < 8 * 120; idx += 384) {
                int ci  = idx / 120;
                int rem = idx - ci * 120;
                int r = rem / 12, c = rem - r * 12;
                int gy = r - 1, gx = c - 1;
                float v = 0.f;
                if (gy >= 0 && gy < 8 && gx >= 0 && gx < 8)
                    v = in[((size_t)(b * Tn + ts) * 64 + chunk * 8 + ci) * 64 + gy * 8 + gx];
                lin[idx] = v;
            }
            const float* wsrc = w2 + ((size_t)(kt * 64 + chunk * 8) * 9) * 96;
            for (int idx = tid; idx < 6912; idx += 384) lw[idx] = wsrc[idx];
            __syncthreads();

            #pragma unroll
            for (int ci8 = 0; ci8 < 8; ++ci8) {
                const float* pl = lin + ci8 * 120;
                float p[5][5];
                #pragma unroll
                for (int iy = 0; iy < 5; ++iy) {
                    const float* rp = pl + (4 * qy + iy) * 12 + 4 * qx;
                    float4 v4 = *(const float4*)rp;
                    p[iy][0] = v4.x; p[iy][1] = v4.y; p[iy][2] = v4.z; p[iy][3] = v4.w;
                    p[iy][4] = rp[4];
                }
                const float* wp = lw + ci8 * 9 * 96 + co;
                #pragma unroll
                for (int ky = 0; ky < 3; ++ky)
                    #pragma unroll
                    for (int kx = 0; kx < 3; ++kx) {
                        float wv = wp[(ky * 3 + kx) * 96];
                        acc[0] = fmaf(wv, p[ky][kx],         acc[0]);
                        acc[1] = fmaf(wv, p[ky][kx + 2],     acc[1]);
                        acc[2] = fmaf(wv, p[ky + 2][kx],     acc[2]);
                        acc[3] = fmaf(wv, p[ky + 2][kx + 2], acc[3]);
                    }
            }
        }
    }
    float bi = bias[co], g = gam[co], be = bet[co];
    float a0 = fmaxf(fmaf(g, acc[0] + bi, be), 0.f);
    float a1 = fmaxf(fmaf(g, acc[1] + bi, be), 0.f);
    float a2 = fmaxf(fmaf(g, acc[2] + bi, be), 0.f);
    float a3 = fmaxf(fmaf(g, acc[3] + bi, be), 0.f);
    out[((size_t)bt * 96 + co) * 4 + qy * 2 + qx] = fmaxf(fmaxf(a0, a1), fmaxf(a2, a3));
}

// ---------------------------------------------------------------------------
// Fused: GAP(2x2) -> ep projection, bbox MLP, u = ff + bf.
// ---------------------------------------------------------------------------
__global__ void fuse_u_kernel(const float* __restrict__ buf2, const float* __restrict__ ep_w,
                              const float* __restrict__ ep_b, const float* __restrict__ bb,
                              const float* __restrict__ bp1_w, const float* __restrict__ bp1_b,
                              const float* __restrict__ bp2_w, const float* __restrict__ bp2_b,
                              float* __restrict__ u)
{
    int bt = blockIdx.x;
    int m  = threadIdx.x;
    __shared__ float hs[64];
    __shared__ float gap[96];
    if (m < 64) {
        float a = bp1_b[m];
        #pragma unroll
        for (int k = 0; k < 4; ++k) a = fmaf(bp1_w[m * 4 + k], bb[bt * 4 + k], a);
        hs[m] = fmaxf(a, 0.f);
    } else if (m < 160) {
        int c = m - 64;
        const float* p = buf2 + ((size_t)bt * 96 + c) * 4;
        gap[c] = 0.25f * (p[0] + p[1] + p[2] + p[3]);
    }
    __syncthreads();
    float ff = ep_b[m];
    for (int c = 0; c < 96; ++c) ff = fmaf(gap[c], ep_w[m * 96 + c], ff);
    float bfv = bp2_b[m];
    for (int j = 0; j < 64; ++j) bfv = fmaf(hs[j], bp2_w[m * 64 + j], bfv);
    u[(size_t)bt * 256 + m] = ff + bfv;
}

// ---------------------------------------------------------------------------
// Linear with 4-token m-tiling.
// ---------------------------------------------------------------------------
__global__ void linear_kernel(const float* __restrict__ in, const float* __restrict__ w,
                              const float* __restrict__ bias, float* __restrict__ out,
                              int K, int N, int ldin, int act, int total)
{
    int idx = blockIdx.x * blockDim.x + threadIdx.x;
    if (idx >= total) return;
    int o = idx % N; int m0 = (idx / N) * 4;
    const float4* wp = (const float4*)(w + (size_t)o * K);
    const float4* i0 = (const float4*)(in + (size_t)(m0 + 0) * ldin);
    const float4* i1 = (const float4*)(in + (size_t)(m0 + 1) * ldin);
    const float4* i2 = (const float4*)(in + (size_t)(m0 + 2) * ldin);
    const float4* i3 = (const float4*)(in + (size_t)(m0 + 3) * ldin);
    float a0 = 0.f, a1 = 0.f, a2 = 0.f, a3 = 0.f;
    int K4 = K >> 2;
    for (int k = 0; k < K4; ++k) {
        float4 wv = wp[k];
        float4 x0 = i0[k], x1 = i1[k], x2 = i2[k], x3 = i3[k];
        a0 = fmaf(x0.x, wv.x, a0); a0 = fmaf(x0.y, wv.y, a0);
        a0 = fmaf(x0.z, wv.z, a0); a0 = fmaf(x0.w, wv.w, a0);
        a1 = fmaf(x1.x, wv.x, a1); a1 = fmaf(x1.y, wv.y, a1);
        a1 = fmaf(x1.z, wv.z, a1); a1 = fmaf(x1.w, wv.w, a1);
        a2 = fmaf(x2.x, wv.x, a2); a2 = fmaf(x2.y, wv.y, a2);
        a2 = fmaf(x2.z, wv.z, a2); a2 = fmaf(x2.w, wv.w, a2);
        a3 = fmaf(x3.x, wv.x, a3); a3 = fmaf(x3.y, wv.y, a3);
        a3 = fmaf(x3.z, wv.z, a3); a3 = fmaf(x3.w, wv.w, a3);
    }
    float av[4] = {a0, a1, a2, a3};
    float bv = bias ? bias[o] : 0.f;
    #pragma unroll
    for (int r = 0; r < 4; ++r) {
        float a = av[r] + bv;
        if (act == 1)      a = fmaxf(a, 0.f);
        else if (act == 2) a = 1.f / (1.f + expf(-a));
        else if (act == 3) a = (a > 20.f) ? a : log1pf(expf(a));
        out[(size_t)(m0 + r) * N + o] = a;
    }
}

// ---------------------------------------------------------------------------
// Causal depthwise conv1d (k=4) + SiLU.
// ---------------------------------------------------------------------------
__global__ void conv1d_silu_kernel(const float* __restrict__ xz, const float* __restrict__ cw,
                                   const float* __restrict__ cb, float* __restrict__ xs)
{
    int idx = blockIdx.x * blockDim.x + threadIdx.x;
    if (idx >= Bn * Tn * D_INNER) return;
    int d = idx % D_INNER; int r = idx / D_INNER;
    int t = r % Tn; int b = r / Tn;
    float acc = cb[d];
    #pragma unroll
    for (int k = 0; k < 4; ++k) {
        int ts = t - 3 + k;
        if (ts >= 0) acc = fmaf(cw[d * 4 + k], xz[(size_t)(b * Tn + ts) * 1024 + d], acc);
    }
    xs[idx] = acc / (1.f + expf(-acc));
}

// ---------------------------------------------------------------------------
// Wave-parallel selective scan.
// ---------------------------------------------------------------------------
__global__ __launch_bounds__(256) void ssm_kernel(
    const float* __restrict__ xdbl, const float* __restrict__ dtb,
    const float* __restrict__ xs, const float* __restrict__ xz,
    const float* __restrict__ A_log, const float* __restrict__ Dp,
    float* __restrict__ y)
{
    int tid = threadIdx.x;
    int lane = tid & 63;
    int s = lane & 15, dsub = lane >> 4;
    int gid = blockIdx.x * 4 + (tid >> 6);
    int b = gid >> 7;
    int d = ((gid & 127) << 2) + dsub;

    float A = -expf(A_log[d * 16 + s]);
    float Dv = Dp[d];
    float h = 0.f;
    for (int t = 0; t < Tn; ++t) {
        int bt = b * Tn + t;
        float dtv = dtb[(size_t)bt * 512 + d];
        float xv  = xs [(size_t)bt * 512 + d];
        float Bs  = xdbl[(size_t)bt * 48 + 16 + s];
        float Cs  = xdbl[(size_t)bt * 48 + 32 + s];
        float dA = expf(dtv * A);
        h = fmaf(dA, h, dtv * Bs * xv);
        float c = h * Cs;
        c += __shfl_xor(c, 8, 16);
        c += __shfl_xor(c, 4, 16);
        c += __shfl_xor(c, 2, 16);
        c += __shfl_xor(c, 1, 16);
        if (s == 0) {
            float zv = xz[(size_t)bt * 1024 + 512 + d];
            float sig = 1.f / (1.f + expf(-zv));
            y[(size_t)bt * 512 + d] = (c + Dv * xv) * (zv * sig);
        }
    }
}

// ---------------------------------------------------------------------------
// Kalman filter scan, one thread per batch.
// ---------------------------------------------------------------------------
__global__ void kf_kernel(const float* __restrict__ meas, const float* __restrict__ bb,
                          const float* __restrict__ Fin, const float* __restrict__ Hmin,
                          const float* __restrict__ lq, const float* __restrict__ lr,
                          float* __restrict__ pred)
{
    int b = blockIdx.x * blockDim.x + threadIdx.x;
    if (b >= Bn) return;
    float F[4][4], Hm[4][4], Qd[4], Rd[4];
    #pragma unroll
    for (int i = 0; i < 4; ++i) {
        Qd[i] = expf(lq[i]) + 1e-6f;
        Rd[i] = expf(lr[i]) + 1e-6f;
        #pragma unroll
        for (int j = 0; j < 4; ++j) { F[i][j] = Fin[i * 4 + j]; Hm[i][j] = Hmin[i * 4 + j]; }
    }
    float s[4], P[4][4];
    #pragma unroll
    for (int i = 0; i < 4; ++i) {
        s[i] = bb[(b * Tn) * 4 + i];
        #pragma unroll
        for (int j = 0; j < 4; ++j) P[i][j] = (i == j) ? 0.01f : 0.f;
    }
    for (int t = 0; t < Tn; ++t) {
        float mv[4];
        #pragma unroll
        for (int i = 0; i < 4; ++i) mv[i] = meas[(b * Tn + t) * 4 + i];
        float sp[4];
        #pragma unroll
        for (int i = 0; i < 4; ++i) { float a = 0.f;
            #pragma unroll
            for (int j = 0; j < 4; ++j) a = fmaf(F[i][j], s[j], a); sp[i] = a; }
        float FP[4][4];
        #pragma unroll
        for (int i = 0; i < 4; ++i)
            #pragma unroll
            for (int j = 0; j < 4; ++j) { float a = 0.f;
                for (int k = 0; k < 4; ++k) a = fmaf(F[i][k], P[k][j], a); FP[i][j] = a; }
        float Pp[4][4];
        #pragma unroll
        for (int i = 0; i < 4; ++i)
            #pragma unroll
            for (int j = 0; j < 4; ++j) { float a = 0.f;
                for (int k = 0; k < 4; ++k) a = fmaf(FP[i][k], F[j][k], a);
                Pp[i][j] = a + ((i == j) ? Qd[i] : 0.f); }
        float yr[4];
        #pragma unroll
        for (int i = 0; i < 4; ++i) { float a = 0.f;
            for (int j = 0; j < 4; ++j) a = fmaf(Hm[i][j], sp[j], a); yr[i] = mv[i] - a; }
        float HP[4][4];
        #pragma unroll
        for (int i = 0; i < 4; ++i)
            #pragma unroll
            for (int j = 0; j < 4; ++j) { float a = 0.f;
                for (int k = 0; k < 4; ++k) a = fmaf(Hm[i][k], Pp[k][j], a); HP[i][j] = a; }
        float S[4][8];
        #pragma unroll
        for (int i = 0; i < 4; ++i)
            #pragma unroll
            for (int j = 0; j < 4; ++j) { float a = 0.f;
                for (int k = 0; k < 4; ++k) a = fmaf(HP[i][k], Hm[j][k], a);
                S[i][j] = a + ((i == j) ? Rd[i] : 0.f);
                S[i][4 + j] = Hm[i][j]; }
        #pragma unroll
        for (int c = 0; c < 4; ++c) {
            float dinv = 1.f / S[c][c];
            #pragma unroll
            for (int j = 0; j < 8; ++j) S[c][j] *= dinv;
            #pragma unroll
            for (int r2 = 0; r2 < 4; ++r2) {
                if (r2 == c) continue;
                float f = S[r2][c];
                #pragma unroll
                for (int j = 0; j < 8; ++j) S[r2][j] = fmaf(-f, S[c][j], S[r2][j]);
            }
        }
        float K[4][4];
        #pragma unroll
        for (int i = 0; i < 4; ++i)
            #pragma unroll
            for (int k = 0; k < 4; ++k) { float a = 0.f;
                for (int j = 0; j < 4; ++j) a = fmaf(Pp[i][j], S[k][4 + j], a); K[i][k] = a; }
        float sn[4];
        #pragma unroll
        for (int i = 0; i < 4; ++i) { float a = sp[i];
            for (int j = 0; j < 4; ++j) a = fmaf(K[i][j], yr[j], a); sn[i] = a; }
        float IKH[4][4];
        #pragma unroll
        for (int i = 0; i < 4; ++i)
            #pragma unroll
            for (int j = 0; j < 4; ++j) { float a = (i == j) ? 1.f : 0.f;
                for (int k = 0; k < 4; ++k) a = fmaf(-K[i][k], Hm[k][j], a); IKH[i][j] = a; }
        float T1[4][4];
        #pragma unroll
        for (int i = 0; i < 4; ++i)
            #pragma unroll
            for (int j = 0; j < 4; ++j) { float a = 0.f;
                for (int k = 0; k < 4; ++k) a = fmaf(IKH[i][k], Pp[k][j], a); T1[i][j] = a; }
        #pragma unroll
        for (int i = 0; i < 4; ++i)
            #pragma unroll
            for (int j = 0; j < 4; ++j) { float a = 0.f;
                for (int k = 0; k < 4; ++k) a = fmaf(T1[i][k], IKH[j][k], a);
                for (int k = 0; k < 4; ++k) a = fmaf(K[i][k] * Rd[k], K[j][k], a);
                P[i][j] = a; }
        #pragma unroll
        for (int i = 0; i < 4; ++i) { s[i] = sn[i]; pred[(b * Tn + t) * 4 + i] = sn[i]; }
    }
}

// ---------------------------------------------------------------------------
extern "C" void kernel_launch(void* const* d_in, const int* in_sizes, int n_in,
                              void* d_out, int out_size, void* d_ws, size_t ws_size,
                              hipStream_t stream)
{
    const float* frames = (const float*)d_in[0];
    const float* bb     = (const float*)d_in[1];
    const float* cw0 = (const float*)d_in[2],  *cb0 = (const float*)d_in[3];
    const float* g0  = (const float*)d_in[4],  *be0 = (const float*)d_in[5];
    const float* cw1 = (const float*)d_in[6],  *cb1 = (const float*)d_in[7];
    const float* g1  = (const float*)d_in[8],  *be1 = (const float*)d_in[9];
    const float* cw2 = (const float*)d_in[10], *cb2 = (const float*)d_in[11];
    const float* g2  = (const float*)d_in[12], *be2 = (const float*)d_in[13];
    const float* ep_w  = (const float*)d_in[14], *ep_b  = (const float*)d_in[15];
    const float* bp1_w = (const float*)d_in[16], *bp1_b = (const float*)d_in[17];
    const float* bp2_w = (const float*)d_in[18], *bp2_b = (const float*)d_in[19];
    const float* in_proj_w = (const float*)d_in[20];
    const float* c1w = (const float*)d_in[21], *c1b = (const float*)d_in[22];
    const float* x_proj_w = (const float*)d_in[23];
    const float* dt_w = (const float*)d_in[24], *dt_b = (const float*)d_in[25];
    const float* A_log = (const float*)d_in[26], *Dp = (const float*)d_in[27];
    const float* out_proj_w = (const float*)d_in[28];
    const float* h1_w = (const float*)d_in[29], *h1_b = (const float*)d_in[30];
    const float* h2_w = (const float*)d_in[31], *h2_b = (const float*)d_in[32];
    const float* kfF = (const float*)d_in[33], *kfH = (const float*)d_in[34];
    const float* kfq = (const float*)d_in[35], *kfr = (const float*)d_in[36];

    // workspace layout (floats)
    float* ws   = (float*)d_ws;
    float* buf0 = ws;                                   // (8,32,32,32,32)
    float* buf1 = buf0 + (size_t)8 * 32 * 32 * 32 * 32; // (8,32,64,8,8)
    float* buf2 = buf1 + (size_t)8 * 32 * 64 * 8 * 8;   // (8,32,96,2,2)
    float* ub   = buf2 + (size_t)8 * 32 * 96 * 2 * 2;   // (256,256)
    float* xzb  = ub   + 256 * 256;                     // (256,1024)
    float* xsb  = xzb  + 256 * 1024;                    // (256,512)
    float* xdb  = xsb  + 256 * 512;                     // (256,48)
    float* dtbf = xdb  + 256 * 48;                      // (256,512)
    float* yb   = dtbf + 256 * 512;                     // (256,512)
    float* mob  = yb   + 256 * 512;                     // (256,256)
    float* hidb = mob  + 256 * 256;                     // (256,128)
    float* w2b  = hidb + 256 * 128;                     // 165888 transposed conv2 weights

    float* kf_out   = (float*)d_out;          // (8,32,4)
    float* meas_out = kf_out + Bn * Tn * 4;   // (8,32,4)

    auto nblk = [](int n) { return dim3((unsigned)((n + 255) / 256)); };

    // CNN backbone
    conv2_wt_kernel<<<nblk(96 * 64 * 27), 256, 0, stream>>>(cw2, w2b);
    conv0_kernel<<<dim3(256 * 16), 256, 0, stream>>>(frames, cw0, cb0, g0, be0, buf0);
    conv1_kernel<<<dim3(256), 512, 0, stream>>>(buf0, cw1, cb1, g1, be1, buf1);
    conv2_kernel<<<dim3(256), 384, 0, stream>>>(buf1, w2b, cb2, g2, be2, buf2);

    // GAP + embed proj + bbox MLP -> u
    fuse_u_kernel<<<256, 256, 0, stream>>>(buf2, ep_w, ep_b, bb, bp1_w, bp1_b, bp2_w, bp2_b, ub);

    // Mamba block
    linear_kernel<<<nblk(64 * 1024), 256, 0, stream>>>(ub, in_proj_w, nullptr, xzb,
                                                       256, 1024, 256, 0, 64 * 1024);
    conv1d_silu_kernel<<<nblk(256 * 512), 256, 0, stream>>>(xzb, c1w, c1b, xsb);
    linear_kernel<<<nblk(64 * 48), 256, 0, stream>>>(xsb, x_proj_w, nullptr, xdb,
                                                     512, 48, 512, 0, 64 * 48);
    linear_kernel<<<nblk(64 * 512), 256, 0, stream>>>(xdb, dt_w, dt_b, dtbf,
                                                      16, 512, 48, 3, 64 * 512);
    ssm_kernel<<<dim3(256), 256, 0, stream>>>(xdb, dtbf, xsb, xzb, A_log, Dp, yb);
    linear_kernel<<<nblk(64 * 256), 256, 0, stream>>>(yb, out_proj_w, nullptr, mob,
                                                      512, 256, 512, 0, 64 * 256);

    // Measurement head -> meas (second output)
    linear_kernel<<<nblk(64 * 128), 256, 0, stream>>>(mob, h1_w, h1_b, hidb,
                                                      256, 128, 256, 1, 64 * 128);
    linear_kernel<<<nblk(64 * 4), 256, 0, stream>>>(hidb, h2_w, h2_b, meas_out,
                                                    128, 4, 128, 2, 64 * 4);

    // Kalman filter -> kf_pred (first output)
    kf_kernel<<<1, 64, 0, stream>>>(meas_out, bb, kfF, kfH, kfq, kfr, kf_out);
}

// Round 5
// 779.891 us; speedup vs baseline: 5.6177x; 1.2578x over previous
//
#include <hip/hip_runtime.h>
#include <math.h>

// Problem constants
constexpr int Bn = 8, Tn = 32;
constexpr int D_INNER = 512;

typedef __attribute__((ext_vector_type(8))) short short8;   // 8 bf16
typedef __attribute__((ext_vector_type(4))) float f32x4;

__device__ inline unsigned short f2bf(float x) {
    unsigned int u = __float_as_uint(x);
    unsigned int r = (u + 0x7FFF + ((u >> 16) & 1)) >> 16;  // RNE
    return (unsigned short)r;
}

// ---------------------------------------------------------------------------
// Stage 0: Conv3D 3ci->32co, 128x128 in, stride(1,2,2), pad 1 + BN + ReLU +
// maxpool(2,2) -> (B,T,32,32,32). LDS-staged fp32 (unchanged this round).
// ---------------------------------------------------------------------------
constexpr int C0_PLANE = 9 * 132;          // 1188
constexpr int C0_FILL  = 3 * C0_PLANE;     // 3564

__global__ __launch_bounds__(256) void conv0_kernel(
    const float* __restrict__ in, const float* __restrict__ w,
    const float* __restrict__ bias, const float* __restrict__ gam,
    const float* __restrict__ bet, float* __restrict__ out)
{
    int tid = threadIdx.x;
    int lane = tid & 63;
    int px = lane & 31, lpy = lane >> 5;                 // 0..31, 0..1
    int wv_ = __builtin_amdgcn_readfirstlane(tid >> 6);  // wave 0..3
    int coBase = wv_ * 8;
    int bt = blockIdx.x >> 4, ytile = blockIdx.x & 15;
    int b = bt >> 5, t = bt & 31;
    int gy0 = 8 * ytile - 1;

    __shared__ __align__(16) float lds[2][C0_FILL];

    float acc[8][4];
    #pragma unroll
    for (int j = 0; j < 8; ++j)
        #pragma unroll
        for (int q = 0; q < 4; ++q) acc[j][q] = 0.f;

    {
        int ts = t - 1;
        bool tok = (ts >= 0);
        const float* src = in + (size_t)(b * Tn + (tok ? ts : 0)) * 3 * 16384;
        for (int idx = tid; idx < C0_FILL; idx += 256) {
            int ci = idx / C0_PLANE;
            int rem = idx - ci * C0_PLANE;
            int r = rem / 132, c = rem - r * 132;
            int gy = gy0 + r, gx = c - 1;
            float v = 0.f;
            if (tok && gy >= 0 && gy < 128 && gx >= 0 && gx < 128)
                v = src[ci * 16384 + gy * 128 + gx];
            lds[0][idx] = v;
        }
    }
    __syncthreads();

    #pragma unroll
    for (int s = 0; s < 3; ++s) {
        if (s < 2) {
            int ts = t + s;
            bool tok = (ts < Tn);
            const float* src = in + (size_t)(b * Tn + (tok ? ts : 0)) * 3 * 16384;
            float* dst = lds[(s + 1) & 1];
            for (int idx = tid; idx < C0_FILL; idx += 256) {
                int ci = idx / C0_PLANE;
                int rem = idx - ci * C0_PLANE;
                int r = rem / 132, c = rem - r * 132;
                int gy = gy0 + r, gx = c - 1;
                float v = 0.f;
                if (tok && gy >= 0 && gy < 128 && gx >= 0 && gx < 128)
                    v = src[ci * 16384 + gy * 128 + gx];
                dst[idx] = v;
            }
        }
        const float* buf = lds[s & 1];
        #pragma unroll
        for (int ci = 0; ci < 3; ++ci) {
            const float* pl = buf + ci * C0_PLANE;
            float p[5][5];
            #pragma unroll
            for (int iy = 0; iy < 5; ++iy) {
                const float* rp = pl + (4 * lpy + iy) * 132 + 4 * px;
                float4 v4 = *(const float4*)rp;
                p[iy][0] = v4.x; p[iy][1] = v4.y; p[iy][2] = v4.z; p[iy][3] = v4.w;
                p[iy][4] = rp[4];
            }
            #pragma unroll
            for (int j = 0; j < 8; ++j) {
                const float* wp = w + ((size_t)((coBase + j) * 3 + ci) * 3 + s) * 9;
                #pragma unroll
                for (int ky = 0; ky < 3; ++ky)
                    #pragma unroll
                    for (int kx = 0; kx < 3; ++kx) {
                        float wvv = wp[ky * 3 + kx];
                        acc[j][0] = fmaf(wvv, p[ky][kx],         acc[j][0]);
                        acc[j][1] = fmaf(wvv, p[ky][kx + 2],     acc[j][1]);
                        acc[j][2] = fmaf(wvv, p[ky + 2][kx],     acc[j][2]);
                        acc[j][3] = fmaf(wvv, p[ky + 2][kx + 2], acc[j][3]);
                    }
            }
        }
        __syncthreads();
    }

    int py = ytile * 2 + lpy;
    #pragma unroll
    for (int j = 0; j < 8; ++j) {
        int co = coBase + j;
        float bi = bias[co], g = gam[co], be = bet[co];
        float a0 = fmaxf(fmaf(g, acc[j][0] + bi, be), 0.f);
        float a1 = fmaxf(fmaf(g, acc[j][1] + bi, be), 0.f);
        float a2 = fmaxf(fmaf(g, acc[j][2] + bi, be), 0.f);
        float a3 = fmaxf(fmaf(g, acc[j][3] + bi, be), 0.f);
        out[(((size_t)bt * 32 + co) * 32 + py) * 32 + px] =
            fmaxf(fmaxf(a0, a1), fmaxf(a2, a3));
    }
}

// ---------------------------------------------------------------------------
// conv1 weight prep: w (64,32,3,3,3) fp32 -> bf16 [kt][k9][co][ci-swizzled].
// Swizzle: ci-group g stored at sub-block (g ^ (co&3)) so B-frag reads are a
// single ds_read_b128 with ~2-way bank aliasing.
// ---------------------------------------------------------------------------
__global__ void conv1_wt_kernel(const float* __restrict__ w, unsigned short* __restrict__ w1b)
{
    int d = blockIdx.x * blockDim.x + threadIdx.x;
    if (d >= 3 * 9 * 64 * 32) return;
    int sl = d & 7;
    int sg = (d >> 3) & 3;
    int co = (d >> 5) & 63;
    int r  = d >> 11;                  // kt*9 + k9
    int k9 = r % 9, kt = r / 9;
    int g  = sg ^ (co & 3);
    int ci = g * 8 + sl;
    w1b[d] = f2bf(w[((size_t)(co * 32 + ci) * 3 + kt) * 9 + k9]);
}

// ---------------------------------------------------------------------------
// Stage 1 as MFMA implicit GEMM (bf16 in, fp32 acc).
// One block per (b,t), 512 thr = 8 waves. Per (b,t): C[M=256][N=64], M = conv
// positions (oy,ox) of the 16x16 pre-pool output, K = 864 = 27 k-steps
// (kt,ky,kx) of K=32 (ci). Wave w: oy in {2w, 2w+1} (2 M-tiles), all co
// (4 N-tiles), acc[2][4]. Maxpool(2,2): ox pairs = adjacent acc regs,
// oy pairs = the two M-tiles -> fully in-register.
// LDS per kt: S = input 32ci x 33y x 34x bf16 at [y][x][ci] with XOR-swizzled
// 16B ci-blocks (A-frag = 1 ds_read_b128); W = 9*64*32 bf16 weights.
// ---------------------------------------------------------------------------
__global__ __launch_bounds__(512) void conv1_kernel(
    const float* __restrict__ in, const unsigned short* __restrict__ w1b,
    const float* __restrict__ bias, const float* __restrict__ gam,
    const float* __restrict__ bet, float* __restrict__ out)
{
    int tid  = threadIdx.x;
    int lane = tid & 63;
    int wv   = tid >> 6;               // wave 0..7
    int q    = lane >> 4;              // 0..3
    int l15  = lane & 15;
    int bt = blockIdx.x;
    int b = bt >> 5, t = bt & 31;

    __shared__ __align__(16) unsigned short S[33 * 34 * 32];   // 71808 B
    __shared__ __align__(16) unsigned short W[9 * 64 * 32];    // 36864 B

    f32x4 acc[2][4];
    #pragma unroll
    for (int mt = 0; mt < 2; ++mt)
        #pragma unroll
        for (int nt = 0; nt < 4; ++nt) acc[mt][nt] = (f32x4)0.f;

    for (int kt = 0; kt < 3; ++kt) {
        int ts = t + kt - 1;
        if (ts < 0 || ts >= Tn) continue;          // block-uniform
        __syncthreads();                           // S/W reuse guard
        // ---- stage input plane (fp32 -> bf16, transposed+swizzled) ----
        const float* src = in + (size_t)(b * Tn + ts) * 32 * 1024;
        for (int e = tid; e < 32 * 33 * 34; e += 512) {
            int ci  = e / (33 * 34);
            int rem = e - ci * (33 * 34);
            int ys = rem / 34, xs = rem - ys * 34;
            int y = ys - 1, x = xs - 1;
            float v = (y >= 0 && x >= 0 && x < 32) ? src[ci * 1024 + y * 32 + x] : 0.f;
            int blk = (ys * 34 + xs) * 4 + ((ci >> 3) ^ ((xs >> 1) & 3));
            S[blk * 8 + (ci & 7)] = f2bf(v);
        }
        // ---- stage weights (contiguous bf16 copy) ----
        {
            const uint4* wsrc = (const uint4*)(w1b + kt * 18432);
            uint4* wdst = (uint4*)W;
            for (int e = tid; e < 2304; e += 512) wdst[e] = wsrc[e];
        }
        __syncthreads();

        for (int k9 = 0; k9 < 9; ++k9) {
            int ky = k9 / 3, kx = k9 - ky * 3;
            short8 bf[4];
            #pragma unroll
            for (int nt = 0; nt < 4; ++nt) {
                int co = nt * 16 + l15;
                int blk = (k9 * 64 + co) * 4 + (q ^ (co & 3));
                bf[nt] = *(const short8*)(W + blk * 8);
            }
            short8 af[2];
            #pragma unroll
            for (int mt = 0; mt < 2; ++mt) {
                int oy = 2 * wv + mt;
                int ys = 2 * oy + ky;
                int xs = 2 * l15 + kx;
                int blk = (ys * 34 + xs) * 4 + (q ^ ((xs >> 1) & 3));
                af[mt] = *(const short8*)(S + blk * 8);
            }
            #pragma unroll
            for (int mt = 0; mt < 2; ++mt)
                #pragma unroll
                for (int nt = 0; nt < 4; ++nt)
                    acc[mt][nt] = __builtin_amdgcn_mfma_f32_16x16x32_bf16(
                        af[mt], bf[nt], acc[mt][nt], 0, 0, 0);
        }
    }

    // ---- epilogue: BN + ReLU + maxpool(2,2), all in-register ----
    // D mapping (16x16x32): col = lane&15 = n(co), row = q*4 + reg = m(ox).
    #pragma unroll
    for (int nt = 0; nt < 4; ++nt) {
        int co = nt * 16 + l15;
        float bi = bias[co], g = gam[co], be = bet[co];
        #pragma unroll
        for (int j = 0; j < 2; ++j) {
            float m0 = fmaxf(fmaf(g, acc[0][nt][2 * j]     + bi, be), 0.f);
            float m1 = fmaxf(fmaf(g, acc[0][nt][2 * j + 1] + bi, be), 0.f);
            float m2 = fmaxf(fmaf(g, acc[1][nt][2 * j]     + bi, be), 0.f);
            float m3 = fmaxf(fmaf(g, acc[1][nt][2 * j + 1] + bi, be), 0.f);
            float p = fmaxf(fmaxf(m0, m1), fmaxf(m2, m3));
            int px = 2 * q + j, py = wv;
            out[((size_t)bt * 64 + co) * 64 + py * 8 + px] = p;
        }
    }
}

// ---------------------------------------------------------------------------
// One-time weight transpose for stage 2: w (96,64,3,9) -> w2[kt][ci][k9][co].
// ---------------------------------------------------------------------------
__global__ void conv2_wt_kernel(const float* __restrict__ w, float* __restrict__ w2)
{
    int idx = blockIdx.x * blockDim.x + threadIdx.x;
    if (idx >= 96 * 64 * 27) return;
    int co = idx % 96; int r = idx / 96;
    int k9 = r % 9;    r /= 9;
    int ci = r % 64;   int kt = r / 64;
    w2[idx] = w[(((size_t)co * 64 + ci) * 3 + kt) * 9 + k9];
}

// ---------------------------------------------------------------------------
// Stage 2: Conv3D 64ci->96co on 8x8 -> pooled 2x2. LDS-staged fp32.
// ---------------------------------------------------------------------------
__global__ __launch_bounds__(384) void conv2_kernel(
    const float* __restrict__ in, const float* __restrict__ w2,
    const float* __restrict__ bias, const float* __restrict__ gam,
    const float* __restrict__ bet, float* __restrict__ out)
{
    int tid = threadIdx.x;
    int co = tid >> 2, quad = tid & 3;
    int qy = quad >> 1, qx = quad & 1;
    int bt = blockIdx.x;
    int b = bt >> 5, t = bt & 31;

    __shared__ __align__(16) float lin[8 * 120];
    __shared__ __align__(16) float lw[8 * 9 * 96];

    float acc[4] = {0.f, 0.f, 0.f, 0.f};

    for (int kt = 0; kt < 3; ++kt) {
        int ts = t + kt - 1;
        if (ts < 0 || ts >= Tn) continue;
        for (int chunk = 0; chunk < 8; ++chunk) {
            __syncthreads();
            for (int idx = tid; idx < 8 * 120; idx += 384) {
                int ci  = idx / 120;
                int rem = idx - ci * 120;
                int r = rem / 12, c = rem - r * 12;
                int gy = r - 1, gx = c - 1;
                float v = 0.f;
                if (gy >= 0 && gy < 8 && gx >= 0 && gx < 8)
                    v = in[((size_t)(b * Tn + ts) * 64 + chunk * 8 + ci) * 64 + gy * 8 + gx];
                lin[idx] = v;
            }
            const float* wsrc = w2 + ((size_t)(kt * 64 + chunk * 8) * 9) * 96;
            for (int idx = tid; idx < 6912; idx += 384) lw[idx] = wsrc[idx];
            __syncthreads();

            #pragma unroll
            for (int ci8 = 0; ci8 < 8; ++ci8) {
                const float* pl = lin + ci8 * 120;
                float p[5][5];
                #pragma unroll
                for (int iy = 0; iy < 5; ++iy) {
                    const float* rp = pl + (4 * qy + iy) * 12 + 4 * qx;
                    float4 v4 = *(const float4*)rp;
                    p[iy][0] = v4.x; p[iy][1] = v4.y; p[iy][2] = v4.z; p[iy][3] = v4.w;
                    p[iy][4] = rp[4];
                }
                const float* wp = lw + ci8 * 9 * 96 + co;
                #pragma unroll
                for (int ky = 0; ky < 3; ++ky)
                    #pragma unroll
                    for (int kx = 0; kx < 3; ++kx) {
                        float wv = wp[(ky * 3 + kx) * 96];
                        acc[0] = fmaf(wv, p[ky][kx],         acc[0]);
                        acc[1] = fmaf(wv, p[ky][kx + 2],     acc[1]);
                        acc[2] = fmaf(wv, p[ky + 2][kx],     acc[2]);
                        acc[3] = fmaf(wv, p[ky + 2][kx + 2], acc[3]);
                    }
            }
        }
    }
    float bi = bias[co], g = gam[co], be = bet[co];
    float a0 = fmaxf(fmaf(g, acc[0] + bi, be), 0.f);
    float a1 = fmaxf(fmaf(g, acc[1] + bi, be), 0.f);
    float a2 = fmaxf(fmaf(g, acc[2] + bi, be), 0.f);
    float a3 = fmaxf(fmaf(g, acc[3] + bi, be), 0.f);
    out[((size_t)bt * 96 + co) * 4 + qy * 2 + qx] = fmaxf(fmaxf(a0, a1), fmaxf(a2, a3));
}

// ---------------------------------------------------------------------------
// Fused: GAP(2x2) -> ep projection, bbox MLP, u = ff + bf.
// ---------------------------------------------------------------------------
__global__ void fuse_u_kernel(const float* __restrict__ buf2, const float* __restrict__ ep_w,
                              const float* __restrict__ ep_b, const float* __restrict__ bb,
                              const float* __restrict__ bp1_w, const float* __restrict__ bp1_b,
                              const float* __restrict__ bp2_w, const float* __restrict__ bp2_b,
                              float* __restrict__ u)
{
    int bt = blockIdx.x;
    int m  = threadIdx.x;
    __shared__ float hs[64];
    __shared__ float gap[96];
    if (m < 64) {
        float a = bp1_b[m];
        #pragma unroll
        for (int k = 0; k < 4; ++k) a = fmaf(bp1_w[m * 4 + k], bb[bt * 4 + k], a);
        hs[m] = fmaxf(a, 0.f);
    } else if (m < 160) {
        int c = m - 64;
        const float* p = buf2 + ((size_t)bt * 96 + c) * 4;
        gap[c] = 0.25f * (p[0] + p[1] + p[2] + p[3]);
    }
    __syncthreads();
    float ff = ep_b[m];
    for (int c = 0; c < 96; ++c) ff = fmaf(gap[c], ep_w[m * 96 + c], ff);
    float bfv = bp2_b[m];
    for (int j = 0; j < 64; ++j) bfv = fmaf(hs[j], bp2_w[m * 64 + j], bfv);
    u[(size_t)bt * 256 + m] = ff + bfv;
}

// ---------------------------------------------------------------------------
// Linear with 4-token m-tiling.
// ---------------------------------------------------------------------------
__global__ void linear_kernel(const float* __restrict__ in, const float* __restrict__ w,
                              const float* __restrict__ bias, float* __restrict__ out,
                              int K, int N, int ldin, int act, int total)
{
    int idx = blockIdx.x * blockDim.x + threadIdx.x;
    if (idx >= total) return;
    int o = idx % N; int m0 = (idx / N) * 4;
    const float4* wp = (const float4*)(w + (size_t)o * K);
    const float4* i0 = (const float4*)(in + (size_t)(m0 + 0) * ldin);
    const float4* i1 = (const float4*)(in + (size_t)(m0 + 1) * ldin);
    const float4* i2 = (const float4*)(in + (size_t)(m0 + 2) * ldin);
    const float4* i3 = (const float4*)(in + (size_t)(m0 + 3) * ldin);
    float a0 = 0.f, a1 = 0.f, a2 = 0.f, a3 = 0.f;
    int K4 = K >> 2;
    for (int k = 0; k < K4; ++k) {
        float4 wv = wp[k];
        float4 x0 = i0[k], x1 = i1[k], x2 = i2[k], x3 = i3[k];
        a0 = fmaf(x0.x, wv.x, a0); a0 = fmaf(x0.y, wv.y, a0);
        a0 = fmaf(x0.z, wv.z, a0); a0 = fmaf(x0.w, wv.w, a0);
        a1 = fmaf(x1.x, wv.x, a1); a1 = fmaf(x1.y, wv.y, a1);
        a1 = fmaf(x1.z, wv.z, a1); a1 = fmaf(x1.w, wv.w, a1);
        a2 = fmaf(x2.x, wv.x, a2); a2 = fmaf(x2.y, wv.y, a2);
        a2 = fmaf(x2.z, wv.z, a2); a2 = fmaf(x2.w, wv.w, a2);
        a3 = fmaf(x3.x, wv.x, a3); a3 = fmaf(x3.y, wv.y, a3);
        a3 = fmaf(x3.z, wv.z, a3); a3 = fmaf(x3.w, wv.w, a3);
    }
    float av[4] = {a0, a1, a2, a3};
    float bv = bias ? bias[o] : 0.f;
    #pragma unroll
    for (int r = 0; r < 4; ++r) {
        float a = av[r] + bv;
        if (act == 1)      a = fmaxf(a, 0.f);
        else if (act == 2) a = 1.f / (1.f + expf(-a));
        else if (act == 3) a = (a > 20.f) ? a : log1pf(expf(a));
        out[(size_t)(m0 + r) * N + o] = a;
    }
}

// ---------------------------------------------------------------------------
// Causal depthwise conv1d (k=4) + SiLU.
// ---------------------------------------------------------------------------
__global__ void conv1d_silu_kernel(const float* __restrict__ xz, const float* __restrict__ cw,
                                   const float* __restrict__ cb, float* __restrict__ xs)
{
    int idx = blockIdx.x * blockDim.x + threadIdx.x;
    if (idx >= Bn * Tn * D_INNER) return;
    int d = idx % D_INNER; int r = idx / D_INNER;
    int t = r % Tn; int b = r / Tn;
    float acc = cb[d];
    #pragma unroll
    for (int k = 0; k < 4; ++k) {
        int ts = t - 3 + k;
        if (ts >= 0) acc = fmaf(cw[d * 4 + k], xz[(size_t)(b * Tn + ts) * 1024 + d], acc);
    }
    xs[idx] = acc / (1.f + expf(-acc));
}

// ---------------------------------------------------------------------------
// Wave-parallel selective scan.
// ---------------------------------------------------------------------------
__global__ __launch_bounds__(256) void ssm_kernel(
    const float* __restrict__ xdbl, const float* __restrict__ dtb,
    const float* __restrict__ xs, const float* __restrict__ xz,
    const float* __restrict__ A_log, const float* __restrict__ Dp,
    float* __restrict__ y)
{
    int tid = threadIdx.x;
    int lane = tid & 63;
    int s = lane & 15, dsub = lane >> 4;
    int gid = blockIdx.x * 4 + (tid >> 6);
    int b = gid >> 7;
    int d = ((gid & 127) << 2) + dsub;

    float A = -expf(A_log[d * 16 + s]);
    float Dv = Dp[d];
    float h = 0.f;
    for (int t = 0; t < Tn; ++t) {
        int bt = b * Tn + t;
        float dtv = dtb[(size_t)bt * 512 + d];
        float xv  = xs [(size_t)bt * 512 + d];
        float Bs  = xdbl[(size_t)bt * 48 + 16 + s];
        float Cs  = xdbl[(size_t)bt * 48 + 32 + s];
        float dA = expf(dtv * A);
        h = fmaf(dA, h, dtv * Bs * xv);
        float c = h * Cs;
        c += __shfl_xor(c, 8, 16);
        c += __shfl_xor(c, 4, 16);
        c += __shfl_xor(c, 2, 16);
        c += __shfl_xor(c, 1, 16);
        if (s == 0) {
            float zv = xz[(size_t)bt * 1024 + 512 + d];
            float sig = 1.f / (1.f + expf(-zv));
            y[(size_t)bt * 512 + d] = (c + Dv * xv) * (zv * sig);
        }
    }
}

// ---------------------------------------------------------------------------
// Kalman filter scan, one thread per batch.
// ---------------------------------------------------------------------------
__global__ void kf_kernel(const float* __restrict__ meas, const float* __restrict__ bb,
                          const float* __restrict__ Fin, const float* __restrict__ Hmin,
                          const float* __restrict__ lq, const float* __restrict__ lr,
                          float* __restrict__ pred)
{
    int b = blockIdx.x * blockDim.x + threadIdx.x;
    if (b >= Bn) return;
    float F[4][4], Hm[4][4], Qd[4], Rd[4];
    #pragma unroll
    for (int i = 0; i < 4; ++i) {
        Qd[i] = expf(lq[i]) + 1e-6f;
        Rd[i] = expf(lr[i]) + 1e-6f;
        #pragma unroll
        for (int j = 0; j < 4; ++j) { F[i][j] = Fin[i * 4 + j]; Hm[i][j] = Hmin[i * 4 + j]; }
    }
    float s[4], P[4][4];
    #pragma unroll
    for (int i = 0; i < 4; ++i) {
        s[i] = bb[(b * Tn) * 4 + i];
        #pragma unroll
        for (int j = 0; j < 4; ++j) P[i][j] = (i == j) ? 0.01f : 0.f;
    }
    for (int t = 0; t < Tn; ++t) {
        float mv[4];
        #pragma unroll
        for (int i = 0; i < 4; ++i) mv[i] = meas[(b * Tn + t) * 4 + i];
        float sp[4];
        #pragma unroll
        for (int i = 0; i < 4; ++i) { float a = 0.f;
            #pragma unroll
            for (int j = 0; j < 4; ++j) a = fmaf(F[i][j], s[j], a); sp[i] = a; }
        float FP[4][4];
        #pragma unroll
        for (int i = 0; i < 4; ++i)
            #pragma unroll
            for (int j = 0; j < 4; ++j) { float a = 0.f;
                for (int k = 0; k < 4; ++k) a = fmaf(F[i][k], P[k][j], a); FP[i][j] = a; }
        float Pp[4][4];
        #pragma unroll
        for (int i = 0; i < 4; ++i)
            #pragma unroll
            for (int j = 0; j < 4; ++j) { float a = 0.f;
                for (int k = 0; k < 4; ++k) a = fmaf(FP[i][k], F[j][k], a);
                Pp[i][j] = a + ((i == j) ? Qd[i] : 0.f); }
        float yr[4];
        #pragma unroll
        for (int i = 0; i < 4; ++i) { float a = 0.f;
            for (int j = 0; j < 4; ++j) a = fmaf(Hm[i][j], sp[j], a); yr[i] = mv[i] - a; }
        float HP[4][4];
        #pragma unroll
        for (int i = 0; i < 4; ++i)
            #pragma unroll
            for (int j = 0; j < 4; ++j) { float a = 0.f;
                for (int k = 0; k < 4; ++k) a = fmaf(Hm[i][k], Pp[k][j], a); HP[i][j] = a; }
        float S[4][8];
        #pragma unroll
        for (int i = 0; i < 4; ++i)
            #pragma unroll
            for (int j = 0; j < 4; ++j) { float a = 0.f;
                for (int k = 0; k < 4; ++k) a = fmaf(HP[i][k], Hm[j][k], a);
                S[i][j] = a + ((i == j) ? Rd[i] : 0.f);
                S[i][4 + j] = Hm[i][j]; }
        #pragma unroll
        for (int c = 0; c < 4; ++c) {
            float dinv = 1.f / S[c][c];
            #pragma unroll
            for (int j = 0; j < 8; ++j) S[c][j] *= dinv;
            #pragma unroll
            for (int r2 = 0; r2 < 4; ++r2) {
                if (r2 == c) continue;
                float f = S[r2][c];
                #pragma unroll
                for (int j = 0; j < 8; ++j) S[r2][j] = fmaf(-f, S[c][j], S[r2][j]);
            }
        }
        float K[4][4];
        #pragma unroll
        for (int i = 0; i < 4; ++i)
            #pragma unroll
            for (int k = 0; k < 4; ++k) { float a = 0.f;
                for (int j = 0; j < 4; ++j) a = fmaf(Pp[i][j], S[k][4 + j], a); K[i][k] = a; }
        float sn[4];
        #pragma unroll
        for (int i = 0; i < 4; ++i) { float a = sp[i];
            for (int j = 0; j < 4; ++j) a = fmaf(K[i][j], yr[j], a); sn[i] = a; }
        float IKH[4][4];
        #pragma unroll
        for (int i = 0; i < 4; ++i)
            #pragma unroll
            for (int j = 0; j < 4; ++j) { float a = (i == j) ? 1.f : 0.f;
                for (int k = 0; k < 4; ++k) a = fmaf(-K[i][k], Hm[k][j], a); IKH[i][j] = a; }
        float T1[4][4];
        #pragma unroll
        for (int i = 0; i < 4; ++i)
            #pragma unroll
            for (int j = 0; j < 4; ++j) { float a = 0.f;
                for (int k = 0; k < 4; ++k) a = fmaf(IKH[i][k], Pp[k][j], a); T1[i][j] = a; }
        #pragma unroll
        for (int i = 0; i < 4; ++i)
            #pragma unroll
            for (int j = 0; j < 4; ++j) { float a = 0.f;
                for (int k = 0; k < 4; ++k) a = fmaf(T1[i][k], IKH[j][k], a);
                for (int k = 0; k < 4; ++k) a = fmaf(K[i][k] * Rd[k], K[j][k], a);
                P[i][j] = a; }
        #pragma unroll
        for (int i = 0; i < 4; ++i) { s[i] = sn[i]; pred[(b * Tn + t) * 4 + i] = sn[i]; }
    }
}

// ---------------------------------------------------------------------------
extern "C" void kernel_launch(void* const* d_in, const int* in_sizes, int n_in,
                              void* d_out, int out_size, void* d_ws, size_t ws_size,
                              hipStream_t stream)
{
    const float* frames = (const float*)d_in[0];
    const float* bb     = (const float*)d_in[1];
    const float* cw0 = (const float*)d_in[2],  *cb0 = (const float*)d_in[3];
    const float* g0  = (const float*)d_in[4],  *be0 = (const float*)d_in[5];
    const float* cw1 = (const float*)d_in[6],  *cb1 = (const float*)d_in[7];
    const float* g1  = (const float*)d_in[8],  *be1 = (const float*)d_in[9];
    const float* cw2 = (const float*)d_in[10], *cb2 = (const float*)d_in[11];
    const float* g2  = (const float*)d_in[12], *be2 = (const float*)d_in[13];
    const float* ep_w  = (const float*)d_in[14], *ep_b  = (const float*)d_in[15];
    const float* bp1_w = (const float*)d_in[16], *bp1_b = (const float*)d_in[17];
    const float* bp2_w = (const float*)d_in[18], *bp2_b = (const float*)d_in[19];
    const float* in_proj_w = (const float*)d_in[20];
    const float* c1w = (const float*)d_in[21], *c1b = (const float*)d_in[22];
    const float* x_proj_w = (const float*)d_in[23];
    const float* dt_w = (const float*)d_in[24], *dt_b = (const float*)d_in[25];
    const float* A_log = (const float*)d_in[26], *Dp = (const float*)d_in[27];
    const float* out_proj_w = (const float*)d_in[28];
    const float* h1_w = (const float*)d_in[29], *h1_b = (const float*)d_in[30];
    const float* h2_w = (const float*)d_in[31], *h2_b = (const float*)d_in[32];
    const float* kfF = (const float*)d_in[33], *kfH = (const float*)d_in[34];
    const float* kfq = (const float*)d_in[35], *kfr = (const float*)d_in[36];

    // workspace layout (floats)
    float* ws   = (float*)d_ws;
    float* buf0 = ws;                                   // (8,32,32,32,32)
    float* buf1 = buf0 + (size_t)8 * 32 * 32 * 32 * 32; // (8,32,64,8,8)
    float* buf2 = buf1 + (size_t)8 * 32 * 64 * 8 * 8;   // (8,32,96,2,2)
    float* ub   = buf2 + (size_t)8 * 32 * 96 * 2 * 2;   // (256,256)
    float* xzb  = ub   + 256 * 256;                     // (256,1024)
    float* xsb  = xzb  + 256 * 1024;                    // (256,512)
    float* xdb  = xsb  + 256 * 512;                     // (256,48)
    float* dtbf = xdb  + 256 * 48;                      // (256,512)
    float* yb   = dtbf + 256 * 512;                     // (256,512)
    float* mob  = yb   + 256 * 512;                     // (256,256)
    float* hidb = mob  + 256 * 256;                     // (256,128)
    float* w2b  = hidb + 256 * 128;                     // conv2 transposed weights (165888)
    unsigned short* w1b = (unsigned short*)(w2b + 165888); // conv1 bf16 weights (55296 u16)

    float* kf_out   = (float*)d_out;          // (8,32,4)
    float* meas_out = kf_out + Bn * Tn * 4;   // (8,32,4)

    auto nblk = [](int n) { return dim3((unsigned)((n + 255) / 256)); };

    // CNN backbone
    conv1_wt_kernel<<<nblk(3 * 9 * 64 * 32), 256, 0, stream>>>(cw1, w1b);
    conv2_wt_kernel<<<nblk(96 * 64 * 27), 256, 0, stream>>>(cw2, w2b);
    conv0_kernel<<<dim3(256 * 16), 256, 0, stream>>>(frames, cw0, cb0, g0, be0, buf0);
    conv1_kernel<<<dim3(256), 512, 0, stream>>>(buf0, w1b, cb1, g1, be1, buf1);
    conv2_kernel<<<dim3(256), 384, 0, stream>>>(buf1, w2b, cb2, g2, be2, buf2);

    // GAP + embed proj + bbox MLP -> u
    fuse_u_kernel<<<256, 256, 0, stream>>>(buf2, ep_w, ep_b, bb, bp1_w, bp1_b, bp2_w, bp2_b, ub);

    // Mamba block
    linear_kernel<<<nblk(64 * 1024), 256, 0, stream>>>(ub, in_proj_w, nullptr, xzb,
                                                       256, 1024, 256, 0, 64 * 1024);
    conv1d_silu_kernel<<<nblk(256 * 512), 256, 0, stream>>>(xzb, c1w, c1b, xsb);
    linear_kernel<<<nblk(64 * 48), 256, 0, stream>>>(xsb, x_proj_w, nullptr, xdb,
                                                     512, 48, 512, 0, 64 * 48);
    linear_kernel<<<nblk(64 * 512), 256, 0, stream>>>(xdb, dt_w, dt_b, dtbf,
                                                      16, 512, 48, 3, 64 * 512);
    ssm_kernel<<<dim3(256), 256, 0, stream>>>(xdb, dtbf, xsb, xzb, A_log, Dp, yb);
    linear_kernel<<<nblk(64 * 256), 256, 0, stream>>>(yb, out_proj_w, nullptr, mob,
                                                      512, 256, 512, 0, 64 * 256);

    // Measurement head -> meas (second output)
    linear_kernel<<<nblk(64 * 128), 256, 0, stream>>>(mob, h1_w, h1_b, hidb,
                                                      256, 128, 256, 1, 64 * 128);
    linear_kernel<<<nblk(64 * 4), 256, 0, stream>>>(hidb, h2_w, h2_b, meas_out,
                                                    128, 4, 128, 2, 64 * 4);

    // Kalman filter -> kf_pred (first output)
    kf_kernel<<<1, 64, 0, stream>>>(meas_out, bb, kfF, kfH, kfq, kfr, kf_out);
}

// Round 6
// 639.992 us; speedup vs baseline: 6.8457x; 1.2186x over previous
//
#include <hip/hip_runtime.h>
#include <math.h>

// Problem constants
constexpr int Bn = 8, Tn = 32;
constexpr int D_INNER = 512;

typedef __attribute__((ext_vector_type(8))) short short8;   // 8 bf16
typedef __attribute__((ext_vector_type(8))) unsigned short ushort8;
typedef __attribute__((ext_vector_type(4))) float f32x4;

__device__ inline unsigned short f2bf(float x) {
    unsigned int u = __float_as_uint(x);
    unsigned int r = (u + 0x7FFF + ((u >> 16) & 1)) >> 16;  // RNE
    return (unsigned short)r;
}

// ---------------------------------------------------------------------------
// conv0 weight prep: w (32,3,3,3,3) fp32 -> bf16 [kt][ky][co][sq][ci8].
// k-group q = kx (0..2; 3 = zero pad), ci padded 3->8.
// Swizzle: stored slot sq = q ^ (co&3) ^ ((co>>2)&3)  (involution).
// ---------------------------------------------------------------------------
__global__ void conv0_wt_kernel(const float* __restrict__ w, unsigned short* __restrict__ w0b)
{
    int d = blockIdx.x * blockDim.x + threadIdx.x;
    if (d >= 3 * 3 * 32 * 4 * 8) return;
    int sl = d & 7;               // ci
    int sq = (d >> 3) & 3;        // stored slot
    int co = (d >> 5) & 31;
    int r  = d >> 10;             // kt*3 + ky
    int ky = r % 3, kt = r / 3;
    int q  = sq ^ (co & 3) ^ ((co >> 2) & 3);   // actual kx group
    float v = 0.f;
    if (q < 3 && sl < 3)
        v = w[((((size_t)co * 3 + sl) * 3 + kt) * 3 + ky) * 3 + q];
    w0b[d] = f2bf(v);
}

// ---------------------------------------------------------------------------
// Stage 0 as MFMA implicit GEMM (bf16, fp32 acc).
// Per (b,t): C[M=4096][N=32], M = pre-pool output (oy,ox) of 64x64, K = 32 =
// (kx group q: 0..2 real + pad) x (ci8: 3 real + pad). 9 K-steps (kt x ky).
// Block = (b,t) x ytile(8 oy rows = 4 pooled rows); 8 waves: wave w ->
// oy pair (w>>1), ox half (w&1) -> acc[2 dy][2 oxt][2 nt].
// LDS input staging per kt (dbuf): [r=0..16][E(0..63)|O(-1..63)][ci8] bf16
// 16B blocks; phase split makes every A-frag one stride-1 ds_read_b128:
//   q=0 (kx=-1): O[ox-1] = blk 64+ox; q=1: E[ox] = blk ox; q=2: O[ox] = 65+ox.
// Maxpool(2,2): ox pairs = adjacent C rows in-lane, oy pairs = dy in-wave.
// ---------------------------------------------------------------------------
constexpr int S0_ROWB = 132;                 // 16B blocks per staged row
constexpr int S0_BLKS = 17 * S0_ROWB;        // 2244 blocks = 35904 B

__device__ inline void conv0_fill(unsigned short* dst, const float* __restrict__ in,
                                  int b, int ts, int yt, int tid)
{
    bool tok = (ts >= 0 && ts < Tn);
    const float* src = in + (size_t)(b * Tn + (tok ? ts : 0)) * 3 * 16384;
    for (int e = tid; e < S0_BLKS; e += 512) {
        int r = e / S0_ROWB, c = e - r * S0_ROWB;
        int gy = 16 * yt - 1 + r;
        int x  = (c < 64) ? (2 * c) : (2 * c - 129);
        bool ok = tok && gy >= 0 && gy < 128 && x >= 0 && x < 128;
        float v0 = 0.f, v1 = 0.f, v2 = 0.f;
        if (ok) {
            const float* p = src + gy * 128 + x;
            v0 = p[0]; v1 = p[16384]; v2 = p[32768];
        }
        ushort8 pk = (ushort8)0;
        pk[0] = f2bf(v0); pk[1] = f2bf(v1); pk[2] = f2bf(v2);
        *(ushort8*)(dst + (size_t)e * 8) = pk;
    }
}

__global__ __launch_bounds__(512) void conv0_kernel(
    const float* __restrict__ in, const unsigned short* __restrict__ w0b,
    const float* __restrict__ bias, const float* __restrict__ gam,
    const float* __restrict__ bet, float* __restrict__ out)
{
    int tid  = threadIdx.x;
    int lane = tid & 63;
    int wv   = __builtin_amdgcn_readfirstlane(tid >> 6);  // wave 0..7
    int q    = lane >> 4;              // k-group / C-row quad
    int l15  = lane & 15;
    int pyp  = wv >> 1;                // oy pair 0..3
    int hx   = wv & 1;                 // ox half
    int bt = blockIdx.x >> 3, yt = blockIdx.x & 7;
    int b = bt >> 5, t = bt & 31;

    __shared__ __align__(16) unsigned short S[2][S0_BLKS * 8];  // 2 x 35904 B
    __shared__ __align__(16) unsigned short W[9 * 32 * 32];     // 18432 B

    f32x4 acc[2][2][2];
    #pragma unroll
    for (int dy = 0; dy < 2; ++dy)
        #pragma unroll
        for (int ot = 0; ot < 2; ++ot)
            #pragma unroll
            for (int nt = 0; nt < 2; ++nt) acc[dy][ot][nt] = (f32x4)0.f;

    // stage all weights + first input stage
    {
        const uint4* wsrc = (const uint4*)w0b;
        uint4* wdst = (uint4*)W;
        for (int e = tid; e < 1152; e += 512) wdst[e] = wsrc[e];
    }
    conv0_fill(S[0], in, b, t - 1, yt, tid);
    __syncthreads();

    for (int kt = 0; kt < 3; ++kt) {
        if (kt < 2) conv0_fill(S[(kt + 1) & 1], in, b, t + kt, yt, tid);
        const unsigned short* Sb = S[kt & 1];
        #pragma unroll
        for (int ky = 0; ky < 3; ++ky) {
            short8 bfr[2];
            #pragma unroll
            for (int nt = 0; nt < 2; ++nt) {
                int co = nt * 16 + l15;
                int i16 = ((kt * 3 + ky) * 32 + co) * 4 +
                          (q ^ (co & 3) ^ ((co >> 2) & 3));
                bfr[nt] = *(const short8*)(W + (size_t)i16 * 8);
            }
            #pragma unroll
            for (int dy = 0; dy < 2; ++dy) {
                int r = 4 * pyp + 2 * dy + ky;          // staged row 0..16
                #pragma unroll
                for (int ot = 0; ot < 2; ++ot) {
                    int ox = (2 * hx + ot) * 16 + l15;
                    short8 af = (short8)0;
                    if (q < 3) {
                        int cblk = (q == 1) ? ox : (64 + ox + (q >> 1));
                        af = *(const short8*)(Sb + (size_t)(r * S0_ROWB + cblk) * 8);
                    }
                    #pragma unroll
                    for (int nt = 0; nt < 2; ++nt)
                        acc[dy][ot][nt] = __builtin_amdgcn_mfma_f32_16x16x32_bf16(
                            af, bfr[nt], acc[dy][ot][nt], 0, 0, 0);
                }
            }
        }
        __syncthreads();
    }

    // epilogue: BN + ReLU + maxpool(2,2) in-register
    // C rows m = q*4+reg (= ox offset), cols = co.
    #pragma unroll
    for (int nt = 0; nt < 2; ++nt) {
        int co = nt * 16 + l15;
        float bi = bias[co], g = gam[co], be = bet[co];
        #pragma unroll
        for (int ot = 0; ot < 2; ++ot)
            #pragma unroll
            for (int j = 0; j < 2; ++j) {
                float m0 = fmaxf(fmaf(g, acc[0][ot][nt][2 * j]     + bi, be), 0.f);
                float m1 = fmaxf(fmaf(g, acc[0][ot][nt][2 * j + 1] + bi, be), 0.f);
                float m2 = fmaxf(fmaf(g, acc[1][ot][nt][2 * j]     + bi, be), 0.f);
                float m3 = fmaxf(fmaf(g, acc[1][ot][nt][2 * j + 1] + bi, be), 0.f);
                float p = fmaxf(fmaxf(m0, m1), fmaxf(m2, m3));
                int pox = (2 * hx + ot) * 8 + q * 2 + j;
                int poy = yt * 4 + pyp;
                out[(((size_t)bt * 32 + co) * 32 + poy) * 32 + pox] = p;
            }
    }
}

// ---------------------------------------------------------------------------
// conv1 weight prep: w (64,32,3,3,3) fp32 -> bf16 [kt][k9][co][ci-swizzled].
// ---------------------------------------------------------------------------
__global__ void conv1_wt_kernel(const float* __restrict__ w, unsigned short* __restrict__ w1b)
{
    int d = blockIdx.x * blockDim.x + threadIdx.x;
    if (d >= 3 * 9 * 64 * 32) return;
    int sl = d & 7;
    int sg = (d >> 3) & 3;
    int co = (d >> 5) & 63;
    int r  = d >> 11;                  // kt*9 + k9
    int k9 = r % 9, kt = r / 9;
    int g  = sg ^ (co & 3);
    int ci = g * 8 + sl;
    w1b[d] = f2bf(w[((size_t)(co * 32 + ci) * 3 + kt) * 9 + k9]);
}

// ---------------------------------------------------------------------------
// Stage 1 as MFMA implicit GEMM (bf16 in, fp32 acc). (verified round 5)
// ---------------------------------------------------------------------------
__global__ __launch_bounds__(512) void conv1_kernel(
    const float* __restrict__ in, const unsigned short* __restrict__ w1b,
    const float* __restrict__ bias, const float* __restrict__ gam,
    const float* __restrict__ bet, float* __restrict__ out)
{
    int tid  = threadIdx.x;
    int lane = tid & 63;
    int wv   = tid >> 6;               // wave 0..7
    int q    = lane >> 4;              // 0..3
    int l15  = lane & 15;
    int bt = blockIdx.x;
    int b = bt >> 5, t = bt & 31;

    __shared__ __align__(16) unsigned short S[33 * 34 * 32];   // 71808 B
    __shared__ __align__(16) unsigned short W[9 * 64 * 32];    // 36864 B

    f32x4 acc[2][4];
    #pragma unroll
    for (int mt = 0; mt < 2; ++mt)
        #pragma unroll
        for (int nt = 0; nt < 4; ++nt) acc[mt][nt] = (f32x4)0.f;

    for (int kt = 0; kt < 3; ++kt) {
        int ts = t + kt - 1;
        if (ts < 0 || ts >= Tn) continue;          // block-uniform
        __syncthreads();                           // S/W reuse guard
        const float* src = in + (size_t)(b * Tn + ts) * 32 * 1024;
        for (int e = tid; e < 32 * 33 * 34; e += 512) {
            int ci  = e / (33 * 34);
            int rem = e - ci * (33 * 34);
            int ys = rem / 34, xs = rem - ys * 34;
            int y = ys - 1, x = xs - 1;
            float v = (y >= 0 && x >= 0 && x < 32) ? src[ci * 1024 + y * 32 + x] : 0.f;
            int blk = (ys * 34 + xs) * 4 + ((ci >> 3) ^ ((xs >> 1) & 3));
            S[blk * 8 + (ci & 7)] = f2bf(v);
        }
        {
            const uint4* wsrc = (const uint4*)(w1b + kt * 18432);
            uint4* wdst = (uint4*)W;
            for (int e = tid; e < 2304; e += 512) wdst[e] = wsrc[e];
        }
        __syncthreads();

        for (int k9 = 0; k9 < 9; ++k9) {
            int ky = k9 / 3, kx = k9 - ky * 3;
            short8 bf[4];
            #pragma unroll
            for (int nt = 0; nt < 4; ++nt) {
                int co = nt * 16 + l15;
                int blk = (k9 * 64 + co) * 4 + (q ^ (co & 3));
                bf[nt] = *(const short8*)(W + blk * 8);
            }
            short8 af[2];
            #pragma unroll
            for (int mt = 0; mt < 2; ++mt) {
                int oy = 2 * wv + mt;
                int ys = 2 * oy + ky;
                int xs = 2 * l15 + kx;
                int blk = (ys * 34 + xs) * 4 + (q ^ ((xs >> 1) & 3));
                af[mt] = *(const short8*)(S + blk * 8);
            }
            #pragma unroll
            for (int mt = 0; mt < 2; ++mt)
                #pragma unroll
                for (int nt = 0; nt < 4; ++nt)
                    acc[mt][nt] = __builtin_amdgcn_mfma_f32_16x16x32_bf16(
                        af[mt], bf[nt], acc[mt][nt], 0, 0, 0);
        }
    }

    #pragma unroll
    for (int nt = 0; nt < 4; ++nt) {
        int co = nt * 16 + l15;
        float bi = bias[co], g = gam[co], be = bet[co];
        #pragma unroll
        for (int j = 0; j < 2; ++j) {
            float m0 = fmaxf(fmaf(g, acc[0][nt][2 * j]     + bi, be), 0.f);
            float m1 = fmaxf(fmaf(g, acc[0][nt][2 * j + 1] + bi, be), 0.f);
            float m2 = fmaxf(fmaf(g, acc[1][nt][2 * j]     + bi, be), 0.f);
            float m3 = fmaxf(fmaf(g, acc[1][nt][2 * j + 1] + bi, be), 0.f);
            float p = fmaxf(fmaxf(m0, m1), fmaxf(m2, m3));
            int px = 2 * q + j, py = wv;
            out[((size_t)bt * 64 + co) * 64 + py * 8 + px] = p;
        }
    }
}

// ---------------------------------------------------------------------------
// One-time weight transpose for stage 2: w (96,64,3,9) -> w2[kt][ci][k9][co].
// ---------------------------------------------------------------------------
__global__ void conv2_wt_kernel(const float* __restrict__ w, float* __restrict__ w2)
{
    int idx = blockIdx.x * blockDim.x + threadIdx.x;
    if (idx >= 96 * 64 * 27) return;
    int co = idx % 96; int r = idx / 96;
    int k9 = r % 9;    r /= 9;
    int ci = r % 64;   int kt = r / 64;
    w2[idx] = w[(((size_t)co * 64 + ci) * 3 + kt) * 9 + k9];
}

// ---------------------------------------------------------------------------
// Stage 2: Conv3D 64ci->96co on 8x8 -> pooled 2x2. LDS-staged fp32.
// ---------------------------------------------------------------------------
__global__ __launch_bounds__(384) void conv2_kernel(
    const float* __restrict__ in, const float* __restrict__ w2,
    const float* __restrict__ bias, const float* __restrict__ gam,
    const float* __restrict__ bet, float* __restrict__ out)
{
    int tid = threadIdx.x;
    int co = tid >> 2, quad = tid & 3;
    int qy = quad >> 1, qx = quad & 1;
    int bt = blockIdx.x;
    int b = bt >> 5, t = bt & 31;

    __shared__ __align__(16) float lin[8 * 120];
    __shared__ __align__(16) float lw[8 * 9 * 96];

    float acc[4] = {0.f, 0.f, 0.f, 0.f};

    for (int kt = 0; kt < 3; ++kt) {
        int ts = t + kt - 1;
        if (ts < 0 || ts >= Tn) continue;
        for (int chunk = 0; chunk < 8; ++chunk) {
            __syncthreads();
            for (int idx = tid; idx < 8 * 120; idx += 384) {
                int ci  = idx / 120;
                int rem = idx - ci * 120;
                int r = rem / 12, c = rem - r * 12;
                int gy = r - 1, gx = c - 1;
                float v = 0.f;
                if (gy >= 0 && gy < 8 && gx >= 0 && gx < 8)
                    v = in[((size_t)(b * Tn + ts) * 64 + chunk * 8 + ci) * 64 + gy * 8 + gx];
                lin[idx] = v;
            }
            const float* wsrc = w2 + ((size_t)(kt * 64 + chunk * 8) * 9) * 96;
            for (int idx = tid; idx < 6912; idx += 384) lw[idx] = wsrc[idx];
            __syncthreads();

            #pragma unroll
            for (int ci8 = 0; ci8 < 8; ++ci8) {
                const float* pl = lin + ci8 * 120;
                float p[5][5];
                #pragma unroll
                for (int iy = 0; iy < 5; ++iy) {
                    const float* rp = pl + (4 * qy + iy) * 12 + 4 * qx;
                    float4 v4 = *(const float4*)rp;
                    p[iy][0] = v4.x; p[iy][1] = v4.y; p[iy][2] = v4.z; p[iy][3] = v4.w;
                    p[iy][4] = rp[4];
                }
                const float* wp = lw + ci8 * 9 * 96 + co;
                #pragma unroll
                for (int ky = 0; ky < 3; ++ky)
                    #pragma unroll
                    for (int kx = 0; kx < 3; ++kx) {
                        float wv = wp[(ky * 3 + kx) * 96];
                        acc[0] = fmaf(wv, p[ky][kx],         acc[0]);
                        acc[1] = fmaf(wv, p[ky][kx + 2],     acc[1]);
                        acc[2] = fmaf(wv, p[ky + 2][kx],     acc[2]);
                        acc[3] = fmaf(wv, p[ky + 2][kx + 2], acc[3]);
                    }
            }
        }
    }
    float bi = bias[co], g = gam[co], be = bet[co];
    float a0 = fmaxf(fmaf(g, acc[0] + bi, be), 0.f);
    float a1 = fmaxf(fmaf(g, acc[1] + bi, be), 0.f);
    float a2 = fmaxf(fmaf(g, acc[2] + bi, be), 0.f);
    float a3 = fmaxf(fmaf(g, acc[3] + bi, be), 0.f);
    out[((size_t)bt * 96 + co) * 4 + qy * 2 + qx] = fmaxf(fmaxf(a0, a1), fmaxf(a2, a3));
}

// ---------------------------------------------------------------------------
// Fused: GAP(2x2) -> ep projection, bbox MLP, u = ff + bf.
// ---------------------------------------------------------------------------
__global__ void fuse_u_kernel(const float* __restrict__ buf2, const float* __restrict__ ep_w,
                              const float* __restrict__ ep_b, const float* __restrict__ bb,
                              const float* __restrict__ bp1_w, const float* __restrict__ bp1_b,
                              const float* __restrict__ bp2_w, const float* __restrict__ bp2_b,
                              float* __restrict__ u)
{
    int bt = blockIdx.x;
    int m  = threadIdx.x;
    __shared__ float hs[64];
    __shared__ float gap[96];
    if (m < 64) {
        float a = bp1_b[m];
        #pragma unroll
        for (int k = 0; k < 4; ++k) a = fmaf(bp1_w[m * 4 + k], bb[bt * 4 + k], a);
        hs[m] = fmaxf(a, 0.f);
    } else if (m < 160) {
        int c = m - 64;
        const float* p = buf2 + ((size_t)bt * 96 + c) * 4;
        gap[c] = 0.25f * (p[0] + p[1] + p[2] + p[3]);
    }
    __syncthreads();
    float ff = ep_b[m];
    for (int c = 0; c < 96; ++c) ff = fmaf(gap[c], ep_w[m * 96 + c], ff);
    float bfv = bp2_b[m];
    for (int j = 0; j < 64; ++j) bfv = fmaf(hs[j], bp2_w[m * 64 + j], bfv);
    u[(size_t)bt * 256 + m] = ff + bfv;
}

// ---------------------------------------------------------------------------
// Linear with 4-token m-tiling.
// ---------------------------------------------------------------------------
__global__ void linear_kernel(const float* __restrict__ in, const float* __restrict__ w,
                              const float* __restrict__ bias, float* __restrict__ out,
                              int K, int N, int ldin, int act, int total)
{
    int idx = blockIdx.x * blockDim.x + threadIdx.x;
    if (idx >= total) return;
    int o = idx % N; int m0 = (idx / N) * 4;
    const float4* wp = (const float4*)(w + (size_t)o * K);
    const float4* i0 = (const float4*)(in + (size_t)(m0 + 0) * ldin);
    const float4* i1 = (const float4*)(in + (size_t)(m0 + 1) * ldin);
    const float4* i2 = (const float4*)(in + (size_t)(m0 + 2) * ldin);
    const float4* i3 = (const float4*)(in + (size_t)(m0 + 3) * ldin);
    float a0 = 0.f, a1 = 0.f, a2 = 0.f, a3 = 0.f;
    int K4 = K >> 2;
    for (int k = 0; k < K4; ++k) {
        float4 wv = wp[k];
        float4 x0 = i0[k], x1 = i1[k], x2 = i2[k], x3 = i3[k];
        a0 = fmaf(x0.x, wv.x, a0); a0 = fmaf(x0.y, wv.y, a0);
        a0 = fmaf(x0.z, wv.z, a0); a0 = fmaf(x0.w, wv.w, a0);
        a1 = fmaf(x1.x, wv.x, a1); a1 = fmaf(x1.y, wv.y, a1);
        a1 = fmaf(x1.z, wv.z, a1); a1 = fmaf(x1.w, wv.w, a1);
        a2 = fmaf(x2.x, wv.x, a2); a2 = fmaf(x2.y, wv.y, a2);
        a2 = fmaf(x2.z, wv.z, a2); a2 = fmaf(x2.w, wv.w, a2);
        a3 = fmaf(x3.x, wv.x, a3); a3 = fmaf(x3.y, wv.y, a3);
        a3 = fmaf(x3.z, wv.z, a3); a3 = fmaf(x3.w, wv.w, a3);
    }
    float av[4] = {a0, a1, a2, a3};
    float bv = bias ? bias[o] : 0.f;
    #pragma unroll
    for (int r = 0; r < 4; ++r) {
        float a = av[r] + bv;
        if (act == 1)      a = fmaxf(a, 0.f);
        else if (act == 2) a = 1.f / (1.f + expf(-a));
        else if (act == 3) a = (a > 20.f) ? a : log1pf(expf(a));
        out[(size_t)(m0 + r) * N + o] = a;
    }
}

// ---------------------------------------------------------------------------
// Causal depthwise conv1d (k=4) + SiLU.
// ---------------------------------------------------------------------------
__global__ void conv1d_silu_kernel(const float* __restrict__ xz, const float* __restrict__ cw,
                                   const float* __restrict__ cb, float* __restrict__ xs)
{
    int idx = blockIdx.x * blockDim.x + threadIdx.x;
    if (idx >= Bn * Tn * D_INNER) return;
    int d = idx % D_INNER; int r = idx / D_INNER;
    int t = r % Tn; int b = r / Tn;
    float acc = cb[d];
    #pragma unroll
    for (int k = 0; k < 4; ++k) {
        int ts = t - 3 + k;
        if (ts >= 0) acc = fmaf(cw[d * 4 + k], xz[(size_t)(b * Tn + ts) * 1024 + d], acc);
    }
    xs[idx] = acc / (1.f + expf(-acc));
}

// ---------------------------------------------------------------------------
// Wave-parallel selective scan.
// ---------------------------------------------------------------------------
__global__ __launch_bounds__(256) void ssm_kernel(
    const float* __restrict__ xdbl, const float* __restrict__ dtb,
    const float* __restrict__ xs, const float* __restrict__ xz,
    const float* __restrict__ A_log, const float* __restrict__ Dp,
    float* __restrict__ y)
{
    int tid = threadIdx.x;
    int lane = tid & 63;
    int s = lane & 15, dsub = lane >> 4;
    int gid = blockIdx.x * 4 + (tid >> 6);
    int b = gid >> 7;
    int d = ((gid & 127) << 2) + dsub;

    float A = -expf(A_log[d * 16 + s]);
    float Dv = Dp[d];
    float h = 0.f;
    for (int t = 0; t < Tn; ++t) {
        int bt = b * Tn + t;
        float dtv = dtb[(size_t)bt * 512 + d];
        float xv  = xs [(size_t)bt * 512 + d];
        float Bs  = xdbl[(size_t)bt * 48 + 16 + s];
        float Cs  = xdbl[(size_t)bt * 48 + 32 + s];
        float dA = expf(dtv * A);
        h = fmaf(dA, h, dtv * Bs * xv);
        float c = h * Cs;
        c += __shfl_xor(c, 8, 16);
        c += __shfl_xor(c, 4, 16);
        c += __shfl_xor(c, 2, 16);
        c += __shfl_xor(c, 1, 16);
        if (s == 0) {
            float zv = xz[(size_t)bt * 1024 + 512 + d];
            float sig = 1.f / (1.f + expf(-zv));
            y[(size_t)bt * 512 + d] = (c + Dv * xv) * (zv * sig);
        }
    }
}

// ---------------------------------------------------------------------------
// Kalman filter scan, one thread per batch.
// ---------------------------------------------------------------------------
__global__ void kf_kernel(const float* __restrict__ meas, const float* __restrict__ bb,
                          const float* __restrict__ Fin, const float* __restrict__ Hmin,
                          const float* __restrict__ lq, const float* __restrict__ lr,
                          float* __restrict__ pred)
{
    int b = blockIdx.x * blockDim.x + threadIdx.x;
    if (b >= Bn) return;
    float F[4][4], Hm[4][4], Qd[4], Rd[4];
    #pragma unroll
    for (int i = 0; i < 4; ++i) {
        Qd[i] = expf(lq[i]) + 1e-6f;
        Rd[i] = expf(lr[i]) + 1e-6f;
        #pragma unroll
        for (int j = 0; j < 4; ++j) { F[i][j] = Fin[i * 4 + j]; Hm[i][j] = Hmin[i * 4 + j]; }
    }
    float s[4], P[4][4];
    #pragma unroll
    for (int i = 0; i < 4; ++i) {
        s[i] = bb[(b * Tn) * 4 + i];
        #pragma unroll
        for (int j = 0; j < 4; ++j) P[i][j] = (i == j) ? 0.01f : 0.f;
    }
    for (int t = 0; t < Tn; ++t) {
        float mv[4];
        #pragma unroll
        for (int i = 0; i < 4; ++i) mv[i] = meas[(b * Tn + t) * 4 + i];
        float sp[4];
        #pragma unroll
        for (int i = 0; i < 4; ++i) { float a = 0.f;
            #pragma unroll
            for (int j = 0; j < 4; ++j) a = fmaf(F[i][j], s[j], a); sp[i] = a; }
        float FP[4][4];
        #pragma unroll
        for (int i = 0; i < 4; ++i)
            #pragma unroll
            for (int j = 0; j < 4; ++j) { float a = 0.f;
                for (int k = 0; k < 4; ++k) a = fmaf(F[i][k], P[k][j], a); FP[i][j] = a; }
        float Pp[4][4];
        #pragma unroll
        for (int i = 0; i < 4; ++i)
            #pragma unroll
            for (int j = 0; j < 4; ++j) { float a = 0.f;
                for (int k = 0; k < 4; ++k) a = fmaf(FP[i][k], F[j][k], a);
                Pp[i][j] = a + ((i == j) ? Qd[i] : 0.f); }
        float yr[4];
        #pragma unroll
        for (int i = 0; i < 4; ++i) { float a = 0.f;
            for (int j = 0; j < 4; ++j) a = fmaf(Hm[i][j], sp[j], a); yr[i] = mv[i] - a; }
        float HP[4][4];
        #pragma unroll
        for (int i = 0; i < 4; ++i)
            #pragma unroll
            for (int j = 0; j < 4; ++j) { float a = 0.f;
                for (int k = 0; k < 4; ++k) a = fmaf(Hm[i][k], Pp[k][j], a); HP[i][j] = a; }
        float S[4][8];
        #pragma unroll
        for (int i = 0; i < 4; ++i)
            #pragma unroll
            for (int j = 0; j < 4; ++j) { float a = 0.f;
                for (int k = 0; k < 4; ++k) a = fmaf(HP[i][k], Hm[j][k], a);
                S[i][j] = a + ((i == j) ? Rd[i] : 0.f);
                S[i][4 + j] = Hm[i][j]; }
        #pragma unroll
        for (int c = 0; c < 4; ++c) {
            float dinv = 1.f / S[c][c];
            #pragma unroll
            for (int j = 0; j < 8; ++j) S[c][j] *= dinv;
            #pragma unroll
            for (int r2 = 0; r2 < 4; ++r2) {
                if (r2 == c) continue;
                float f = S[r2][c];
                #pragma unroll
                for (int j = 0; j < 8; ++j) S[r2][j] = fmaf(-f, S[c][j], S[r2][j]);
            }
        }
        float K[4][4];
        #pragma unroll
        for (int i = 0; i < 4; ++i)
            #pragma unroll
            for (int k = 0; k < 4; ++k) { float a = 0.f;
                for (int j = 0; j < 4; ++j) a = fmaf(Pp[i][j], S[k][4 + j], a); K[i][k] = a; }
        float sn[4];
        #pragma unroll
        for (int i = 0; i < 4; ++i) { float a = sp[i];
            for (int j = 0; j < 4; ++j) a = fmaf(K[i][j], yr[j], a); sn[i] = a; }
        float IKH[4][4];
        #pragma unroll
        for (int i = 0; i < 4; ++i)
            #pragma unroll
            for (int j = 0; j < 4; ++j) { float a = (i == j) ? 1.f : 0.f;
                for (int k = 0; k < 4; ++k) a = fmaf(-K[i][k], Hm[k][j], a); IKH[i][j] = a; }
        float T1[4][4];
        #pragma unroll
        for (int i = 0; i < 4; ++i)
            #pragma unroll
            for (int j = 0; j < 4; ++j) { float a = 0.f;
                for (int k = 0; k < 4; ++k) a = fmaf(IKH[i][k], Pp[k][j], a); T1[i][j] = a; }
        #pragma unroll
        for (int i = 0; i < 4; ++i)
            #pragma unroll
            for (int j = 0; j < 4; ++j) { float a = 0.f;
                for (int k = 0; k < 4; ++k) a = fmaf(T1[i][k], IKH[j][k], a);
                for (int k = 0; k < 4; ++k) a = fmaf(K[i][k] * Rd[k], K[j][k], a);
                P[i][j] = a; }
        #pragma unroll
        for (int i = 0; i < 4; ++i) { s[i] = sn[i]; pred[(b * Tn + t) * 4 + i] = sn[i]; }
    }
}

// ---------------------------------------------------------------------------
extern "C" void kernel_launch(void* const* d_in, const int* in_sizes, int n_in,
                              void* d_out, int out_size, void* d_ws, size_t ws_size,
                              hipStream_t stream)
{
    const float* frames = (const float*)d_in[0];
    const float* bb     = (const float*)d_in[1];
    const float* cw0 = (const float*)d_in[2],  *cb0 = (const float*)d_in[3];
    const float* g0  = (const float*)d_in[4],  *be0 = (const float*)d_in[5];
    const float* cw1 = (const float*)d_in[6],  *cb1 = (const float*)d_in[7];
    const float* g1  = (const float*)d_in[8],  *be1 = (const float*)d_in[9];
    const float* cw2 = (const float*)d_in[10], *cb2 = (const float*)d_in[11];
    const float* g2  = (const float*)d_in[12], *be2 = (const float*)d_in[13];
    const float* ep_w  = (const float*)d_in[14], *ep_b  = (const float*)d_in[15];
    const float* bp1_w = (const float*)d_in[16], *bp1_b = (const float*)d_in[17];
    const float* bp2_w = (const float*)d_in[18], *bp2_b = (const float*)d_in[19];
    const float* in_proj_w = (const float*)d_in[20];
    const float* c1w = (const float*)d_in[21], *c1b = (const float*)d_in[22];
    const float* x_proj_w = (const float*)d_in[23];
    const float* dt_w = (const float*)d_in[24], *dt_b = (const float*)d_in[25];
    const float* A_log = (const float*)d_in[26], *Dp = (const float*)d_in[27];
    const float* out_proj_w = (const float*)d_in[28];
    const float* h1_w = (const float*)d_in[29], *h1_b = (const float*)d_in[30];
    const float* h2_w = (const float*)d_in[31], *h2_b = (const float*)d_in[32];
    const float* kfF = (const float*)d_in[33], *kfH = (const float*)d_in[34];
    const float* kfq = (const float*)d_in[35], *kfr = (const float*)d_in[36];

    // workspace layout (floats)
    float* ws   = (float*)d_ws;
    float* buf0 = ws;                                   // (8,32,32,32,32)
    float* buf1 = buf0 + (size_t)8 * 32 * 32 * 32 * 32; // (8,32,64,8,8)
    float* buf2 = buf1 + (size_t)8 * 32 * 64 * 8 * 8;   // (8,32,96,2,2)
    float* ub   = buf2 + (size_t)8 * 32 * 96 * 2 * 2;   // (256,256)
    float* xzb  = ub   + 256 * 256;                     // (256,1024)
    float* xsb  = xzb  + 256 * 1024;                    // (256,512)
    float* xdb  = xsb  + 256 * 512;                     // (256,48)
    float* dtbf = xdb  + 256 * 48;                      // (256,512)
    float* yb   = dtbf + 256 * 512;                     // (256,512)
    float* mob  = yb   + 256 * 512;                     // (256,256)
    float* hidb = mob  + 256 * 256;                     // (256,128)
    float* w2b  = hidb + 256 * 128;                     // conv2 transposed weights (165888)
    unsigned short* w1b = (unsigned short*)(w2b + 165888); // conv1 bf16 weights (55296 u16)
    unsigned short* w0b = w1b + 55296;                     // conv0 bf16 weights (9216 u16)

    float* kf_out   = (float*)d_out;          // (8,32,4)
    float* meas_out = kf_out + Bn * Tn * 4;   // (8,32,4)

    auto nblk = [](int n) { return dim3((unsigned)((n + 255) / 256)); };

    // CNN backbone
    conv0_wt_kernel<<<nblk(9216), 256, 0, stream>>>(cw0, w0b);
    conv1_wt_kernel<<<nblk(3 * 9 * 64 * 32), 256, 0, stream>>>(cw1, w1b);
    conv2_wt_kernel<<<nblk(96 * 64 * 27), 256, 0, stream>>>(cw2, w2b);
    conv0_kernel<<<dim3(2048), 512, 0, stream>>>(frames, w0b, cb0, g0, be0, buf0);
    conv1_kernel<<<dim3(256), 512, 0, stream>>>(buf0, w1b, cb1, g1, be1, buf1);
    conv2_kernel<<<dim3(256), 384, 0, stream>>>(buf1, w2b, cb2, g2, be2, buf2);

    // GAP + embed proj + bbox MLP -> u
    fuse_u_kernel<<<256, 256, 0, stream>>>(buf2, ep_w, ep_b, bb, bp1_w, bp1_b, bp2_w, bp2_b, ub);

    // Mamba block
    linear_kernel<<<nblk(64 * 1024), 256, 0, stream>>>(ub, in_proj_w, nullptr, xzb,
                                                       256, 1024, 256, 0, 64 * 1024);
    conv1d_silu_kernel<<<nblk(256 * 512), 256, 0, stream>>>(xzb, c1w, c1b, xsb);
    linear_kernel<<<nblk(64 * 48), 256, 0, stream>>>(xsb, x_proj_w, nullptr, xdb,
                                                     512, 48, 512, 0, 64 * 48);
    linear_kernel<<<nblk(64 * 512), 256, 0, stream>>>(xdb, dt_w, dt_b, dtbf,
                                                      16, 512, 48, 3, 64 * 512);
    ssm_kernel<<<dim3(256), 256, 0, stream>>>(xdb, dtbf, xsb, xzb, A_log, Dp, yb);
    linear_kernel<<<nblk(64 * 256), 256, 0, stream>>>(yb, out_proj_w, nullptr, mob,
                                                      512, 256, 512, 0, 64 * 256);

    // Measurement head -> meas (second output)
    linear_kernel<<<nblk(64 * 128), 256, 0, stream>>>(mob, h1_w, h1_b, hidb,
                                                      256, 128, 256, 1, 64 * 128);
    linear_kernel<<<nblk(64 * 4), 256, 0, stream>>>(hidb, h2_w, h2_b, meas_out,
                                                    128, 4, 128, 2, 64 * 4);

    // Kalman filter -> kf_pred (first output)
    kf_kernel<<<1, 64, 0, stream>>>(meas_out, bb, kfF, kfH, kfq, kfr, kf_out);
}

// Round 7
// 543.573 us; speedup vs baseline: 8.0600x; 1.1774x over previous
//
#include <hip/hip_runtime.h>
#include <math.h>

// Problem constants
constexpr int Bn = 8, Tn = 32;
constexpr int D_INNER = 512;

typedef __attribute__((ext_vector_type(8))) short short8;   // 8 bf16
typedef __attribute__((ext_vector_type(8))) unsigned short ushort8;
typedef __attribute__((ext_vector_type(4))) float f32x4;

__device__ inline unsigned short f2bf(float x) {
    unsigned int u = __float_as_uint(x);
    unsigned int r = (u + 0x7FFF + ((u >> 16) & 1)) >> 16;  // RNE
    return (unsigned short)r;
}

// ---------------------------------------------------------------------------
// conv0 weight prep: w (32,3,3,3,3) fp32 -> bf16 [kt][ky][co][sq][ci8].
// ---------------------------------------------------------------------------
__global__ void conv0_wt_kernel(const float* __restrict__ w, unsigned short* __restrict__ w0b)
{
    int d = blockIdx.x * blockDim.x + threadIdx.x;
    if (d >= 3 * 3 * 32 * 4 * 8) return;
    int sl = d & 7;               // ci
    int sq = (d >> 3) & 3;        // stored slot
    int co = (d >> 5) & 31;
    int r  = d >> 10;             // kt*3 + ky
    int ky = r % 3, kt = r / 3;
    int q  = sq ^ (co & 3) ^ ((co >> 2) & 3);   // actual kx group
    float v = 0.f;
    if (q < 3 && sl < 3)
        v = w[((((size_t)co * 3 + sl) * 3 + kt) * 3 + ky) * 3 + q];
    w0b[d] = f2bf(v);
}

// ---------------------------------------------------------------------------
// Stage 0 as MFMA implicit GEMM (bf16, fp32 acc). (verified round 6)
// ---------------------------------------------------------------------------
constexpr int S0_ROWB = 132;                 // 16B blocks per staged row
constexpr int S0_BLKS = 17 * S0_ROWB;        // 2244 blocks = 35904 B

__device__ inline void conv0_fill(unsigned short* dst, const float* __restrict__ in,
                                  int b, int ts, int yt, int tid)
{
    bool tok = (ts >= 0 && ts < Tn);
    const float* src = in + (size_t)(b * Tn + (tok ? ts : 0)) * 3 * 16384;
    for (int e = tid; e < S0_BLKS; e += 512) {
        int r = e / S0_ROWB, c = e - r * S0_ROWB;
        int gy = 16 * yt - 1 + r;
        int x  = (c < 64) ? (2 * c) : (2 * c - 129);
        bool ok = tok && gy >= 0 && gy < 128 && x >= 0 && x < 128;
        float v0 = 0.f, v1 = 0.f, v2 = 0.f;
        if (ok) {
            const float* p = src + gy * 128 + x;
            v0 = p[0]; v1 = p[16384]; v2 = p[32768];
        }
        ushort8 pk = (ushort8)0;
        pk[0] = f2bf(v0); pk[1] = f2bf(v1); pk[2] = f2bf(v2);
        *(ushort8*)(dst + (size_t)e * 8) = pk;
    }
}

__global__ __launch_bounds__(512) void conv0_kernel(
    const float* __restrict__ in, const unsigned short* __restrict__ w0b,
    const float* __restrict__ bias, const float* __restrict__ gam,
    const float* __restrict__ bet, float* __restrict__ out)
{
    int tid  = threadIdx.x;
    int lane = tid & 63;
    int wv   = __builtin_amdgcn_readfirstlane(tid >> 6);  // wave 0..7
    int q    = lane >> 4;              // k-group / C-row quad
    int l15  = lane & 15;
    int pyp  = wv >> 1;                // oy pair 0..3
    int hx   = wv & 1;                 // ox half
    int bt = blockIdx.x >> 3, yt = blockIdx.x & 7;
    int b = bt >> 5, t = bt & 31;

    __shared__ __align__(16) unsigned short S[2][S0_BLKS * 8];  // 2 x 35904 B
    __shared__ __align__(16) unsigned short W[9 * 32 * 32];     // 18432 B

    f32x4 acc[2][2][2];
    #pragma unroll
    for (int dy = 0; dy < 2; ++dy)
        #pragma unroll
        for (int ot = 0; ot < 2; ++ot)
            #pragma unroll
            for (int nt = 0; nt < 2; ++nt) acc[dy][ot][nt] = (f32x4)0.f;

    {
        const uint4* wsrc = (const uint4*)w0b;
        uint4* wdst = (uint4*)W;
        for (int e = tid; e < 1152; e += 512) wdst[e] = wsrc[e];
    }
    conv0_fill(S[0], in, b, t - 1, yt, tid);
    __syncthreads();

    for (int kt = 0; kt < 3; ++kt) {
        if (kt < 2) conv0_fill(S[(kt + 1) & 1], in, b, t + kt, yt, tid);
        const unsigned short* Sb = S[kt & 1];
        #pragma unroll
        for (int ky = 0; ky < 3; ++ky) {
            short8 bfr[2];
            #pragma unroll
            for (int nt = 0; nt < 2; ++nt) {
                int co = nt * 16 + l15;
                int i16 = ((kt * 3 + ky) * 32 + co) * 4 +
                          (q ^ (co & 3) ^ ((co >> 2) & 3));
                bfr[nt] = *(const short8*)(W + (size_t)i16 * 8);
            }
            #pragma unroll
            for (int dy = 0; dy < 2; ++dy) {
                int r = 4 * pyp + 2 * dy + ky;          // staged row 0..16
                #pragma unroll
                for (int ot = 0; ot < 2; ++ot) {
                    int ox = (2 * hx + ot) * 16 + l15;
                    short8 af = (short8)0;
                    if (q < 3) {
                        int cblk = (q == 1) ? ox : (64 + ox + (q >> 1));
                        af = *(const short8*)(Sb + (size_t)(r * S0_ROWB + cblk) * 8);
                    }
                    #pragma unroll
                    for (int nt = 0; nt < 2; ++nt)
                        acc[dy][ot][nt] = __builtin_amdgcn_mfma_f32_16x16x32_bf16(
                            af, bfr[nt], acc[dy][ot][nt], 0, 0, 0);
                }
            }
        }
        __syncthreads();
    }

    #pragma unroll
    for (int nt = 0; nt < 2; ++nt) {
        int co = nt * 16 + l15;
        float bi = bias[co], g = gam[co], be = bet[co];
        #pragma unroll
        for (int ot = 0; ot < 2; ++ot)
            #pragma unroll
            for (int j = 0; j < 2; ++j) {
                float m0 = fmaxf(fmaf(g, acc[0][ot][nt][2 * j]     + bi, be), 0.f);
                float m1 = fmaxf(fmaf(g, acc[0][ot][nt][2 * j + 1] + bi, be), 0.f);
                float m2 = fmaxf(fmaf(g, acc[1][ot][nt][2 * j]     + bi, be), 0.f);
                float m3 = fmaxf(fmaf(g, acc[1][ot][nt][2 * j + 1] + bi, be), 0.f);
                float p = fmaxf(fmaxf(m0, m1), fmaxf(m2, m3));
                int pox = (2 * hx + ot) * 8 + q * 2 + j;
                int poy = yt * 4 + pyp;
                out[(((size_t)bt * 32 + co) * 32 + poy) * 32 + pox] = p;
            }
    }
}

// ---------------------------------------------------------------------------
// conv1 weight prep: w (64,32,3,3,3) fp32 -> bf16 [kt][k9][co][ci-swizzled].
// ---------------------------------------------------------------------------
__global__ void conv1_wt_kernel(const float* __restrict__ w, unsigned short* __restrict__ w1b)
{
    int d = blockIdx.x * blockDim.x + threadIdx.x;
    if (d >= 3 * 9 * 64 * 32) return;
    int sl = d & 7;
    int sg = (d >> 3) & 3;
    int co = (d >> 5) & 63;
    int r  = d >> 11;                  // kt*9 + k9
    int k9 = r % 9, kt = r / 9;
    int g  = sg ^ (co & 3);
    int ci = g * 8 + sl;
    w1b[d] = f2bf(w[((size_t)(co * 32 + ci) * 3 + kt) * 9 + k9]);
}

// ---------------------------------------------------------------------------
// Stage 1 as MFMA implicit GEMM (bf16 in, fp32 acc). (verified round 5)
// ---------------------------------------------------------------------------
__global__ __launch_bounds__(512) void conv1_kernel(
    const float* __restrict__ in, const unsigned short* __restrict__ w1b,
    const float* __restrict__ bias, const float* __restrict__ gam,
    const float* __restrict__ bet, float* __restrict__ out)
{
    int tid  = threadIdx.x;
    int lane = tid & 63;
    int wv   = tid >> 6;               // wave 0..7
    int q    = lane >> 4;              // 0..3
    int l15  = lane & 15;
    int bt = blockIdx.x;
    int b = bt >> 5, t = bt & 31;

    __shared__ __align__(16) unsigned short S[33 * 34 * 32];   // 71808 B
    __shared__ __align__(16) unsigned short W[9 * 64 * 32];    // 36864 B

    f32x4 acc[2][4];
    #pragma unroll
    for (int mt = 0; mt < 2; ++mt)
        #pragma unroll
        for (int nt = 0; nt < 4; ++nt) acc[mt][nt] = (f32x4)0.f;

    for (int kt = 0; kt < 3; ++kt) {
        int ts = t + kt - 1;
        if (ts < 0 || ts >= Tn) continue;          // block-uniform
        __syncthreads();                           // S/W reuse guard
        const float* src = in + (size_t)(b * Tn + ts) * 32 * 1024;
        for (int e = tid; e < 32 * 33 * 34; e += 512) {
            int ci  = e / (33 * 34);
            int rem = e - ci * (33 * 34);
            int ys = rem / 34, xs = rem - ys * 34;
            int y = ys - 1, x = xs - 1;
            float v = (y >= 0 && x >= 0 && x < 32) ? src[ci * 1024 + y * 32 + x] : 0.f;
            int blk = (ys * 34 + xs) * 4 + ((ci >> 3) ^ ((xs >> 1) & 3));
            S[blk * 8 + (ci & 7)] = f2bf(v);
        }
        {
            const uint4* wsrc = (const uint4*)(w1b + kt * 18432);
            uint4* wdst = (uint4*)W;
            for (int e = tid; e < 2304; e += 512) wdst[e] = wsrc[e];
        }
        __syncthreads();

        for (int k9 = 0; k9 < 9; ++k9) {
            int ky = k9 / 3, kx = k9 - ky * 3;
            short8 bf[4];
            #pragma unroll
            for (int nt = 0; nt < 4; ++nt) {
                int co = nt * 16 + l15;
                int blk = (k9 * 64 + co) * 4 + (q ^ (co & 3));
                bf[nt] = *(const short8*)(W + blk * 8);
            }
            short8 af[2];
            #pragma unroll
            for (int mt = 0; mt < 2; ++mt) {
                int oy = 2 * wv + mt;
                int ys = 2 * oy + ky;
                int xs = 2 * l15 + kx;
                int blk = (ys * 34 + xs) * 4 + (q ^ ((xs >> 1) & 3));
                af[mt] = *(const short8*)(S + blk * 8);
            }
            #pragma unroll
            for (int mt = 0; mt < 2; ++mt)
                #pragma unroll
                for (int nt = 0; nt < 4; ++nt)
                    acc[mt][nt] = __builtin_amdgcn_mfma_f32_16x16x32_bf16(
                        af[mt], bf[nt], acc[mt][nt], 0, 0, 0);
        }
    }

    #pragma unroll
    for (int nt = 0; nt < 4; ++nt) {
        int co = nt * 16 + l15;
        float bi = bias[co], g = gam[co], be = bet[co];
        #pragma unroll
        for (int j = 0; j < 2; ++j) {
            float m0 = fmaxf(fmaf(g, acc[0][nt][2 * j]     + bi, be), 0.f);
            float m1 = fmaxf(fmaf(g, acc[0][nt][2 * j + 1] + bi, be), 0.f);
            float m2 = fmaxf(fmaf(g, acc[1][nt][2 * j]     + bi, be), 0.f);
            float m3 = fmaxf(fmaf(g, acc[1][nt][2 * j + 1] + bi, be), 0.f);
            float p = fmaxf(fmaxf(m0, m1), fmaxf(m2, m3));
            int px = 2 * q + j, py = wv;
            out[((size_t)bt * 64 + co) * 64 + py * 8 + px] = p;
        }
    }
}

// ---------------------------------------------------------------------------
// conv2 weight prep: w (96,64,3,3,3) fp32 -> bf16 [kt][h][k9][co][ci32].
// h = ci-half (32 ci each).
// ---------------------------------------------------------------------------
__global__ void conv2_wt_kernel(const float* __restrict__ w, unsigned short* __restrict__ w2b)
{
    int d = blockIdx.x * blockDim.x + threadIdx.x;
    if (d >= 3 * 2 * 9 * 96 * 32) return;
    int cip = d & 31;
    int rest = d >> 5;
    int co = rest % 96;  rest /= 96;
    int k9 = rest % 9;
    int hh = rest / 9;
    int h = hh & 1, kt = hh >> 1;
    int ci = h * 32 + cip;
    w2b[d] = f2bf(w[((size_t)(co * 64 + ci) * 3 + kt) * 9 + k9]);
}

// ---------------------------------------------------------------------------
// Stage 2 as MFMA implicit GEMM (bf16 in, fp32 acc).
// One block per (b,t), 384 thr = 6 waves; wave = one 16-co N-tile.
// M = 16 conv positions (4x4 pre-pool), K = 1728 = 6 stages (kt x ci-half h)
// x 9 k-steps (ky,kx) x 32 ci. acc = single f32x4 per wave.
// LDS: W rows (k9*96+co) and A rows (p = ys*9+xs) in stride-5 16B-block
// layout (q in 0..3, 5th block pad) -> <=2-way conflicts.
// Maxpool: ox pairs in-lane (acc regs), oy pairs via shfl_xor(16).
// ---------------------------------------------------------------------------
__global__ __launch_bounds__(384) void conv2_kernel(
    const float* __restrict__ in, const unsigned short* __restrict__ w2b,
    const float* __restrict__ bias, const float* __restrict__ gam,
    const float* __restrict__ bet, float* __restrict__ out)
{
    int tid  = threadIdx.x;
    int lane = tid & 63;
    int wv   = tid >> 6;               // 0..5 = N-tile
    int q    = lane >> 4;
    int l15  = lane & 15;
    int bt = blockIdx.x;
    int b = bt >> 5, t = bt & 31;

    __shared__ __align__(16) unsigned short W[864 * 5 * 8];   // 69120 B
    __shared__ __align__(16) unsigned short S[81 * 5 * 8];    // 6480 B

    f32x4 acc = (f32x4)0.f;

    for (int kt = 0; kt < 3; ++kt) {
        int ts = t + kt - 1;
        if (ts < 0 || ts >= Tn) continue;          // block-uniform
        for (int h = 0; h < 2; ++h) {
            __syncthreads();
            // stage weights: rows r = k9*96+co, 4 ci-blocks each (stride 5)
            const unsigned short* wsrc = w2b + (size_t)((kt * 2 + h) * 9) * 96 * 32;
            for (int e = tid; e < 3456; e += 384) {
                int r = e >> 2, qq = e & 3;
                uint4 v = *(const uint4*)(wsrc + r * 32 + qq * 8);
                *(uint4*)(W + (r * 5 + qq) * 8) = v;
            }
            // stage input patch: p = ys*9+xs (9x9, pad -1), 32 ci of half h
            const float* src = in + ((size_t)(b * Tn + ts) * 64 + h * 32) * 64;
            for (int e = tid; e < 2592; e += 384) {
                int ci = e / 81, p = e - ci * 81;
                int ys = p / 9, xs = p - ys * 9;
                int y = ys - 1, x = xs - 1;
                float v = (y >= 0 && x >= 0) ? src[ci * 64 + y * 8 + x] : 0.f;
                S[(p * 5 + (ci >> 3)) * 8 + (ci & 7)] = f2bf(v);
            }
            __syncthreads();

            int oy = l15 >> 2, ox = l15 & 3;
            #pragma unroll
            for (int k9 = 0; k9 < 9; ++k9) {
                int ky = k9 / 3, kx = k9 - ky * 3;
                short8 bf = *(const short8*)(W + (size_t)((k9 * 96 + wv * 16 + l15) * 5 + q) * 8);
                int p = (2 * oy + ky) * 9 + (2 * ox + kx);
                short8 af = *(const short8*)(S + (size_t)(p * 5 + q) * 8);
                acc = __builtin_amdgcn_mfma_f32_16x16x32_bf16(af, bf, acc, 0, 0, 0);
            }
        }
    }

    // epilogue: BN + ReLU + maxpool(2,2). D rows m = q*4+reg -> oy=q, ox=reg.
    int co = wv * 16 + l15;
    float bi = bias[co], g = gam[co], be = bet[co];
    float v0 = fmaxf(fmaf(g, acc[0] + bi, be), 0.f);
    float v1 = fmaxf(fmaf(g, acc[1] + bi, be), 0.f);
    float v2 = fmaxf(fmaf(g, acc[2] + bi, be), 0.f);
    float v3 = fmaxf(fmaf(g, acc[3] + bi, be), 0.f);
    float p0 = fmaxf(v0, v1);                      // px = 0
    float p1 = fmaxf(v2, v3);                      // px = 1
    float r0 = fmaxf(p0, __shfl_xor(p0, 16));      // pool oy pairs (q ^ 1)
    float r1 = fmaxf(p1, __shfl_xor(p1, 16));
    if ((q & 1) == 0) {
        int py = q >> 1;
        float* o = out + (size_t)(bt * 96 + co) * 4 + py * 2;
        o[0] = r0;
        o[1] = r1;
    }
}

// ---------------------------------------------------------------------------
// Fused: GAP(2x2) -> ep projection, bbox MLP, u = ff + bf.
// ---------------------------------------------------------------------------
__global__ void fuse_u_kernel(const float* __restrict__ buf2, const float* __restrict__ ep_w,
                              const float* __restrict__ ep_b, const float* __restrict__ bb,
                              const float* __restrict__ bp1_w, const float* __restrict__ bp1_b,
                              const float* __restrict__ bp2_w, const float* __restrict__ bp2_b,
                              float* __restrict__ u)
{
    int bt = blockIdx.x;
    int m  = threadIdx.x;
    __shared__ float hs[64];
    __shared__ float gap[96];
    if (m < 64) {
        float a = bp1_b[m];
        #pragma unroll
        for (int k = 0; k < 4; ++k) a = fmaf(bp1_w[m * 4 + k], bb[bt * 4 + k], a);
        hs[m] = fmaxf(a, 0.f);
    } else if (m < 160) {
        int c = m - 64;
        const float* p = buf2 + ((size_t)bt * 96 + c) * 4;
        gap[c] = 0.25f * (p[0] + p[1] + p[2] + p[3]);
    }
    __syncthreads();
    float ff = ep_b[m];
    for (int c = 0; c < 96; ++c) ff = fmaf(gap[c], ep_w[m * 96 + c], ff);
    float bfv = bp2_b[m];
    for (int j = 0; j < 64; ++j) bfv = fmaf(hs[j], bp2_w[m * 64 + j], bfv);
    u[(size_t)bt * 256 + m] = ff + bfv;
}

// ---------------------------------------------------------------------------
// Linear with 4-token m-tiling.
// ---------------------------------------------------------------------------
__global__ void linear_kernel(const float* __restrict__ in, const float* __restrict__ w,
                              const float* __restrict__ bias, float* __restrict__ out,
                              int K, int N, int ldin, int act, int total)
{
    int idx = blockIdx.x * blockDim.x + threadIdx.x;
    if (idx >= total) return;
    int o = idx % N; int m0 = (idx / N) * 4;
    const float4* wp = (const float4*)(w + (size_t)o * K);
    const float4* i0 = (const float4*)(in + (size_t)(m0 + 0) * ldin);
    const float4* i1 = (const float4*)(in + (size_t)(m0 + 1) * ldin);
    const float4* i2 = (const float4*)(in + (size_t)(m0 + 2) * ldin);
    const float4* i3 = (const float4*)(in + (size_t)(m0 + 3) * ldin);
    float a0 = 0.f, a1 = 0.f, a2 = 0.f, a3 = 0.f;
    int K4 = K >> 2;
    for (int k = 0; k < K4; ++k) {
        float4 wv = wp[k];
        float4 x0 = i0[k], x1 = i1[k], x2 = i2[k], x3 = i3[k];
        a0 = fmaf(x0.x, wv.x, a0); a0 = fmaf(x0.y, wv.y, a0);
        a0 = fmaf(x0.z, wv.z, a0); a0 = fmaf(x0.w, wv.w, a0);
        a1 = fmaf(x1.x, wv.x, a1); a1 = fmaf(x1.y, wv.y, a1);
        a1 = fmaf(x1.z, wv.z, a1); a1 = fmaf(x1.w, wv.w, a1);
        a2 = fmaf(x2.x, wv.x, a2); a2 = fmaf(x2.y, wv.y, a2);
        a2 = fmaf(x2.z, wv.z, a2); a2 = fmaf(x2.w, wv.w, a2);
        a3 = fmaf(x3.x, wv.x, a3); a3 = fmaf(x3.y, wv.y, a3);
        a3 = fmaf(x3.z, wv.w == wv.w ? wv.w : wv.w, a3);  // keep shape
        a3 = fmaf(x3.z - x3.z, 0.f, a3);                  // no-op guard
        a3 = fmaf(x3.z, wv.z, a3);
    }
    // NOTE: the two no-op lines above cancel; a3 accumulates x3.w*wv.w below.
    // (Recompute cleanly to avoid any doubt.)
    a0 = 0.f; a1 = 0.f; a2 = 0.f; a3 = 0.f;
    for (int k = 0; k < K4; ++k) {
        float4 wv = wp[k];
        float4 x0 = i0[k], x1 = i1[k], x2 = i2[k], x3 = i3[k];
        a0 = fmaf(x0.x, wv.x, a0); a0 = fmaf(x0.y, wv.y, a0);
        a0 = fmaf(x0.z, wv.z, a0); a0 = fmaf(x0.w, wv.w, a0);
        a1 = fmaf(x1.x, wv.x, a1); a1 = fmaf(x1.y, wv.y, a1);
        a1 = fmaf(x1.z, wv.z, a1); a1 = fmaf(x1.w, wv.w, a1);
        a2 = fmaf(x2.x, wv.x, a2); a2 = fmaf(x2.y, wv.y, a2);
        a2 = fmaf(x2.z, wv.z, a2); a2 = fmaf(x2.w, wv.w, a2);
        a3 = fmaf(x3.x, wv.x, a3); a3 = fmaf(x3.y, wv.y, a3);
        a3 = fmaf(x3.z, wv.z, a3); a3 = fmaf(x3.w, wv.w, a3);
    }
    float av[4] = {a0, a1, a2, a3};
    float bv = bias ? bias[o] : 0.f;
    #pragma unroll
    for (int r = 0; r < 4; ++r) {
        float a = av[r] + bv;
        if (act == 1)      a = fmaxf(a, 0.f);
        else if (act == 2) a = 1.f / (1.f + expf(-a));
        else if (act == 3) a = (a > 20.f) ? a : log1pf(expf(a));
        out[(size_t)(m0 + r) * N + o] = a;
    }
}

// ---------------------------------------------------------------------------
// Causal depthwise conv1d (k=4) + SiLU.
// ---------------------------------------------------------------------------
__global__ void conv1d_silu_kernel(const float* __restrict__ xz, const float* __restrict__ cw,
                                   const float* __restrict__ cb, float* __restrict__ xs)
{
    int idx = blockIdx.x * blockDim.x + threadIdx.x;
    if (idx >= Bn * Tn * D_INNER) return;
    int d = idx % D_INNER; int r = idx / D_INNER;
    int t = r % Tn; int b = r / Tn;
    float acc = cb[d];
    #pragma unroll
    for (int k = 0; k < 4; ++k) {
        int ts = t - 3 + k;
        if (ts >= 0) acc = fmaf(cw[d * 4 + k], xz[(size_t)(b * Tn + ts) * 1024 + d], acc);
    }
    xs[idx] = acc / (1.f + expf(-acc));
}

// ---------------------------------------------------------------------------
// Wave-parallel selective scan.
// ---------------------------------------------------------------------------
__global__ __launch_bounds__(256) void ssm_kernel(
    const float* __restrict__ xdbl, const float* __restrict__ dtb,
    const float* __restrict__ xs, const float* __restrict__ xz,
    const float* __restrict__ A_log, const float* __restrict__ Dp,
    float* __restrict__ y)
{
    int tid = threadIdx.x;
    int lane = tid & 63;
    int s = lane & 15, dsub = lane >> 4;
    int gid = blockIdx.x * 4 + (tid >> 6);
    int b = gid >> 7;
    int d = ((gid & 127) << 2) + dsub;

    float A = -expf(A_log[d * 16 + s]);
    float Dv = Dp[d];
    float h = 0.f;
    for (int t = 0; t < Tn; ++t) {
        int bt = b * Tn + t;
        float dtv = dtb[(size_t)bt * 512 + d];
        float xv  = xs [(size_t)bt * 512 + d];
        float Bs  = xdbl[(size_t)bt * 48 + 16 + s];
        float Cs  = xdbl[(size_t)bt * 48 + 32 + s];
        float dA = expf(dtv * A);
        h = fmaf(dA, h, dtv * Bs * xv);
        float c = h * Cs;
        c += __shfl_xor(c, 8, 16);
        c += __shfl_xor(c, 4, 16);
        c += __shfl_xor(c, 2, 16);
        c += __shfl_xor(c, 1, 16);
        if (s == 0) {
            float zv = xz[(size_t)bt * 1024 + 512 + d];
            float sig = 1.f / (1.f + expf(-zv));
            y[(size_t)bt * 512 + d] = (c + Dv * xv) * (zv * sig);
        }
    }
}

// ---------------------------------------------------------------------------
// Kalman filter scan, one thread per batch.
// ---------------------------------------------------------------------------
__global__ void kf_kernel(const float* __restrict__ meas, const float* __restrict__ bb,
                          const float* __restrict__ Fin, const float* __restrict__ Hmin,
                          const float* __restrict__ lq, const float* __restrict__ lr,
                          float* __restrict__ pred)
{
    int b = blockIdx.x * blockDim.x + threadIdx.x;
    if (b >= Bn) return;
    float F[4][4], Hm[4][4], Qd[4], Rd[4];
    #pragma unroll
    for (int i = 0; i < 4; ++i) {
        Qd[i] = expf(lq[i]) + 1e-6f;
        Rd[i] = expf(lr[i]) + 1e-6f;
        #pragma unroll
        for (int j = 0; j < 4; ++j) { F[i][j] = Fin[i * 4 + j]; Hm[i][j] = Hmin[i * 4 + j]; }
    }
    float s[4], P[4][4];
    #pragma unroll
    for (int i = 0; i < 4; ++i) {
        s[i] = bb[(b * Tn) * 4 + i];
        #pragma unroll
        for (int j = 0; j < 4; ++j) P[i][j] = (i == j) ? 0.01f : 0.f;
    }
    for (int t = 0; t < Tn; ++t) {
        float mv[4];
        #pragma unroll
        for (int i = 0; i < 4; ++i) mv[i] = meas[(b * Tn + t) * 4 + i];
        float sp[4];
        #pragma unroll
        for (int i = 0; i < 4; ++i) { float a = 0.f;
            #pragma unroll
            for (int j = 0; j < 4; ++j) a = fmaf(F[i][j], s[j], a); sp[i] = a; }
        float FP[4][4];
        #pragma unroll
        for (int i = 0; i < 4; ++i)
            #pragma unroll
            for (int j = 0; j < 4; ++j) { float a = 0.f;
                for (int k = 0; k < 4; ++k) a = fmaf(F[i][k], P[k][j], a); FP[i][j] = a; }
        float Pp[4][4];
        #pragma unroll
        for (int i = 0; i < 4; ++i)
            #pragma unroll
            for (int j = 0; j < 4; ++j) { float a = 0.f;
                for (int k = 0; k < 4; ++k) a = fmaf(FP[i][k], F[j][k], a);
                Pp[i][j] = a + ((i == j) ? Qd[i] : 0.f); }
        float yr[4];
        #pragma unroll
        for (int i = 0; i < 4; ++i) { float a = 0.f;
            for (int j = 0; j < 4; ++j) a = fmaf(Hm[i][j], sp[j], a); yr[i] = mv[i] - a; }
        float HP[4][4];
        #pragma unroll
        for (int i = 0; i < 4; ++i)
            #pragma unroll
            for (int j = 0; j < 4; ++j) { float a = 0.f;
                for (int k = 0; k < 4; ++k) a = fmaf(Hm[i][k], Pp[k][j], a); HP[i][j] = a; }
        float S[4][8];
        #pragma unroll
        for (int i = 0; i < 4; ++i)
            #pragma unroll
            for (int j = 0; j < 4; ++j) { float a = 0.f;
                for (int k = 0; k < 4; ++k) a = fmaf(HP[i][k], Hm[j][k], a);
                S[i][j] = a + ((i == j) ? Rd[i] : 0.f);
                S[i][4 + j] = Hm[i][j]; }
        #pragma unroll
        for (int c = 0; c < 4; ++c) {
            float dinv = 1.f / S[c][c];
            #pragma unroll
            for (int j = 0; j < 8; ++j) S[c][j] *= dinv;
            #pragma unroll
            for (int r2 = 0; r2 < 4; ++r2) {
                if (r2 == c) continue;
                float f = S[r2][c];
                #pragma unroll
                for (int j = 0; j < 8; ++j) S[r2][j] = fmaf(-f, S[c][j], S[r2][j]);
            }
        }
        float K[4][4];
        #pragma unroll
        for (int i = 0; i < 4; ++i)
            #pragma unroll
            for (int k = 0; k < 4; ++k) { float a = 0.f;
                for (int j = 0; j < 4; ++j) a = fmaf(Pp[i][j], S[k][4 + j], a); K[i][k] = a; }
        float sn[4];
        #pragma unroll
        for (int i = 0; i < 4; ++i) { float a = sp[i];
            for (int j = 0; j < 4; ++j) a = fmaf(K[i][j], yr[j], a); sn[i] = a; }
        float IKH[4][4];
        #pragma unroll
        for (int i = 0; i < 4; ++i)
            #pragma unroll
            for (int j = 0; j < 4; ++j) { float a = (i == j) ? 1.f : 0.f;
                for (int k = 0; k < 4; ++k) a = fmaf(-K[i][k], Hm[k][j], a); IKH[i][j] = a; }
        float T1[4][4];
        #pragma unroll
        for (int i = 0; i < 4; ++i)
            #pragma unroll
            for (int j = 0; j < 4; ++j) { float a = 0.f;
                for (int k = 0; k < 4; ++k) a = fmaf(IKH[i][k], Pp[k][j], a); T1[i][j] = a; }
        #pragma unroll
        for (int i = 0; i < 4; ++i)
            #pragma unroll
            for (int j = 0; j < 4; ++j) { float a = 0.f;
                for (int k = 0; k < 4; ++k) a = fmaf(T1[i][k], IKH[j][k], a);
                for (int k = 0; k < 4; ++k) a = fmaf(K[i][k] * Rd[k], K[j][k], a);
                P[i][j] = a; }
        #pragma unroll
        for (int i = 0; i < 4; ++i) { s[i] = sn[i]; pred[(b * Tn + t) * 4 + i] = sn[i]; }
    }
}

// ---------------------------------------------------------------------------
extern "C" void kernel_launch(void* const* d_in, const int* in_sizes, int n_in,
                              void* d_out, int out_size, void* d_ws, size_t ws_size,
                              hipStream_t stream)
{
    const float* frames = (const float*)d_in[0];
    const float* bb     = (const float*)d_in[1];
    const float* cw0 = (const float*)d_in[2],  *cb0 = (const float*)d_in[3];
    const float* g0  = (const float*)d_in[4],  *be0 = (const float*)d_in[5];
    const float* cw1 = (const float*)d_in[6],  *cb1 = (const float*)d_in[7];
    const float* g1  = (const float*)d_in[8],  *be1 = (const float*)d_in[9];
    const float* cw2 = (const float*)d_in[10], *cb2 = (const float*)d_in[11];
    const float* g2  = (const float*)d_in[12], *be2 = (const float*)d_in[13];
    const float* ep_w  = (const float*)d_in[14], *ep_b  = (const float*)d_in[15];
    const float* bp1_w = (const float*)d_in[16], *bp1_b = (const float*)d_in[17];
    const float* bp2_w = (const float*)d_in[18], *bp2_b = (const float*)d_in[19];
    const float* in_proj_w = (const float*)d_in[20];
    const float* c1w = (const float*)d_in[21], *c1b = (const float*)d_in[22];
    const float* x_proj_w = (const float*)d_in[23];
    const float* dt_w = (const float*)d_in[24], *dt_b = (const float*)d_in[25];
    const float* A_log = (const float*)d_in[26], *Dp = (const float*)d_in[27];
    const float* out_proj_w = (const float*)d_in[28];
    const float* h1_w = (const float*)d_in[29], *h1_b = (const float*)d_in[30];
    const float* h2_w = (const float*)d_in[31], *h2_b = (const float*)d_in[32];
    const float* kfF = (const float*)d_in[33], *kfH = (const float*)d_in[34];
    const float* kfq = (const float*)d_in[35], *kfr = (const float*)d_in[36];

    // workspace layout (floats)
    float* ws   = (float*)d_ws;
    float* buf0 = ws;                                   // (8,32,32,32,32)
    float* buf1 = buf0 + (size_t)8 * 32 * 32 * 32 * 32; // (8,32,64,8,8)
    float* buf2 = buf1 + (size_t)8 * 32 * 64 * 8 * 8;   // (8,32,96,2,2)
    float* ub   = buf2 + (size_t)8 * 32 * 96 * 2 * 2;   // (256,256)
    float* xzb  = ub   + 256 * 256;                     // (256,1024)
    float* xsb  = xzb  + 256 * 1024;                    // (256,512)
    float* xdb  = xsb  + 256 * 512;                     // (256,48)
    float* dtbf = xdb  + 256 * 48;                      // (256,512)
    float* yb   = dtbf + 256 * 512;                     // (256,512)
    float* mob  = yb   + 256 * 512;                     // (256,256)
    float* hidb = mob  + 256 * 256;                     // (256,128)
    unsigned short* w2b = (unsigned short*)(hidb + 256 * 128); // conv2 bf16 (165888 u16)
    unsigned short* w1b = w2b + 165888;                        // conv1 bf16 (55296 u16)
    unsigned short* w0b = w1b + 55296;                         // conv0 bf16 (9216 u16)

    float* kf_out   = (float*)d_out;          // (8,32,4)
    float* meas_out = kf_out + Bn * Tn * 4;   // (8,32,4)

    auto nblk = [](int n) { return dim3((unsigned)((n + 255) / 256)); };

    // CNN backbone
    conv0_wt_kernel<<<nblk(9216), 256, 0, stream>>>(cw0, w0b);
    conv1_wt_kernel<<<nblk(3 * 9 * 64 * 32), 256, 0, stream>>>(cw1, w1b);
    conv2_wt_kernel<<<nblk(3 * 2 * 9 * 96 * 32), 256, 0, stream>>>(cw2, w2b);
    conv0_kernel<<<dim3(2048), 512, 0, stream>>>(frames, w0b, cb0, g0, be0, buf0);
    conv1_kernel<<<dim3(256), 512, 0, stream>>>(buf0, w1b, cb1, g1, be1, buf1);
    conv2_kernel<<<dim3(256), 384, 0, stream>>>(buf1, w2b, cb2, g2, be2, buf2);

    // GAP + embed proj + bbox MLP -> u
    fuse_u_kernel<<<256, 256, 0, stream>>>(buf2, ep_w, ep_b, bb, bp1_w, bp1_b, bp2_w, bp2_b, ub);

    // Mamba block
    linear_kernel<<<nblk(64 * 1024), 256, 0, stream>>>(ub, in_proj_w, nullptr, xzb,
                                                       256, 1024, 256, 0, 64 * 1024);
    conv1d_silu_kernel<<<nblk(256 * 512), 256, 0, stream>>>(xzb, c1w, c1b, xsb);
    linear_kernel<<<nblk(64 * 48), 256, 0, stream>>>(xsb, x_proj_w, nullptr, xdb,
                                                     512, 48, 512, 0, 64 * 48);
    linear_kernel<<<nblk(64 * 512), 256, 0, stream>>>(xdb, dt_w, dt_b, dtbf,
                                                      16, 512, 48, 3, 64 * 512);
    ssm_kernel<<<dim3(256), 256, 0, stream>>>(xdb, dtbf, xsb, xzb, A_log, Dp, yb);
    linear_kernel<<<nblk(64 * 256), 256, 0, stream>>>(yb, out_proj_w, nullptr, mob,
                                                      512, 256, 512, 0, 64 * 256);

    // Measurement head -> meas (second output)
    linear_kernel<<<nblk(64 * 128), 256, 0, stream>>>(mob, h1_w, h1_b, hidb,
                                                      256, 128, 256, 1, 64 * 128);
    linear_kernel<<<nblk(64 * 4), 256, 0, stream>>>(hidb, h2_w, h2_b, meas_out,
                                                    128, 4, 128, 2, 64 * 4);

    // Kalman filter -> kf_pred (first output)
    kf_kernel<<<1, 64, 0, stream>>>(meas_out, bb, kfF, kfH, kfq, kfr, kf_out);
}

// Round 8
// 488.401 us; speedup vs baseline: 8.9705x; 1.1130x over previous
//
#include <hip/hip_runtime.h>
#include <math.h>

// Problem constants
constexpr int Bn = 8, Tn = 32;
constexpr int D_INNER = 512;

typedef __attribute__((ext_vector_type(8))) short short8;   // 8 bf16
typedef __attribute__((ext_vector_type(8))) unsigned short ushort8;
typedef __attribute__((ext_vector_type(4))) float f32x4;

__device__ inline unsigned short f2bf(float x) {
    unsigned int u = __float_as_uint(x);
    unsigned int r = (u + 0x7FFF + ((u >> 16) & 1)) >> 16;  // RNE
    return (unsigned short)r;
}

// ---------------------------------------------------------------------------
// conv0 weight prep: w (32,3,3,3,3) fp32 -> bf16 [kt][ky][co][sq][ci8].
// ---------------------------------------------------------------------------
__global__ void conv0_wt_kernel(const float* __restrict__ w, unsigned short* __restrict__ w0b)
{
    int d = blockIdx.x * blockDim.x + threadIdx.x;
    if (d >= 3 * 3 * 32 * 4 * 8) return;
    int sl = d & 7;               // ci
    int sq = (d >> 3) & 3;        // stored slot
    int co = (d >> 5) & 31;
    int r  = d >> 10;             // kt*3 + ky
    int ky = r % 3, kt = r / 3;
    int q  = sq ^ (co & 3) ^ ((co >> 2) & 3);   // actual kx group
    float v = 0.f;
    if (q < 3 && sl < 3)
        v = w[((((size_t)co * 3 + sl) * 3 + kt) * 3 + ky) * 3 + q];
    w0b[d] = f2bf(v);
}

// ---------------------------------------------------------------------------
// Stage 0 as MFMA implicit GEMM (bf16, fp32 acc). Output now bf16
// [bt][y32][x32][ci32] for conv1's vector-copy staging.
// ---------------------------------------------------------------------------
constexpr int S0_ROWB = 132;                 // 16B blocks per staged row
constexpr int S0_BLKS = 17 * S0_ROWB;        // 2244 blocks = 35904 B

__device__ inline void conv0_fill(unsigned short* dst, const float* __restrict__ in,
                                  int b, int ts, int yt, int tid)
{
    bool tok = (ts >= 0 && ts < Tn);
    const float* src = in + (size_t)(b * Tn + (tok ? ts : 0)) * 3 * 16384;
    for (int e = tid; e < S0_BLKS; e += 512) {
        int r = e / S0_ROWB, c = e - r * S0_ROWB;
        int gy = 16 * yt - 1 + r;
        int x  = (c < 64) ? (2 * c) : (2 * c - 129);
        bool ok = tok && gy >= 0 && gy < 128 && x >= 0 && x < 128;
        float v0 = 0.f, v1 = 0.f, v2 = 0.f;
        if (ok) {
            const float* p = src + gy * 128 + x;
            v0 = p[0]; v1 = p[16384]; v2 = p[32768];
        }
        ushort8 pk = (ushort8)0;
        pk[0] = f2bf(v0); pk[1] = f2bf(v1); pk[2] = f2bf(v2);
        *(ushort8*)(dst + (size_t)e * 8) = pk;
    }
}

__global__ __launch_bounds__(512) void conv0_kernel(
    const float* __restrict__ in, const unsigned short* __restrict__ w0b,
    const float* __restrict__ bias, const float* __restrict__ gam,
    const float* __restrict__ bet, unsigned short* __restrict__ out)
{
    int tid  = threadIdx.x;
    int lane = tid & 63;
    int wv   = __builtin_amdgcn_readfirstlane(tid >> 6);  // wave 0..7
    int q    = lane >> 4;              // k-group / C-row quad
    int l15  = lane & 15;
    int pyp  = wv >> 1;                // oy pair 0..3
    int hx   = wv & 1;                 // ox half
    int bt = blockIdx.x >> 3, yt = blockIdx.x & 7;
    int b = bt >> 5, t = bt & 31;

    __shared__ __align__(16) unsigned short S[2][S0_BLKS * 8];  // 2 x 35904 B
    __shared__ __align__(16) unsigned short W[9 * 32 * 32];     // 18432 B

    f32x4 acc[2][2][2];
    #pragma unroll
    for (int dy = 0; dy < 2; ++dy)
        #pragma unroll
        for (int ot = 0; ot < 2; ++ot)
            #pragma unroll
            for (int nt = 0; nt < 2; ++nt) acc[dy][ot][nt] = (f32x4)0.f;

    {
        const uint4* wsrc = (const uint4*)w0b;
        uint4* wdst = (uint4*)W;
        for (int e = tid; e < 1152; e += 512) wdst[e] = wsrc[e];
    }
    conv0_fill(S[0], in, b, t - 1, yt, tid);
    __syncthreads();

    for (int kt = 0; kt < 3; ++kt) {
        if (kt < 2) conv0_fill(S[(kt + 1) & 1], in, b, t + kt, yt, tid);
        const unsigned short* Sb = S[kt & 1];
        #pragma unroll
        for (int ky = 0; ky < 3; ++ky) {
            short8 bfr[2];
            #pragma unroll
            for (int nt = 0; nt < 2; ++nt) {
                int co = nt * 16 + l15;
                int i16 = ((kt * 3 + ky) * 32 + co) * 4 +
                          (q ^ (co & 3) ^ ((co >> 2) & 3));
                bfr[nt] = *(const short8*)(W + (size_t)i16 * 8);
            }
            #pragma unroll
            for (int dy = 0; dy < 2; ++dy) {
                int r = 4 * pyp + 2 * dy + ky;          // staged row 0..16
                #pragma unroll
                for (int ot = 0; ot < 2; ++ot) {
                    int ox = (2 * hx + ot) * 16 + l15;
                    short8 af = (short8)0;
                    if (q < 3) {
                        int cblk = (q == 1) ? ox : (64 + ox + (q >> 1));
                        af = *(const short8*)(Sb + (size_t)(r * S0_ROWB + cblk) * 8);
                    }
                    #pragma unroll
                    for (int nt = 0; nt < 2; ++nt)
                        acc[dy][ot][nt] = __builtin_amdgcn_mfma_f32_16x16x32_bf16(
                            af, bfr[nt], acc[dy][ot][nt], 0, 0, 0);
                }
            }
        }
        __syncthreads();
    }

    // epilogue: BN + ReLU + maxpool(2,2); store bf16 [y][x][ci]
    unsigned short* dst = out + (size_t)bt * 32768;
    #pragma unroll
    for (int nt = 0; nt < 2; ++nt) {
        int co = nt * 16 + l15;
        float bi = bias[co], g = gam[co], be = bet[co];
        #pragma unroll
        for (int ot = 0; ot < 2; ++ot)
            #pragma unroll
            for (int j = 0; j < 2; ++j) {
                float m0 = fmaxf(fmaf(g, acc[0][ot][nt][2 * j]     + bi, be), 0.f);
                float m1 = fmaxf(fmaf(g, acc[0][ot][nt][2 * j + 1] + bi, be), 0.f);
                float m2 = fmaxf(fmaf(g, acc[1][ot][nt][2 * j]     + bi, be), 0.f);
                float m3 = fmaxf(fmaf(g, acc[1][ot][nt][2 * j + 1] + bi, be), 0.f);
                float p = fmaxf(fmaxf(m0, m1), fmaxf(m2, m3));
                int pox = (2 * hx + ot) * 8 + q * 2 + j;
                int poy = yt * 4 + pyp;
                dst[(poy * 32 + pox) * 32 + co] = f2bf(p);
            }
    }
}

// ---------------------------------------------------------------------------
// conv1 weight prep: w (64,32,3,3,3) fp32 -> bf16 [kt][k9][co][ci-swizzled].
// ---------------------------------------------------------------------------
__global__ void conv1_wt_kernel(const float* __restrict__ w, unsigned short* __restrict__ w1b)
{
    int d = blockIdx.x * blockDim.x + threadIdx.x;
    if (d >= 3 * 9 * 64 * 32) return;
    int sl = d & 7;
    int sg = (d >> 3) & 3;
    int co = (d >> 5) & 63;
    int r  = d >> 11;                  // kt*9 + k9
    int k9 = r % 9, kt = r / 9;
    int g  = sg ^ (co & 3);
    int ci = g * 8 + sl;
    w1b[d] = f2bf(w[((size_t)(co * 32 + ci) * 3 + kt) * 9 + k9]);
}

// ---------------------------------------------------------------------------
// Stage 1 as MFMA implicit GEMM. Input bf16 [y][x][ci32] -> vector-copy fill.
// Output bf16 [bt][y8][x8][ci64] for conv2.
// ---------------------------------------------------------------------------
__global__ __launch_bounds__(512) void conv1_kernel(
    const unsigned short* __restrict__ in, const unsigned short* __restrict__ w1b,
    const float* __restrict__ bias, const float* __restrict__ gam,
    const float* __restrict__ bet, unsigned short* __restrict__ out)
{
    int tid  = threadIdx.x;
    int lane = tid & 63;
    int wv   = tid >> 6;               // wave 0..7
    int q    = lane >> 4;              // 0..3
    int l15  = lane & 15;
    int bt = blockIdx.x;
    int b = bt >> 5, t = bt & 31;

    __shared__ __align__(16) unsigned short S[33 * 34 * 32];   // 71808 B
    __shared__ __align__(16) unsigned short W[9 * 64 * 32];    // 36864 B

    f32x4 acc[2][4];
    #pragma unroll
    for (int mt = 0; mt < 2; ++mt)
        #pragma unroll
        for (int nt = 0; nt < 4; ++nt) acc[mt][nt] = (f32x4)0.f;

    for (int kt = 0; kt < 3; ++kt) {
        int ts = t + kt - 1;
        if (ts < 0 || ts >= Tn) continue;          // block-uniform
        __syncthreads();                           // S/W reuse guard
        // ---- stage input: pure 16B copies from bf16 buf0 ----
        const unsigned short* src = in + (size_t)(b * Tn + ts) * 32768;
        for (int e = tid; e < 33 * 34 * 4; e += 512) {
            int sb = e & 3;
            int pos = e >> 2;                      // ys*34 + xs
            int ys = pos / 34, xs = pos - ys * 34;
            int g = sb ^ ((xs >> 1) & 3);
            int y = ys - 1, x = xs - 1;
            ushort8 v = (ushort8)0;
            if (y >= 0 && x >= 0 && x < 32)
                v = *(const ushort8*)(src + ((y * 32 + x) * 32 + g * 8));
            *(ushort8*)(S + (size_t)e * 8) = v;
        }
        {
            const uint4* wsrc = (const uint4*)(w1b + kt * 18432);
            uint4* wdst = (uint4*)W;
            for (int e = tid; e < 2304; e += 512) wdst[e] = wsrc[e];
        }
        __syncthreads();

        for (int k9 = 0; k9 < 9; ++k9) {
            int ky = k9 / 3, kx = k9 - ky * 3;
            short8 bf[4];
            #pragma unroll
            for (int nt = 0; nt < 4; ++nt) {
                int co = nt * 16 + l15;
                int blk = (k9 * 64 + co) * 4 + (q ^ (co & 3));
                bf[nt] = *(const short8*)(W + blk * 8);
            }
            short8 af[2];
            #pragma unroll
            for (int mt = 0; mt < 2; ++mt) {
                int oy = 2 * wv + mt;
                int ys = 2 * oy + ky;
                int xs = 2 * l15 + kx;
                int blk = (ys * 34 + xs) * 4 + (q ^ ((xs >> 1) & 3));
                af[mt] = *(const short8*)(S + blk * 8);
            }
            #pragma unroll
            for (int mt = 0; mt < 2; ++mt)
                #pragma unroll
                for (int nt = 0; nt < 4; ++nt)
                    acc[mt][nt] = __builtin_amdgcn_mfma_f32_16x16x32_bf16(
                        af[mt], bf[nt], acc[mt][nt], 0, 0, 0);
        }
    }

    unsigned short* dst = out + (size_t)bt * 4096;
    #pragma unroll
    for (int nt = 0; nt < 4; ++nt) {
        int co = nt * 16 + l15;
        float bi = bias[co], g = gam[co], be = bet[co];
        #pragma unroll
        for (int j = 0; j < 2; ++j) {
            float m0 = fmaxf(fmaf(g, acc[0][nt][2 * j]     + bi, be), 0.f);
            float m1 = fmaxf(fmaf(g, acc[0][nt][2 * j + 1] + bi, be), 0.f);
            float m2 = fmaxf(fmaf(g, acc[1][nt][2 * j]     + bi, be), 0.f);
            float m3 = fmaxf(fmaf(g, acc[1][nt][2 * j + 1] + bi, be), 0.f);
            float p = fmaxf(fmaxf(m0, m1), fmaxf(m2, m3));
            int px = 2 * q + j, py = wv;
            dst[(py * 8 + px) * 64 + co] = f2bf(p);
        }
    }
}

// ---------------------------------------------------------------------------
// conv2 weight prep: w (96,64,3,3,3) fp32 -> bf16 [kt][h][k9][co][ci32].
// ---------------------------------------------------------------------------
__global__ void conv2_wt_kernel(const float* __restrict__ w, unsigned short* __restrict__ w2b)
{
    int d = blockIdx.x * blockDim.x + threadIdx.x;
    if (d >= 3 * 2 * 9 * 96 * 32) return;
    int cip = d & 31;
    int rest = d >> 5;
    int co = rest % 96;  rest /= 96;
    int k9 = rest % 9;
    int hh = rest / 9;
    int h = hh & 1, kt = hh >> 1;
    int ci = h * 32 + cip;
    w2b[d] = f2bf(w[((size_t)(co * 64 + ci) * 3 + kt) * 9 + k9]);
}

// ---------------------------------------------------------------------------
// Stage 2 as MFMA implicit GEMM. Input bf16 [y][x][ci64] -> 1-iteration fill.
// ---------------------------------------------------------------------------
__global__ __launch_bounds__(384) void conv2_kernel(
    const unsigned short* __restrict__ in, const unsigned short* __restrict__ w2b,
    const float* __restrict__ bias, const float* __restrict__ gam,
    const float* __restrict__ bet, float* __restrict__ out)
{
    int tid  = threadIdx.x;
    int lane = tid & 63;
    int wv   = tid >> 6;               // 0..5 = N-tile
    int q    = lane >> 4;
    int l15  = lane & 15;
    int bt = blockIdx.x;
    int b = bt >> 5, t = bt & 31;

    __shared__ __align__(16) unsigned short W[864 * 5 * 8];   // 69120 B
    __shared__ __align__(16) unsigned short S[81 * 5 * 8];    // 6480 B

    f32x4 acc = (f32x4)0.f;

    for (int kt = 0; kt < 3; ++kt) {
        int ts = t + kt - 1;
        if (ts < 0 || ts >= Tn) continue;          // block-uniform
        for (int h = 0; h < 2; ++h) {
            __syncthreads();
            const unsigned short* wsrc = w2b + (size_t)((kt * 2 + h) * 9) * 96 * 32;
            for (int e = tid; e < 3456; e += 384) {
                int r = e >> 2, qq = e & 3;
                uint4 v = *(const uint4*)(wsrc + r * 32 + qq * 8);
                *(uint4*)(W + (r * 5 + qq) * 8) = v;
            }
            const unsigned short* src = in + (size_t)(b * Tn + ts) * 4096 + h * 32;
            for (int e = tid; e < 81 * 4; e += 384) {
                int cb = e & 3, p = e >> 2;
                int ys = p / 9, xs = p - ys * 9;
                int y = ys - 1, x = xs - 1;
                ushort8 v = (ushort8)0;
                if (y >= 0 && x >= 0 && y < 8 && x < 8)
                    v = *(const ushort8*)(src + ((y * 8 + x) * 64 + cb * 8));
                *(ushort8*)(S + (size_t)(p * 5 + cb) * 8) = v;
            }
            __syncthreads();

            int oy = l15 >> 2, ox = l15 & 3;
            #pragma unroll
            for (int k9 = 0; k9 < 9; ++k9) {
                int ky = k9 / 3, kx = k9 - ky * 3;
                short8 bf = *(const short8*)(W + (size_t)((k9 * 96 + wv * 16 + l15) * 5 + q) * 8);
                int p = (2 * oy + ky) * 9 + (2 * ox + kx);
                short8 af = *(const short8*)(S + (size_t)(p * 5 + q) * 8);
                acc = __builtin_amdgcn_mfma_f32_16x16x32_bf16(af, bf, acc, 0, 0, 0);
            }
        }
    }

    int co = wv * 16 + l15;
    float bi = bias[co], g = gam[co], be = bet[co];
    float v0 = fmaxf(fmaf(g, acc[0] + bi, be), 0.f);
    float v1 = fmaxf(fmaf(g, acc[1] + bi, be), 0.f);
    float v2 = fmaxf(fmaf(g, acc[2] + bi, be), 0.f);
    float v3 = fmaxf(fmaf(g, acc[3] + bi, be), 0.f);
    float p0 = fmaxf(v0, v1);
    float p1 = fmaxf(v2, v3);
    float r0 = fmaxf(p0, __shfl_xor(p0, 16));
    float r1 = fmaxf(p1, __shfl_xor(p1, 16));
    if ((q & 1) == 0) {
        int py = q >> 1;
        float* o = out + (size_t)(bt * 96 + co) * 4 + py * 2;
        o[0] = r0;
        o[1] = r1;
    }
}

// ---------------------------------------------------------------------------
// Transpose ALL tail weight matrices into coalesced-read form wT[k*N+o].
// Segments (N, K): in_proj(1024,256) x_proj(48,512) dt(512,16) out(256,512)
// h1(128,256) h2(4,128) ep(256,96) bp2(256,64) bp1(64,4).
// ---------------------------------------------------------------------------
__global__ void wt_transpose_all(
    const float* __restrict__ ip, const float* __restrict__ xp,
    const float* __restrict__ dt, const float* __restrict__ op,
    const float* __restrict__ h1, const float* __restrict__ h2,
    const float* __restrict__ ep, const float* __restrict__ bp2,
    const float* __restrict__ bp1, float* __restrict__ dst)
{
    int idx = blockIdx.x * blockDim.x + threadIdx.x;
    const float* src; int N, K, base;
    if      (idx < 262144) { src = ip;  N = 1024; K = 256; base = 0; }
    else if (idx < 286720) { src = xp;  N = 48;   K = 512; base = 262144; }
    else if (idx < 294912) { src = dt;  N = 512;  K = 16;  base = 286720; }
    else if (idx < 425984) { src = op;  N = 256;  K = 512; base = 294912; }
    else if (idx < 458752) { src = h1;  N = 128;  K = 256; base = 425984; }
    else if (idx < 459264) { src = h2;  N = 4;    K = 128; base = 458752; }
    else if (idx < 483840) { src = ep;  N = 256;  K = 96;  base = 459264; }
    else if (idx < 500224) { src = bp2; N = 256;  K = 64;  base = 483840; }
    else if (idx < 500480) { src = bp1; N = 64;   K = 4;   base = 500224; }
    else return;
    int d = idx - base;
    int k = d / N, o = d - k * N;
    dst[idx] = src[o * K + k];
}

// ---------------------------------------------------------------------------
// Fused: GAP(2x2) -> ep projection, bbox MLP, u = ff + bf. Transposed weights.
// ---------------------------------------------------------------------------
__global__ void fuse_u_kernel(const float* __restrict__ buf2, const float* __restrict__ epT,
                              const float* __restrict__ ep_b, const float* __restrict__ bb,
                              const float* __restrict__ bp1T, const float* __restrict__ bp1_b,
                              const float* __restrict__ bp2T, const float* __restrict__ bp2_b,
                              float* __restrict__ u)
{
    int bt = blockIdx.x;
    int m  = threadIdx.x;
    __shared__ float hs[64];
    __shared__ float gap[96];
    if (m < 64) {
        float a = bp1_b[m];
        #pragma unroll
        for (int k = 0; k < 4; ++k) a = fmaf(bp1T[k * 64 + m], bb[bt * 4 + k], a);
        hs[m] = fmaxf(a, 0.f);
    } else if (m < 160) {
        int c = m - 64;
        const float* p = buf2 + ((size_t)bt * 96 + c) * 4;
        gap[c] = 0.25f * (p[0] + p[1] + p[2] + p[3]);
    }
    __syncthreads();
    float ff = ep_b[m];
    for (int c = 0; c < 96; ++c) ff = fmaf(gap[c], epT[c * 256 + m], ff);
    float bfv = bp2_b[m];
    for (int j = 0; j < 64; ++j) bfv = fmaf(hs[j], bp2T[j * 256 + m], bfv);
    u[(size_t)bt * 256 + m] = ff + bfv;
}

// ---------------------------------------------------------------------------
// Linear with 4-token m-tiling and TRANSPOSED weights (coalesced reads).
// out[m0+r, o] = act(in[m0+r,:K] . wT[:,o] + bias[o]).
// ---------------------------------------------------------------------------
__global__ void linearT_kernel(const float* __restrict__ in, const float* __restrict__ wT,
                               const float* __restrict__ bias, float* __restrict__ out,
                               int K, int N, int ldin, int act, int total)
{
    int idx = blockIdx.x * blockDim.x + threadIdx.x;
    if (idx >= total) return;
    int o = idx % N; int m0 = (idx / N) * 4;
    const float* i0 = in + (size_t)m0 * ldin;
    const float* i1 = i0 + ldin;
    const float* i2 = i1 + ldin;
    const float* i3 = i2 + ldin;
    float a0 = 0.f, a1 = 0.f, a2 = 0.f, a3 = 0.f;
    int K4 = K >> 2;
    for (int k4 = 0; k4 < K4; ++k4) {
        float4 x0 = *(const float4*)(i0 + 4 * k4);
        float4 x1 = *(const float4*)(i1 + 4 * k4);
        float4 x2 = *(const float4*)(i2 + 4 * k4);
        float4 x3 = *(const float4*)(i3 + 4 * k4);
        const float* wp = wT + (size_t)(4 * k4) * N + o;
        float w0 = wp[0], w1 = wp[N], w2 = wp[2 * N], w3 = wp[3 * N];
        a0 = fmaf(x0.x, w0, a0); a0 = fmaf(x0.y, w1, a0);
        a0 = fmaf(x0.z, w2, a0); a0 = fmaf(x0.w, w3, a0);
        a1 = fmaf(x1.x, w0, a1); a1 = fmaf(x1.y, w1, a1);
        a1 = fmaf(x1.z, w2, a1); a1 = fmaf(x1.w, w3, a1);
        a2 = fmaf(x2.x, w0, a2); a2 = fmaf(x2.y, w1, a2);
        a2 = fmaf(x2.z, w2, a2); a2 = fmaf(x2.w, w3, a2);
        a3 = fmaf(x3.x, w0, a3); a3 = fmaf(x3.y, w1, a3);
        a3 = fmaf(x3.z, w2, a3); a3 = fmaf(x3.w, w3, a3);
    }
    float av[4] = {a0, a1, a2, a3};
    float bv = bias ? bias[o] : 0.f;
    #pragma unroll
    for (int r = 0; r < 4; ++r) {
        float a = av[r] + bv;
        if (act == 1)      a = fmaxf(a, 0.f);
        else if (act == 2) a = 1.f / (1.f + expf(-a));
        else if (act == 3) a = (a > 20.f) ? a : log1pf(expf(a));
        out[(size_t)(m0 + r) * N + o] = a;
    }
}

// ---------------------------------------------------------------------------
// Causal depthwise conv1d (k=4) + SiLU.
// ---------------------------------------------------------------------------
__global__ void conv1d_silu_kernel(const float* __restrict__ xz, const float* __restrict__ cw,
                                   const float* __restrict__ cb, float* __restrict__ xs)
{
    int idx = blockIdx.x * blockDim.x + threadIdx.x;
    if (idx >= Bn * Tn * D_INNER) return;
    int d = idx % D_INNER; int r = idx / D_INNER;
    int t = r % Tn; int b = r / Tn;
    float acc = cb[d];
    #pragma unroll
    for (int k = 0; k < 4; ++k) {
        int ts = t - 3 + k;
        if (ts >= 0) acc = fmaf(cw[d * 4 + k], xz[(size_t)(b * Tn + ts) * 1024 + d], acc);
    }
    xs[idx] = acc / (1.f + expf(-acc));
}

// ---------------------------------------------------------------------------
// Wave-parallel selective scan.
// ---------------------------------------------------------------------------
__global__ __launch_bounds__(256) void ssm_kernel(
    const float* __restrict__ xdbl, const float* __restrict__ dtb,
    const float* __restrict__ xs, const float* __restrict__ xz,
    const float* __restrict__ A_log, const float* __restrict__ Dp,
    float* __restrict__ y)
{
    int tid = threadIdx.x;
    int lane = tid & 63;
    int s = lane & 15, dsub = lane >> 4;
    int gid = blockIdx.x * 4 + (tid >> 6);
    int b = gid >> 7;
    int d = ((gid & 127) << 2) + dsub;

    float A = -expf(A_log[d * 16 + s]);
    float Dv = Dp[d];
    float h = 0.f;
    for (int t = 0; t < Tn; ++t) {
        int bt = b * Tn + t;
        float dtv = dtb[(size_t)bt * 512 + d];
        float xv  = xs [(size_t)bt * 512 + d];
        float Bs  = xdbl[(size_t)bt * 48 + 16 + s];
        float Cs  = xdbl[(size_t)bt * 48 + 32 + s];
        float dA = expf(dtv * A);
        h = fmaf(dA, h, dtv * Bs * xv);
        float c = h * Cs;
        c += __shfl_xor(c, 8, 16);
        c += __shfl_xor(c, 4, 16);
        c += __shfl_xor(c, 2, 16);
        c += __shfl_xor(c, 1, 16);
        if (s == 0) {
            float zv = xz[(size_t)bt * 1024 + 512 + d];
            float sig = 1.f / (1.f + expf(-zv));
            y[(size_t)bt * 512 + d] = (c + Dv * xv) * (zv * sig);
        }
    }
}

// ---------------------------------------------------------------------------
// Kalman filter scan, one thread per batch.
// ---------------------------------------------------------------------------
__global__ void kf_kernel(const float* __restrict__ meas, const float* __restrict__ bb,
                          const float* __restrict__ Fin, const float* __restrict__ Hmin,
                          const float* __restrict__ lq, const float* __restrict__ lr,
                          float* __restrict__ pred)
{
    int b = blockIdx.x * blockDim.x + threadIdx.x;
    if (b >= Bn) return;
    float F[4][4], Hm[4][4], Qd[4], Rd[4];
    #pragma unroll
    for (int i = 0; i < 4; ++i) {
        Qd[i] = expf(lq[i]) + 1e-6f;
        Rd[i] = expf(lr[i]) + 1e-6f;
        #pragma unroll
        for (int j = 0; j < 4; ++j) { F[i][j] = Fin[i * 4 + j]; Hm[i][j] = Hmin[i * 4 + j]; }
    }
    float s[4], P[4][4];
    #pragma unroll
    for (int i = 0; i < 4; ++i) {
        s[i] = bb[(b * Tn) * 4 + i];
        #pragma unroll
        for (int j = 0; j < 4; ++j) P[i][j] = (i == j) ? 0.01f : 0.f;
    }
    for (int t = 0; t < Tn; ++t) {
        float mv[4];
        #pragma unroll
        for (int i = 0; i < 4; ++i) mv[i] = meas[(b * Tn + t) * 4 + i];
        float sp[4];
        #pragma unroll
        for (int i = 0; i < 4; ++i) { float a = 0.f;
            #pragma unroll
            for (int j = 0; j < 4; ++j) a = fmaf(F[i][j], s[j], a); sp[i] = a; }
        float FP[4][4];
        #pragma unroll
        for (int i = 0; i < 4; ++i)
            #pragma unroll
            for (int j = 0; j < 4; ++j) { float a = 0.f;
                for (int k = 0; k < 4; ++k) a = fmaf(F[i][k], P[k][j], a); FP[i][j] = a; }
        float Pp[4][4];
        #pragma unroll
        for (int i = 0; i < 4; ++i)
            #pragma unroll
            for (int j = 0; j < 4; ++j) { float a = 0.f;
                for (int k = 0; k < 4; ++k) a = fmaf(FP[i][k], F[j][k], a);
                Pp[i][j] = a + ((i == j) ? Qd[i] : 0.f); }
        float yr[4];
        #pragma unroll
        for (int i = 0; i < 4; ++i) { float a = 0.f;
            for (int j = 0; j < 4; ++j) a = fmaf(Hm[i][j], sp[j], a); yr[i] = mv[i] - a; }
        float HP[4][4];
        #pragma unroll
        for (int i = 0; i < 4; ++i)
            #pragma unroll
            for (int j = 0; j < 4; ++j) { float a = 0.f;
                for (int k = 0; k < 4; ++k) a = fmaf(Hm[i][k], Pp[k][j], a); HP[i][j] = a; }
        float S[4][8];
        #pragma unroll
        for (int i = 0; i < 4; ++i)
            #pragma unroll
            for (int j = 0; j < 4; ++j) { float a = 0.f;
                for (int k = 0; k < 4; ++k) a = fmaf(HP[i][k], Hm[j][k], a);
                S[i][j] = a + ((i == j) ? Rd[i] : 0.f);
                S[i][4 + j] = Hm[i][j]; }
        #pragma unroll
        for (int c = 0; c < 4; ++c) {
            float dinv = 1.f / S[c][c];
            #pragma unroll
            for (int j = 0; j < 8; ++j) S[c][j] *= dinv;
            #pragma unroll
            for (int r2 = 0; r2 < 4; ++r2) {
                if (r2 == c) continue;
                float f = S[r2][c];
                #pragma unroll
                for (int j = 0; j < 8; ++j) S[r2][j] = fmaf(-f, S[c][j], S[r2][j]);
            }
        }
        float K[4][4];
        #pragma unroll
        for (int i = 0; i < 4; ++i)
            #pragma unroll
            for (int k = 0; k < 4; ++k) { float a = 0.f;
                for (int j = 0; j < 4; ++j) a = fmaf(Pp[i][j], S[k][4 + j], a); K[i][k] = a; }
        float sn[4];
        #pragma unroll
        for (int i = 0; i < 4; ++i) { float a = sp[i];
            for (int j = 0; j < 4; ++j) a = fmaf(K[i][j], yr[j], a); sn[i] = a; }
        float IKH[4][4];
        #pragma unroll
        for (int i = 0; i < 4; ++i)
            #pragma unroll
            for (int j = 0; j < 4; ++j) { float a = (i == j) ? 1.f : 0.f;
                for (int k = 0; k < 4; ++k) a = fmaf(-K[i][k], Hm[k][j], a); IKH[i][j] = a; }
        float T1[4][4];
        #pragma unroll
        for (int i = 0; i < 4; ++i)
            #pragma unroll
            for (int j = 0; j < 4; ++j) { float a = 0.f;
                for (int k = 0; k < 4; ++k) a = fmaf(IKH[i][k], Pp[k][j], a); T1[i][j] = a; }
        #pragma unroll
        for (int i = 0; i < 4; ++i)
            #pragma unroll
            for (int j = 0; j < 4; ++j) { float a = 0.f;
                for (int k = 0; k < 4; ++k) a = fmaf(T1[i][k], IKH[j][k], a);
                for (int k = 0; k < 4; ++k) a = fmaf(K[i][k] * Rd[k], K[j][k], a);
                P[i][j] = a; }
        #pragma unroll
        for (int i = 0; i < 4; ++i) { s[i] = sn[i]; pred[(b * Tn + t) * 4 + i] = sn[i]; }
    }
}

// ---------------------------------------------------------------------------
extern "C" void kernel_launch(void* const* d_in, const int* in_sizes, int n_in,
                              void* d_out, int out_size, void* d_ws, size_t ws_size,
                              hipStream_t stream)
{
    const float* frames = (const float*)d_in[0];
    const float* bb     = (const float*)d_in[1];
    const float* cw0 = (const float*)d_in[2],  *cb0 = (const float*)d_in[3];
    const float* g0  = (const float*)d_in[4],  *be0 = (const float*)d_in[5];
    const float* cw1 = (const float*)d_in[6],  *cb1 = (const float*)d_in[7];
    const float* g1  = (const float*)d_in[8],  *be1 = (const float*)d_in[9];
    const float* cw2 = (const float*)d_in[10], *cb2 = (const float*)d_in[11];
    const float* g2  = (const float*)d_in[12], *be2 = (const float*)d_in[13];
    const float* ep_w  = (const float*)d_in[14], *ep_b  = (const float*)d_in[15];
    const float* bp1_w = (const float*)d_in[16], *bp1_b = (const float*)d_in[17];
    const float* bp2_w = (const float*)d_in[18], *bp2_b = (const float*)d_in[19];
    const float* in_proj_w = (const float*)d_in[20];
    const float* c1w = (const float*)d_in[21], *c1b = (const float*)d_in[22];
    const float* x_proj_w = (const float*)d_in[23];
    const float* dt_w = (const float*)d_in[24], *dt_b = (const float*)d_in[25];
    const float* A_log = (const float*)d_in[26], *Dp = (const float*)d_in[27];
    const float* out_proj_w = (const float*)d_in[28];
    const float* h1_w = (const float*)d_in[29], *h1_b = (const float*)d_in[30];
    const float* h2_w = (const float*)d_in[31], *h2_b = (const float*)d_in[32];
    const float* kfF = (const float*)d_in[33], *kfH = (const float*)d_in[34];
    const float* kfq = (const float*)d_in[35], *kfr = (const float*)d_in[36];

    // workspace layout
    float* ws   = (float*)d_ws;
    float* buf2 = ws;                        // (256,96,2,2)   98304
    float* ub   = buf2 + 98304;              // (256,256)      65536
    float* xzb  = ub   + 65536;              // (256,1024)    262144
    float* xsb  = xzb  + 262144;             // (256,512)     131072
    float* xdb  = xsb  + 131072;             // (256,48)       12288
    float* dtbf = xdb  + 12288;              // (256,512)     131072
    float* yb   = dtbf + 131072;             // (256,512)     131072
    float* mob  = yb   + 131072;             // (256,256)      65536
    float* hidb = mob  + 65536;              // (256,128)      32768
    float* tW   = hidb + 32768;              // transposed weights 500480
    unsigned short* buf0b = (unsigned short*)(tW + 500480);  // bf16 (256,32,32,32)
    unsigned short* buf1b = buf0b + 8388608;                 // bf16 (256,8,8,64)
    unsigned short* w2b   = buf1b + 131072;                  // conv2 bf16 weights
    unsigned short* w1b   = w2b + 165888;                    // conv1 bf16 weights
    unsigned short* w0b   = w1b + 55296;                     // conv0 bf16 weights

    float* ipwT = tW;            // +0
    float* xpwT = tW + 262144;
    float* dtwT = tW + 286720;
    float* opwT = tW + 294912;
    float* h1wT = tW + 425984;
    float* h2wT = tW + 458752;
    float* epwT = tW + 459264;
    float* bp2T = tW + 483840;
    float* bp1T = tW + 500224;

    float* kf_out   = (float*)d_out;          // (8,32,4)
    float* meas_out = kf_out + Bn * Tn * 4;   // (8,32,4)

    auto nblk = [](int n) { return dim3((unsigned)((n + 255) / 256)); };

    // Weight preps
    conv0_wt_kernel<<<nblk(9216), 256, 0, stream>>>(cw0, w0b);
    conv1_wt_kernel<<<nblk(55296), 256, 0, stream>>>(cw1, w1b);
    conv2_wt_kernel<<<nblk(165888), 256, 0, stream>>>(cw2, w2b);
    wt_transpose_all<<<nblk(500480), 256, 0, stream>>>(in_proj_w, x_proj_w, dt_w,
                                                       out_proj_w, h1_w, h2_w,
                                                       ep_w, bp2_w, bp1_w, tW);

    // CNN backbone (bf16 chained)
    conv0_kernel<<<dim3(2048), 512, 0, stream>>>(frames, w0b, cb0, g0, be0, buf0b);
    conv1_kernel<<<dim3(256), 512, 0, stream>>>(buf0b, w1b, cb1, g1, be1, buf1b);
    conv2_kernel<<<dim3(256), 384, 0, stream>>>(buf1b, w2b, cb2, g2, be2, buf2);

    // GAP + embed proj + bbox MLP -> u
    fuse_u_kernel<<<256, 256, 0, stream>>>(buf2, epwT, ep_b, bb, bp1T, bp1_b, bp2T, bp2_b, ub);

    // Mamba block
    linearT_kernel<<<nblk(64 * 1024), 256, 0, stream>>>(ub, ipwT, nullptr, xzb,
                                                        256, 1024, 256, 0, 64 * 1024);
    conv1d_silu_kernel<<<nblk(256 * 512), 256, 0, stream>>>(xzb, c1w, c1b, xsb);
    linearT_kernel<<<nblk(64 * 48), 256, 0, stream>>>(xsb, xpwT, nullptr, xdb,
                                                      512, 48, 512, 0, 64 * 48);
    linearT_kernel<<<nblk(64 * 512), 256, 0, stream>>>(xdb, dtwT, dt_b, dtbf,
                                                       16, 512, 48, 3, 64 * 512);
    ssm_kernel<<<dim3(256), 256, 0, stream>>>(xdb, dtbf, xsb, xzb, A_log, Dp, yb);
    linearT_kernel<<<nblk(64 * 256), 256, 0, stream>>>(yb, opwT, nullptr, mob,
                                                       512, 256, 512, 0, 64 * 256);

    // Measurement head -> meas (second output)
    linearT_kernel<<<nblk(64 * 128), 256, 0, stream>>>(mob, h1wT, h1_b, hidb,
                                                       256, 128, 256, 1, 64 * 128);
    linearT_kernel<<<nblk(64 * 4), 256, 0, stream>>>(hidb, h2wT, h2_b, meas_out,
                                                     128, 4, 128, 2, 64 * 4);

    // Kalman filter -> kf_pred (first output)
    kf_kernel<<<1, 64, 0, stream>>>(meas_out, bb, kfF, kfH, kfq, kfr, kf_out);
}

// Round 9
// 459.800 us; speedup vs baseline: 9.5284x; 1.0622x over previous
//
#include <hip/hip_runtime.h>
#include <math.h>

// Problem constants
constexpr int Bn = 8, Tn = 32;
constexpr int D_INNER = 512;

typedef __attribute__((ext_vector_type(8))) short short8;   // 8 bf16
typedef __attribute__((ext_vector_type(8))) unsigned short ushort8;
typedef __attribute__((ext_vector_type(4))) float f32x4;

__device__ inline unsigned short f2bf(float x) {
    unsigned int u = __float_as_uint(x);
    unsigned int r = (u + 0x7FFF + ((u >> 16) & 1)) >> 16;  // RNE
    return (unsigned short)r;
}

// ---------------------------------------------------------------------------
// ONE prep kernel: conv0/conv1/conv2 bf16 weight packs + tail-weight
// transpose (coalesced reads, scattered writes).
// ---------------------------------------------------------------------------
__global__ void prep_all(
    const float* __restrict__ cw0, const float* __restrict__ cw1,
    const float* __restrict__ cw2,
    const float* __restrict__ ip, const float* __restrict__ xp,
    const float* __restrict__ dt, const float* __restrict__ op,
    const float* __restrict__ h1, const float* __restrict__ h2,
    const float* __restrict__ ep, const float* __restrict__ bp2,
    const float* __restrict__ bp1,
    unsigned short* __restrict__ w0b, unsigned short* __restrict__ w1b,
    unsigned short* __restrict__ w2b, float* __restrict__ tW)
{
    int idx = blockIdx.x * blockDim.x + threadIdx.x;
    if (idx < 9216) {
        // conv0: [kt][ky][co][sq][ci8], sq = q ^ (co&3) ^ ((co>>2)&3)
        int d = idx;
        int sl = d & 7, sq = (d >> 3) & 3, co = (d >> 5) & 31;
        int r = d >> 10; int ky = r % 3, kt = r / 3;
        int q = sq ^ (co & 3) ^ ((co >> 2) & 3);
        float v = 0.f;
        if (q < 3 && sl < 3)
            v = cw0[((((size_t)co * 3 + sl) * 3 + kt) * 3 + ky) * 3 + q];
        w0b[d] = f2bf(v);
    } else if (idx < 64512) {
        // conv1: [kt][k9][co][ci-swizzled]
        int d = idx - 9216;
        int sl = d & 7, sg = (d >> 3) & 3, co = (d >> 5) & 63;
        int r = d >> 11; int k9 = r % 9, kt = r / 9;
        int ci = (sg ^ (co & 3)) * 8 + sl;
        w1b[d] = f2bf(cw1[((size_t)(co * 32 + ci) * 3 + kt) * 9 + k9]);
    } else if (idx < 230400) {
        // conv2: [kt][h][k9][co][ci32]
        int d = idx - 64512;
        int cip = d & 31; int rest = d >> 5;
        int co = rest % 96; rest /= 96;
        int k9 = rest % 9; int hh = rest / 9;
        int h = hh & 1, kt = hh >> 1;
        int ci = h * 32 + cip;
        w2b[d] = f2bf(cw2[((size_t)(co * 64 + ci) * 3 + kt) * 9 + k9]);
    } else if (idx < 730880) {
        int d = idx - 230400;
        const float* src; int N, K, base;
        if      (d < 262144) { src = ip;  N = 1024; K = 256; base = 0; }
        else if (d < 286720) { src = xp;  N = 48;   K = 512; base = 262144; }
        else if (d < 294912) { src = dt;  N = 512;  K = 16;  base = 286720; }
        else if (d < 425984) { src = op;  N = 256;  K = 512; base = 294912; }
        else if (d < 458752) { src = h1;  N = 128;  K = 256; base = 425984; }
        else if (d < 459264) { src = h2;  N = 4;    K = 128; base = 458752; }
        else if (d < 483840) { src = ep;  N = 256;  K = 96;  base = 459264; }
        else if (d < 500224) { src = bp2; N = 256;  K = 64;  base = 483840; }
        else                 { src = bp1; N = 64;   K = 4;   base = 500224; }
        int s = d - base;
        int o = s / K, k = s - o * K;            // read coalesced in source order
        tW[base + k * N + o] = src[s];           // scattered write
    }
}

// ---------------------------------------------------------------------------
// Stage 0 as MFMA implicit GEMM (bf16, fp32 acc).
// Unified staged layout: S[r 0..16][c = x-64*xh+1, 68 blocks][ci8] — A-frag is
// a stride-2-block b128 (2-way conflict = free), fill is fully COALESCED.
// Grid: bt x 8 yt x 2 xh (4096 blocks); block 512 = 8 waves =
// (pyp 0..3) x (hx 0..1). Wave: 2 dy x 16 ox x 32 co, acc[2][2].
// LDS: 2 x 18496 (dbuf S) + 18432 (W) = 55.4 KB -> 2 blocks/CU.
// ---------------------------------------------------------------------------
constexpr int C0_STR  = 68;                  // 16B blocks per staged row
constexpr int C0_BLKS = 17 * C0_STR;         // 1156

__device__ inline void conv0_fill(unsigned short* dst, const float* __restrict__ in,
                                  int b, int ts, int yt, int xh, int tid)
{
    bool tok = (ts >= 0 && ts < Tn);
    const float* src = in + (size_t)(b * Tn + (tok ? ts : 0)) * 3 * 16384;
    for (int e = tid; e < C0_BLKS; e += 512) {
        int r = e / C0_STR, c = e - r * C0_STR;
        int gy = 16 * yt - 1 + r;
        int x  = 64 * xh + c - 1;
        bool ok = tok && gy >= 0 && gy < 128 && x >= 0 && x < 128;
        float v0 = 0.f, v1 = 0.f, v2 = 0.f;
        if (ok) {
            const float* p = src + gy * 128 + x;
            v0 = p[0]; v1 = p[16384]; v2 = p[32768];
        }
        ushort8 pk = (ushort8)0;
        pk[0] = f2bf(v0); pk[1] = f2bf(v1); pk[2] = f2bf(v2);
        *(ushort8*)(dst + (size_t)e * 8) = pk;
    }
}

__global__ __launch_bounds__(512) void conv0_kernel(
    const float* __restrict__ in, const unsigned short* __restrict__ w0b,
    const float* __restrict__ bias, const float* __restrict__ gam,
    const float* __restrict__ bet, unsigned short* __restrict__ out)
{
    int tid  = threadIdx.x;
    int lane = tid & 63;
    int wv   = __builtin_amdgcn_readfirstlane(tid >> 6);  // wave 0..7
    int q    = lane >> 4;
    int l15  = lane & 15;
    int pyp  = wv >> 1;                // pooled row within tile (0..3)
    int hx   = wv & 1;                 // 16-ox subtile
    int bI = blockIdx.x;
    int bt = bI >> 4, yt = (bI >> 1) & 7, xh = bI & 1;
    int b = bt >> 5, t = bt & 31;

    __shared__ __align__(16) unsigned short S[2][C0_BLKS * 8];  // 2 x 18496 B
    __shared__ __align__(16) unsigned short W[9 * 32 * 32];     // 18432 B

    f32x4 acc[2][2];
    #pragma unroll
    for (int dy = 0; dy < 2; ++dy)
        #pragma unroll
        for (int nt = 0; nt < 2; ++nt) acc[dy][nt] = (f32x4)0.f;

    {
        const uint4* wsrc = (const uint4*)w0b;
        uint4* wdst = (uint4*)W;
        for (int e = tid; e < 1152; e += 512) wdst[e] = wsrc[e];
    }
    conv0_fill(S[0], in, b, t - 1, yt, xh, tid);
    __syncthreads();

    int oxl = hx * 16 + l15;           // 0..31 within x-half

    for (int kt = 0; kt < 3; ++kt) {
        if (kt < 2) conv0_fill(S[(kt + 1) & 1], in, b, t + kt, yt, xh, tid);
        const unsigned short* Sb = S[kt & 1];
        #pragma unroll
        for (int ky = 0; ky < 3; ++ky) {
            short8 bfr[2];
            #pragma unroll
            for (int nt = 0; nt < 2; ++nt) {
                int co = nt * 16 + l15;
                int i16 = ((kt * 3 + ky) * 32 + co) * 4 +
                          (q ^ (co & 3) ^ ((co >> 2) & 3));
                bfr[nt] = *(const short8*)(W + (size_t)i16 * 8);
            }
            #pragma unroll
            for (int dy = 0; dy < 2; ++dy) {
                int r = 4 * pyp + 2 * dy + ky;          // staged row 0..16
                short8 af = (short8)0;
                if (q < 3)
                    af = *(const short8*)(Sb + (size_t)(r * C0_STR + 2 * oxl + q) * 8);
                #pragma unroll
                for (int nt = 0; nt < 2; ++nt)
                    acc[dy][nt] = __builtin_amdgcn_mfma_f32_16x16x32_bf16(
                        af, bfr[nt], acc[dy][nt], 0, 0, 0);
            }
        }
        __syncthreads();
    }

    // epilogue: BN + ReLU + maxpool(2,2); store bf16 [y][x][ci]
    unsigned short* dst = out + (size_t)bt * 32768;
    #pragma unroll
    for (int nt = 0; nt < 2; ++nt) {
        int co = nt * 16 + l15;
        float bi = bias[co], g = gam[co], be = bet[co];
        #pragma unroll
        for (int j = 0; j < 2; ++j) {
            float m0 = fmaxf(fmaf(g, acc[0][nt][2 * j]     + bi, be), 0.f);
            float m1 = fmaxf(fmaf(g, acc[0][nt][2 * j + 1] + bi, be), 0.f);
            float m2 = fmaxf(fmaf(g, acc[1][nt][2 * j]     + bi, be), 0.f);
            float m3 = fmaxf(fmaf(g, acc[1][nt][2 * j + 1] + bi, be), 0.f);
            float p = fmaxf(fmaxf(m0, m1), fmaxf(m2, m3));
            int pox = xh * 16 + hx * 8 + q * 2 + j;
            int poy = yt * 4 + pyp;
            dst[(poy * 32 + pox) * 32 + co] = f2bf(p);
        }
    }
}

// ---------------------------------------------------------------------------
// Stage 1 as MFMA implicit GEMM, y-half split (2 blocks per bt).
// Block 512 thr = 8 waves: wave = (oyp 0..3) x (nh co-half). acc[2 mt][2 nt].
// LDS: S 36992 + W 36864 = 73.9 KB -> 2 blocks/CU.
// ---------------------------------------------------------------------------
__global__ __launch_bounds__(512) void conv1_kernel(
    const unsigned short* __restrict__ in, const unsigned short* __restrict__ w1b,
    const float* __restrict__ bias, const float* __restrict__ gam,
    const float* __restrict__ bet, unsigned short* __restrict__ out)
{
    int tid  = threadIdx.x;
    int lane = tid & 63;
    int wv   = tid >> 6;               // wave 0..7
    int q    = lane >> 4;
    int l15  = lane & 15;
    int oyp  = wv >> 1;                // oy pair 0..3 (local)
    int nh   = wv & 1;                 // co half
    int bt = blockIdx.x >> 1, half = blockIdx.x & 1;
    int b = bt >> 5, t = bt & 31;

    __shared__ __align__(16) unsigned short S[17 * 34 * 32];   // 36992 B
    __shared__ __align__(16) unsigned short W[9 * 64 * 32];    // 36864 B

    f32x4 acc[2][2];
    #pragma unroll
    for (int mt = 0; mt < 2; ++mt)
        #pragma unroll
        for (int nt = 0; nt < 2; ++nt) acc[mt][nt] = (f32x4)0.f;

    for (int kt = 0; kt < 3; ++kt) {
        int ts = t + kt - 1;
        if (ts < 0 || ts >= Tn) continue;          // block-uniform
        __syncthreads();                           // S/W reuse guard
        // ---- stage input rows [16*half-1 .. 16*half+15]: 16B copies ----
        const unsigned short* src = in + (size_t)(b * Tn + ts) * 32768;
        for (int e = tid; e < 17 * 34 * 4; e += 512) {
            int sb = e & 3;
            int pos = e >> 2;                      // ys*34 + xs
            int ys = pos / 34, xs = pos - ys * 34;
            int g = sb ^ ((xs >> 1) & 3);
            int y = 16 * half + ys - 1, x = xs - 1;
            ushort8 v = (ushort8)0;
            if (y >= 0 && x >= 0 && x < 32)
                v = *(const ushort8*)(src + ((y * 32 + x) * 32 + g * 8));
            *(ushort8*)(S + (size_t)e * 8) = v;
        }
        {
            const uint4* wsrc = (const uint4*)(w1b + kt * 18432);
            uint4* wdst = (uint4*)W;
            for (int e = tid; e < 2304; e += 512) wdst[e] = wsrc[e];
        }
        __syncthreads();

        for (int k9 = 0; k9 < 9; ++k9) {
            int ky = k9 / 3, kx = k9 - ky * 3;
            short8 bf[2];
            #pragma unroll
            for (int nt = 0; nt < 2; ++nt) {
                int co = nh * 32 + nt * 16 + l15;
                int blk = (k9 * 64 + co) * 4 + (q ^ (co & 3));
                bf[nt] = *(const short8*)(W + blk * 8);
            }
            short8 af[2];
            #pragma unroll
            for (int mt = 0; mt < 2; ++mt) {
                int oyl = 2 * oyp + mt;            // 0..7 local
                int ys = 2 * oyl + ky;             // 0..16
                int xs = 2 * l15 + kx;
                int blk = (ys * 34 + xs) * 4 + (q ^ ((xs >> 1) & 3));
                af[mt] = *(const short8*)(S + blk * 8);
            }
            #pragma unroll
            for (int mt = 0; mt < 2; ++mt)
                #pragma unroll
                for (int nt = 0; nt < 2; ++nt)
                    acc[mt][nt] = __builtin_amdgcn_mfma_f32_16x16x32_bf16(
                        af[mt], bf[nt], acc[mt][nt], 0, 0, 0);
        }
    }

    unsigned short* dst = out + (size_t)bt * 4096;
    #pragma unroll
    for (int nt = 0; nt < 2; ++nt) {
        int co = nh * 32 + nt * 16 + l15;
        float bi = bias[co], g = gam[co], be = bet[co];
        #pragma unroll
        for (int j = 0; j < 2; ++j) {
            float m0 = fmaxf(fmaf(g, acc[0][nt][2 * j]     + bi, be), 0.f);
            float m1 = fmaxf(fmaf(g, acc[0][nt][2 * j + 1] + bi, be), 0.f);
            float m2 = fmaxf(fmaf(g, acc[1][nt][2 * j]     + bi, be), 0.f);
            float m3 = fmaxf(fmaf(g, acc[1][nt][2 * j + 1] + bi, be), 0.f);
            float p = fmaxf(fmaxf(m0, m1), fmaxf(m2, m3));
            int px = 2 * q + j, py = half * 4 + oyp;
            dst[(py * 8 + px) * 64 + co] = f2bf(p);
        }
    }
}

// ---------------------------------------------------------------------------
// Stage 2 as MFMA implicit GEMM (verified round 7/8).
// ---------------------------------------------------------------------------
__global__ __launch_bounds__(384) void conv2_kernel(
    const unsigned short* __restrict__ in, const unsigned short* __restrict__ w2b,
    const float* __restrict__ bias, const float* __restrict__ gam,
    const float* __restrict__ bet, float* __restrict__ out)
{
    int tid  = threadIdx.x;
    int lane = tid & 63;
    int wv   = tid >> 6;               // 0..5 = N-tile
    int q    = lane >> 4;
    int l15  = lane & 15;
    int bt = blockIdx.x;
    int b = bt >> 5, t = bt & 31;

    __shared__ __align__(16) unsigned short W[864 * 5 * 8];   // 69120 B
    __shared__ __align__(16) unsigned short S[81 * 5 * 8];    // 6480 B

    f32x4 acc = (f32x4)0.f;

    for (int kt = 0; kt < 3; ++kt) {
        int ts = t + kt - 1;
        if (ts < 0 || ts >= Tn) continue;          // block-uniform
        for (int h = 0; h < 2; ++h) {
            __syncthreads();
            const unsigned short* wsrc = w2b + (size_t)((kt * 2 + h) * 9) * 96 * 32;
            for (int e = tid; e < 3456; e += 384) {
                int r = e >> 2, qq = e & 3;
                uint4 v = *(const uint4*)(wsrc + r * 32 + qq * 8);
                *(uint4*)(W + (r * 5 + qq) * 8) = v;
            }
            const unsigned short* src = in + (size_t)(b * Tn + ts) * 4096 + h * 32;
            for (int e = tid; e < 81 * 4; e += 384) {
                int cb = e & 3, p = e >> 2;
                int ys = p / 9, xs = p - ys * 9;
                int y = ys - 1, x = xs - 1;
                ushort8 v = (ushort8)0;
                if (y >= 0 && x >= 0 && y < 8 && x < 8)
                    v = *(const ushort8*)(src + ((y * 8 + x) * 64 + cb * 8));
                *(ushort8*)(S + (size_t)(p * 5 + cb) * 8) = v;
            }
            __syncthreads();

            int oy = l15 >> 2, ox = l15 & 3;
            #pragma unroll
            for (int k9 = 0; k9 < 9; ++k9) {
                int ky = k9 / 3, kx = k9 - ky * 3;
                short8 bf = *(const short8*)(W + (size_t)((k9 * 96 + wv * 16 + l15) * 5 + q) * 8);
                int p = (2 * oy + ky) * 9 + (2 * ox + kx);
                short8 af = *(const short8*)(S + (size_t)(p * 5 + q) * 8);
                acc = __builtin_amdgcn_mfma_f32_16x16x32_bf16(af, bf, acc, 0, 0, 0);
            }
        }
    }

    int co = wv * 16 + l15;
    float bi = bias[co], g = gam[co], be = bet[co];
    float v0 = fmaxf(fmaf(g, acc[0] + bi, be), 0.f);
    float v1 = fmaxf(fmaf(g, acc[1] + bi, be), 0.f);
    float v2 = fmaxf(fmaf(g, acc[2] + bi, be), 0.f);
    float v3 = fmaxf(fmaf(g, acc[3] + bi, be), 0.f);
    float p0 = fmaxf(v0, v1);
    float p1 = fmaxf(v2, v3);
    float r0 = fmaxf(p0, __shfl_xor(p0, 16));
    float r1 = fmaxf(p1, __shfl_xor(p1, 16));
    if ((q & 1) == 0) {
        int py = q >> 1;
        float* o = out + (size_t)(bt * 96 + co) * 4 + py * 2;
        o[0] = r0;
        o[1] = r1;
    }
}

// ---------------------------------------------------------------------------
// Fused: GAP(2x2) -> ep projection, bbox MLP, u = ff + bf. Transposed weights.
// ---------------------------------------------------------------------------
__global__ void fuse_u_kernel(const float* __restrict__ buf2, const float* __restrict__ epT,
                              const float* __restrict__ ep_b, const float* __restrict__ bb,
                              const float* __restrict__ bp1T, const float* __restrict__ bp1_b,
                              const float* __restrict__ bp2T, const float* __restrict__ bp2_b,
                              float* __restrict__ u)
{
    int bt = blockIdx.x;
    int m  = threadIdx.x;
    __shared__ float hs[64];
    __shared__ float gap[96];
    if (m < 64) {
        float a = bp1_b[m];
        #pragma unroll
        for (int k = 0; k < 4; ++k) a = fmaf(bp1T[k * 64 + m], bb[bt * 4 + k], a);
        hs[m] = fmaxf(a, 0.f);
    } else if (m < 160) {
        int c = m - 64;
        const float* p = buf2 + ((size_t)bt * 96 + c) * 4;
        gap[c] = 0.25f * (p[0] + p[1] + p[2] + p[3]);
    }
    __syncthreads();
    float ff = ep_b[m];
    for (int c = 0; c < 96; ++c) ff = fmaf(gap[c], epT[c * 256 + m], ff);
    float bfv = bp2_b[m];
    for (int j = 0; j < 64; ++j) bfv = fmaf(hs[j], bp2T[j * 256 + m], bfv);
    u[(size_t)bt * 256 + m] = ff + bfv;
}

// ---------------------------------------------------------------------------
// Linear with 4-token m-tiling and transposed weights (coalesced reads).
// ---------------------------------------------------------------------------
__global__ void linearT_kernel(const float* __restrict__ in, const float* __restrict__ wT,
                               const float* __restrict__ bias, float* __restrict__ out,
                               int K, int N, int ldin, int act, int total)
{
    int idx = blockIdx.x * blockDim.x + threadIdx.x;
    if (idx >= total) return;
    int o = idx % N; int m0 = (idx / N) * 4;
    const float* i0 = in + (size_t)m0 * ldin;
    const float* i1 = i0 + ldin;
    const float* i2 = i1 + ldin;
    const float* i3 = i2 + ldin;
    float a0 = 0.f, a1 = 0.f, a2 = 0.f, a3 = 0.f;
    int K4 = K >> 2;
    for (int k4 = 0; k4 < K4; ++k4) {
        float4 x0 = *(const float4*)(i0 + 4 * k4);
        float4 x1 = *(const float4*)(i1 + 4 * k4);
        float4 x2 = *(const float4*)(i2 + 4 * k4);
        float4 x3 = *(const float4*)(i3 + 4 * k4);
        const float* wp = wT + (size_t)(4 * k4) * N + o;
        float w0 = wp[0], w1 = wp[N], w2 = wp[2 * N], w3 = wp[3 * N];
        a0 = fmaf(x0.x, w0, a0); a0 = fmaf(x0.y, w1, a0);
        a0 = fmaf(x0.z, w2, a0); a0 = fmaf(x0.w, w3, a0);
        a1 = fmaf(x1.x, w0, a1); a1 = fmaf(x1.y, w1, a1);
        a1 = fmaf(x1.z, w2, a1); a1 = fmaf(x1.w, w3, a1);
        a2 = fmaf(x2.x, w0, a2); a2 = fmaf(x2.y, w1, a2);
        a2 = fmaf(x2.z, w2, a2); a2 = fmaf(x2.w, w3, a2);
        a3 = fmaf(x3.x, w0, a3); a3 = fmaf(x3.y, w1, a3);
        a3 = fmaf(x3.z, w2, a3); a3 = fmaf(x3.w, w3, a3);
    }
    float av[4] = {a0, a1, a2, a3};
    float bv = bias ? bias[o] : 0.f;
    #pragma unroll
    for (int r = 0; r < 4; ++r) {
        float a = av[r] + bv;
        if (act == 1)      a = fmaxf(a, 0.f);
        else if (act == 2) a = 1.f / (1.f + expf(-a));
        else if (act == 3) a = (a > 20.f) ? a : log1pf(expf(a));
        out[(size_t)(m0 + r) * N + o] = a;
    }
}

// ---------------------------------------------------------------------------
// Causal depthwise conv1d (k=4) + SiLU.
// ---------------------------------------------------------------------------
__global__ void conv1d_silu_kernel(const float* __restrict__ xz, const float* __restrict__ cw,
                                   const float* __restrict__ cb, float* __restrict__ xs)
{
    int idx = blockIdx.x * blockDim.x + threadIdx.x;
    if (idx >= Bn * Tn * D_INNER) return;
    int d = idx % D_INNER; int r = idx / D_INNER;
    int t = r % Tn; int b = r / Tn;
    float acc = cb[d];
    #pragma unroll
    for (int k = 0; k < 4; ++k) {
        int ts = t - 3 + k;
        if (ts >= 0) acc = fmaf(cw[d * 4 + k], xz[(size_t)(b * Tn + ts) * 1024 + d], acc);
    }
    xs[idx] = acc / (1.f + expf(-acc));
}

// ---------------------------------------------------------------------------
// Wave-parallel selective scan.
// ---------------------------------------------------------------------------
__global__ __launch_bounds__(256) void ssm_kernel(
    const float* __restrict__ xdbl, const float* __restrict__ dtb,
    const float* __restrict__ xs, const float* __restrict__ xz,
    const float* __restrict__ A_log, const float* __restrict__ Dp,
    float* __restrict__ y)
{
    int tid = threadIdx.x;
    int lane = tid & 63;
    int s = lane & 15, dsub = lane >> 4;
    int gid = blockIdx.x * 4 + (tid >> 6);
    int b = gid >> 7;
    int d = ((gid & 127) << 2) + dsub;

    float A = -expf(A_log[d * 16 + s]);
    float Dv = Dp[d];
    float h = 0.f;
    for (int t = 0; t < Tn; ++t) {
        int bt = b * Tn + t;
        float dtv = dtb[(size_t)bt * 512 + d];
        float xv  = xs [(size_t)bt * 512 + d];
        float Bs  = xdbl[(size_t)bt * 48 + 16 + s];
        float Cs  = xdbl[(size_t)bt * 48 + 32 + s];
        float dA = expf(dtv * A);
        h = fmaf(dA, h, dtv * Bs * xv);
        float c = h * Cs;
        c += __shfl_xor(c, 8, 16);
        c += __shfl_xor(c, 4, 16);
        c += __shfl_xor(c, 2, 16);
        c += __shfl_xor(c, 1, 16);
        if (s == 0) {
            float zv = xz[(size_t)bt * 1024 + 512 + d];
            float sig = 1.f / (1.f + expf(-zv));
            y[(size_t)bt * 512 + d] = (c + Dv * xv) * (zv * sig);
        }
    }
}

// ---------------------------------------------------------------------------
// Kalman filter scan, one thread per batch.
// ---------------------------------------------------------------------------
__global__ void kf_kernel(const float* __restrict__ meas, const float* __restrict__ bb,
                          const float* __restrict__ Fin, const float* __restrict__ Hmin,
                          const float* __restrict__ lq, const float* __restrict__ lr,
                          float* __restrict__ pred)
{
    int b = blockIdx.x * blockDim.x + threadIdx.x;
    if (b >= Bn) return;
    float F[4][4], Hm[4][4], Qd[4], Rd[4];
    #pragma unroll
    for (int i = 0; i < 4; ++i) {
        Qd[i] = expf(lq[i]) + 1e-6f;
        Rd[i] = expf(lr[i]) + 1e-6f;
        #pragma unroll
        for (int j = 0; j < 4; ++j) { F[i][j] = Fin[i * 4 + j]; Hm[i][j] = Hmin[i * 4 + j]; }
    }
    float s[4], P[4][4];
    #pragma unroll
    for (int i = 0; i < 4; ++i) {
        s[i] = bb[(b * Tn) * 4 + i];
        #pragma unroll
        for (int j = 0; j < 4; ++j) P[i][j] = (i == j) ? 0.01f : 0.f;
    }
    for (int t = 0; t < Tn; ++t) {
        float mv[4];
        #pragma unroll
        for (int i = 0; i < 4; ++i) mv[i] = meas[(b * Tn + t) * 4 + i];
        float sp[4];
        #pragma unroll
        for (int i = 0; i < 4; ++i) { float a = 0.f;
            #pragma unroll
            for (int j = 0; j < 4; ++j) a = fmaf(F[i][j], s[j], a); sp[i] = a; }
        float FP[4][4];
        #pragma unroll
        for (int i = 0; i < 4; ++i)
            #pragma unroll
            for (int j = 0; j < 4; ++j) { float a = 0.f;
                for (int k = 0; k < 4; ++k) a = fmaf(F[i][k], P[k][j], a); FP[i][j] = a; }
        float Pp[4][4];
        #pragma unroll
        for (int i = 0; i < 4; ++i)
            #pragma unroll
            for (int j = 0; j < 4; ++j) { float a = 0.f;
                for (int k = 0; k < 4; ++k) a = fmaf(FP[i][k], F[j][k], a);
                Pp[i][j] = a + ((i == j) ? Qd[i] : 0.f); }
        float yr[4];
        #pragma unroll
        for (int i = 0; i < 4; ++i) { float a = 0.f;
            for (int j = 0; j < 4; ++j) a = fmaf(Hm[i][j], sp[j], a); yr[i] = mv[i] - a; }
        float HP[4][4];
        #pragma unroll
        for (int i = 0; i < 4; ++i)
            #pragma unroll
            for (int j = 0; j < 4; ++j) { float a = 0.f;
                for (int k = 0; k < 4; ++k) a = fmaf(Hm[i][k], Pp[k][j], a); HP[i][j] = a; }
        float S[4][8];
        #pragma unroll
        for (int i = 0; i < 4; ++i)
            #pragma unroll
            for (int j = 0; j < 4; ++j) { float a = 0.f;
                for (int k = 0; k < 4; ++k) a = fmaf(HP[i][k], Hm[j][k], a);
                S[i][j] = a + ((i == j) ? Rd[i] : 0.f);
                S[i][4 + j] = Hm[i][j]; }
        #pragma unroll
        for (int c = 0; c < 4; ++c) {
            float dinv = 1.f / S[c][c];
            #pragma unroll
            for (int j = 0; j < 8; ++j) S[c][j] *= dinv;
            #pragma unroll
            for (int r2 = 0; r2 < 4; ++r2) {
                if (r2 == c) continue;
                float f = S[r2][c];
                #pragma unroll
                for (int j = 0; j < 8; ++j) S[r2][j] = fmaf(-f, S[c][j], S[r2][j]);
            }
        }
        float K[4][4];
        #pragma unroll
        for (int i = 0; i < 4; ++i)
            #pragma unroll
            for (int k = 0; k < 4; ++k) { float a = 0.f;
                for (int j = 0; j < 4; ++j) a = fmaf(Pp[i][j], S[k][4 + j], a); K[i][k] = a; }
        float sn[4];
        #pragma unroll
        for (int i = 0; i < 4; ++i) { float a = sp[i];
            for (int j = 0; j < 4; ++j) a = fmaf(K[i][j], yr[j], a); sn[i] = a; }
        float IKH[4][4];
        #pragma unroll
        for (int i = 0; i < 4; ++i)
            #pragma unroll
            for (int j = 0; j < 4; ++j) { float a = (i == j) ? 1.f : 0.f;
                for (int k = 0; k < 4; ++k) a = fmaf(-K[i][k], Hm[k][j], a); IKH[i][j] = a; }
        float T1[4][4];
        #pragma unroll
        for (int i = 0; i < 4; ++i)
            #pragma unroll
            for (int j = 0; j < 4; ++j) { float a = 0.f;
                for (int k = 0; k < 4; ++k) a = fmaf(IKH[i][k], Pp[k][j], a); T1[i][j] = a; }
        #pragma unroll
        for (int i = 0; i < 4; ++i)
            #pragma unroll
            for (int j = 0; j < 4; ++j) { float a = 0.f;
                for (int k = 0; k < 4; ++k) a = fmaf(T1[i][k], IKH[j][k], a);
                for (int k = 0; k < 4; ++k) a = fmaf(K[i][k] * Rd[k], K[j][k], a);
                P[i][j] = a; }
        #pragma unroll
        for (int i = 0; i < 4; ++i) { s[i] = sn[i]; pred[(b * Tn + t) * 4 + i] = sn[i]; }
    }
}

// ---------------------------------------------------------------------------
extern "C" void kernel_launch(void* const* d_in, const int* in_sizes, int n_in,
                              void* d_out, int out_size, void* d_ws, size_t ws_size,
                              hipStream_t stream)
{
    const float* frames = (const float*)d_in[0];
    const float* bb     = (const float*)d_in[1];
    const float* cw0 = (const float*)d_in[2],  *cb0 = (const float*)d_in[3];
    const float* g0  = (const float*)d_in[4],  *be0 = (const float*)d_in[5];
    const float* cw1 = (const float*)d_in[6],  *cb1 = (const float*)d_in[7];
    const float* g1  = (const float*)d_in[8],  *be1 = (const float*)d_in[9];
    const float* cw2 = (const float*)d_in[10], *cb2 = (const float*)d_in[11];
    const float* g2  = (const float*)d_in[12], *be2 = (const float*)d_in[13];
    const float* ep_w  = (const float*)d_in[14], *ep_b  = (const float*)d_in[15];
    const float* bp1_w = (const float*)d_in[16], *bp1_b = (const float*)d_in[17];
    const float* bp2_w = (const float*)d_in[18], *bp2_b = (const float*)d_in[19];
    const float* in_proj_w = (const float*)d_in[20];
    const float* c1w = (const float*)d_in[21], *c1b = (const float*)d_in[22];
    const float* x_proj_w = (const float*)d_in[23];
    const float* dt_w = (const float*)d_in[24], *dt_b = (const float*)d_in[25];
    const float* A_log = (const float*)d_in[26], *Dp = (const float*)d_in[27];
    const float* out_proj_w = (const float*)d_in[28];
    const float* h1_w = (const float*)d_in[29], *h1_b = (const float*)d_in[30];
    const float* h2_w = (const float*)d_in[31], *h2_b = (const float*)d_in[32];
    const float* kfF = (const float*)d_in[33], *kfH = (const float*)d_in[34];
    const float* kfq = (const float*)d_in[35], *kfr = (const float*)d_in[36];

    // workspace layout
    float* ws   = (float*)d_ws;
    float* buf2 = ws;                        // (256,96,2,2)   98304
    float* ub   = buf2 + 98304;              // (256,256)      65536
    float* xzb  = ub   + 65536;              // (256,1024)    262144
    float* xsb  = xzb  + 262144;             // (256,512)     131072
    float* xdb  = xsb  + 131072;             // (256,48)       12288
    float* dtbf = xdb  + 12288;              // (256,512)     131072
    float* yb   = dtbf + 131072;             // (256,512)     131072
    float* mob  = yb   + 131072;             // (256,256)      65536
    float* hidb = mob  + 65536;              // (256,128)      32768
    float* tW   = hidb + 32768;              // transposed weights 500480
    unsigned short* buf0b = (unsigned short*)(tW + 500480);  // bf16 (256,32,32,32)
    unsigned short* buf1b = buf0b + 8388608;                 // bf16 (256,8,8,64)
    unsigned short* w2b   = buf1b + 131072;                  // conv2 bf16 weights
    unsigned short* w1b   = w2b + 165888;                    // conv1 bf16 weights
    unsigned short* w0b   = w1b + 55296;                     // conv0 bf16 weights

    float* ipwT = tW;            // +0
    float* xpwT = tW + 262144;
    float* dtwT = tW + 286720;
    float* opwT = tW + 294912;
    float* h1wT = tW + 425984;
    float* h2wT = tW + 458752;
    float* epwT = tW + 459264;
    float* bp2T = tW + 483840;
    float* bp1T = tW + 500224;

    float* kf_out   = (float*)d_out;          // (8,32,4)
    float* meas_out = kf_out + Bn * Tn * 4;   // (8,32,4)

    auto nblk = [](int n) { return dim3((unsigned)((n + 255) / 256)); };

    // All weight prep in one kernel
    prep_all<<<nblk(730880), 256, 0, stream>>>(cw0, cw1, cw2,
                                               in_proj_w, x_proj_w, dt_w, out_proj_w,
                                               h1_w, h2_w, ep_w, bp2_w, bp1_w,
                                               w0b, w1b, w2b, tW);

    // CNN backbone (bf16 chained)
    conv0_kernel<<<dim3(4096), 512, 0, stream>>>(frames, w0b, cb0, g0, be0, buf0b);
    conv1_kernel<<<dim3(512), 512, 0, stream>>>(buf0b, w1b, cb1, g1, be1, buf1b);
    conv2_kernel<<<dim3(256), 384, 0, stream>>>(buf1b, w2b, cb2, g2, be2, buf2);

    // GAP + embed proj + bbox MLP -> u
    fuse_u_kernel<<<256, 256, 0, stream>>>(buf2, epwT, ep_b, bb, bp1T, bp1_b, bp2T, bp2_b, ub);

    // Mamba block
    linearT_kernel<<<nblk(64 * 1024), 256, 0, stream>>>(ub, ipwT, nullptr, xzb,
                                                        256, 1024, 256, 0, 64 * 1024);
    conv1d_silu_kernel<<<nblk(256 * 512), 256, 0, stream>>>(xzb, c1w, c1b, xsb);
    linearT_kernel<<<nblk(64 * 48), 256, 0, stream>>>(xsb, xpwT, nullptr, xdb,
                                                      512, 48, 512, 0, 64 * 48);
    linearT_kernel<<<nblk(64 * 512), 256, 0, stream>>>(xdb, dtwT, dt_b, dtbf,
                                                       16, 512, 48, 3, 64 * 512);
    ssm_kernel<<<dim3(256), 256, 0, stream>>>(xdb, dtbf, xsb, xzb, A_log, Dp, yb);
    linearT_kernel<<<nblk(64 * 256), 256, 0, stream>>>(yb, opwT, nullptr, mob,
                                                       512, 256, 512, 0, 64 * 256);

    // Measurement head -> meas (second output)
    linearT_kernel<<<nblk(64 * 128), 256, 0, stream>>>(mob, h1wT, h1_b, hidb,
                                                       256, 128, 256, 1, 64 * 128);
    linearT_kernel<<<nblk(64 * 4), 256, 0, stream>>>(hidb, h2wT, h2_b, meas_out,
                                                     128, 4, 128, 2, 64 * 4);

    // Kalman filter -> kf_pred (first output)
    kf_kernel<<<1, 64, 0, stream>>>(meas_out, bb, kfF, kfH, kfq, kfr, kf_out);
}

// Round 10
// 339.899 us; speedup vs baseline: 12.8897x; 1.3528x over previous
//
#include <hip/hip_runtime.h>
#include <math.h>

// Problem constants
constexpr int Bn = 8, Tn = 32;
constexpr int D_INNER = 512;

typedef __attribute__((ext_vector_type(8))) short short8;   // 8 bf16
typedef __attribute__((ext_vector_type(8))) unsigned short ushort8;
typedef __attribute__((ext_vector_type(4))) float f32x4;

__device__ inline unsigned short f2bf(float x) {
    unsigned int u = __float_as_uint(x);
    unsigned int r = (u + 0x7FFF + ((u >> 16) & 1)) >> 16;  // RNE
    return (unsigned short)r;
}

// ---------------------------------------------------------------------------
// ONE prep kernel: conv bf16 weight packs + tail-weight transposes.
// ---------------------------------------------------------------------------
__global__ void prep_all(
    const float* __restrict__ cw0, const float* __restrict__ cw1,
    const float* __restrict__ cw2,
    const float* __restrict__ ip, const float* __restrict__ xp,
    const float* __restrict__ dt, const float* __restrict__ op,
    const float* __restrict__ h1, const float* __restrict__ h2,
    const float* __restrict__ ep, const float* __restrict__ bp2,
    const float* __restrict__ bp1,
    unsigned short* __restrict__ w0b, unsigned short* __restrict__ w1b,
    unsigned short* __restrict__ w2b, float* __restrict__ tW)
{
    int idx = blockIdx.x * blockDim.x + threadIdx.x;
    if (idx < 9216) {
        int d = idx;
        int sl = d & 7, sq = (d >> 3) & 3, co = (d >> 5) & 31;
        int r = d >> 10; int ky = r % 3, kt = r / 3;
        int q = sq ^ (co & 3) ^ ((co >> 2) & 3);
        float v = 0.f;
        if (q < 3 && sl < 3)
            v = cw0[((((size_t)co * 3 + sl) * 3 + kt) * 3 + ky) * 3 + q];
        w0b[d] = f2bf(v);
    } else if (idx < 64512) {
        int d = idx - 9216;
        int sl = d & 7, sg = (d >> 3) & 3, co = (d >> 5) & 63;
        int r = d >> 11; int k9 = r % 9, kt = r / 9;
        int ci = (sg ^ (co & 3)) * 8 + sl;
        w1b[d] = f2bf(cw1[((size_t)(co * 32 + ci) * 3 + kt) * 9 + k9]);
    } else if (idx < 230400) {
        int d = idx - 64512;
        int cip = d & 31; int rest = d >> 5;
        int co = rest % 96; rest /= 96;
        int k9 = rest % 9; int hh = rest / 9;
        int h = hh & 1, kt = hh >> 1;
        int ci = h * 32 + cip;
        w2b[d] = f2bf(cw2[((size_t)(co * 64 + ci) * 3 + kt) * 9 + k9]);
    } else if (idx < 730880) {
        int d = idx - 230400;
        const float* src; int N, K, base;
        if      (d < 262144) { src = ip;  N = 1024; K = 256; base = 0; }
        else if (d < 286720) { src = xp;  N = 48;   K = 512; base = 262144; }
        else if (d < 294912) { src = dt;  N = 512;  K = 16;  base = 286720; }
        else if (d < 425984) { src = op;  N = 256;  K = 512; base = 294912; }
        else if (d < 458752) { src = h1;  N = 128;  K = 256; base = 425984; }
        else if (d < 459264) { src = h2;  N = 4;    K = 128; base = 458752; }
        else if (d < 483840) { src = ep;  N = 256;  K = 96;  base = 459264; }
        else if (d < 500224) { src = bp2; N = 256;  K = 64;  base = 483840; }
        else                 { src = bp1; N = 64;   K = 4;   base = 500224; }
        int s = d - base;
        int o = s / K, k = s - o * K;
        tW[base + k * N + o] = src[s];
    }
}

// ---------------------------------------------------------------------------
// Stage 0 as MFMA implicit GEMM (verified round 9).
// ---------------------------------------------------------------------------
constexpr int C0_STR  = 68;
constexpr int C0_BLKS = 17 * C0_STR;

__device__ inline void conv0_fill(unsigned short* dst, const float* __restrict__ in,
                                  int b, int ts, int yt, int xh, int tid)
{
    bool tok = (ts >= 0 && ts < Tn);
    const float* src = in + (size_t)(b * Tn + (tok ? ts : 0)) * 3 * 16384;
    for (int e = tid; e < C0_BLKS; e += 512) {
        int r = e / C0_STR, c = e - r * C0_STR;
        int gy = 16 * yt - 1 + r;
        int x  = 64 * xh + c - 1;
        bool ok = tok && gy >= 0 && gy < 128 && x >= 0 && x < 128;
        float v0 = 0.f, v1 = 0.f, v2 = 0.f;
        if (ok) {
            const float* p = src + gy * 128 + x;
            v0 = p[0]; v1 = p[16384]; v2 = p[32768];
        }
        ushort8 pk = (ushort8)0;
        pk[0] = f2bf(v0); pk[1] = f2bf(v1); pk[2] = f2bf(v2);
        *(ushort8*)(dst + (size_t)e * 8) = pk;
    }
}

__global__ __launch_bounds__(512) void conv0_kernel(
    const float* __restrict__ in, const unsigned short* __restrict__ w0b,
    const float* __restrict__ bias, const float* __restrict__ gam,
    const float* __restrict__ bet, unsigned short* __restrict__ out)
{
    int tid  = threadIdx.x;
    int lane = tid & 63;
    int wv   = __builtin_amdgcn_readfirstlane(tid >> 6);
    int q    = lane >> 4;
    int l15  = lane & 15;
    int pyp  = wv >> 1;
    int hx   = wv & 1;
    int bI = blockIdx.x;
    int bt = bI >> 4, yt = (bI >> 1) & 7, xh = bI & 1;
    int b = bt >> 5, t = bt & 31;

    __shared__ __align__(16) unsigned short S[2][C0_BLKS * 8];
    __shared__ __align__(16) unsigned short W[9 * 32 * 32];

    f32x4 acc[2][2];
    #pragma unroll
    for (int dy = 0; dy < 2; ++dy)
        #pragma unroll
        for (int nt = 0; nt < 2; ++nt) acc[dy][nt] = (f32x4)0.f;

    {
        const uint4* wsrc = (const uint4*)w0b;
        uint4* wdst = (uint4*)W;
        for (int e = tid; e < 1152; e += 512) wdst[e] = wsrc[e];
    }
    conv0_fill(S[0], in, b, t - 1, yt, xh, tid);
    __syncthreads();

    int oxl = hx * 16 + l15;

    for (int kt = 0; kt < 3; ++kt) {
        if (kt < 2) conv0_fill(S[(kt + 1) & 1], in, b, t + kt, yt, xh, tid);
        const unsigned short* Sb = S[kt & 1];
        #pragma unroll
        for (int ky = 0; ky < 3; ++ky) {
            short8 bfr[2];
            #pragma unroll
            for (int nt = 0; nt < 2; ++nt) {
                int co = nt * 16 + l15;
                int i16 = ((kt * 3 + ky) * 32 + co) * 4 +
                          (q ^ (co & 3) ^ ((co >> 2) & 3));
                bfr[nt] = *(const short8*)(W + (size_t)i16 * 8);
            }
            #pragma unroll
            for (int dy = 0; dy < 2; ++dy) {
                int r = 4 * pyp + 2 * dy + ky;
                short8 af = (short8)0;
                if (q < 3)
                    af = *(const short8*)(Sb + (size_t)(r * C0_STR + 2 * oxl + q) * 8);
                #pragma unroll
                for (int nt = 0; nt < 2; ++nt)
                    acc[dy][nt] = __builtin_amdgcn_mfma_f32_16x16x32_bf16(
                        af, bfr[nt], acc[dy][nt], 0, 0, 0);
            }
        }
        __syncthreads();
    }

    unsigned short* dst = out + (size_t)bt * 32768;
    #pragma unroll
    for (int nt = 0; nt < 2; ++nt) {
        int co = nt * 16 + l15;
        float bi = bias[co], g = gam[co], be = bet[co];
        #pragma unroll
        for (int j = 0; j < 2; ++j) {
            float m0 = fmaxf(fmaf(g, acc[0][nt][2 * j]     + bi, be), 0.f);
            float m1 = fmaxf(fmaf(g, acc[0][nt][2 * j + 1] + bi, be), 0.f);
            float m2 = fmaxf(fmaf(g, acc[1][nt][2 * j]     + bi, be), 0.f);
            float m3 = fmaxf(fmaf(g, acc[1][nt][2 * j + 1] + bi, be), 0.f);
            float p = fmaxf(fmaxf(m0, m1), fmaxf(m2, m3));
            int pox = xh * 16 + hx * 8 + q * 2 + j;
            int poy = yt * 4 + pyp;
            dst[(poy * 32 + pox) * 32 + co] = f2bf(p);
        }
    }
}

// ---------------------------------------------------------------------------
// Stage 1 as MFMA implicit GEMM, y-half split (verified round 9).
// ---------------------------------------------------------------------------
__global__ __launch_bounds__(512) void conv1_kernel(
    const unsigned short* __restrict__ in, const unsigned short* __restrict__ w1b,
    const float* __restrict__ bias, const float* __restrict__ gam,
    const float* __restrict__ bet, unsigned short* __restrict__ out)
{
    int tid  = threadIdx.x;
    int lane = tid & 63;
    int wv   = tid >> 6;
    int q    = lane >> 4;
    int l15  = lane & 15;
    int oyp  = wv >> 1;
    int nh   = wv & 1;
    int bt = blockIdx.x >> 1, half = blockIdx.x & 1;
    int b = bt >> 5, t = bt & 31;

    __shared__ __align__(16) unsigned short S[17 * 34 * 32];
    __shared__ __align__(16) unsigned short W[9 * 64 * 32];

    f32x4 acc[2][2];
    #pragma unroll
    for (int mt = 0; mt < 2; ++mt)
        #pragma unroll
        for (int nt = 0; nt < 2; ++nt) acc[mt][nt] = (f32x4)0.f;

    for (int kt = 0; kt < 3; ++kt) {
        int ts = t + kt - 1;
        if (ts < 0 || ts >= Tn) continue;
        __syncthreads();
        const unsigned short* src = in + (size_t)(b * Tn + ts) * 32768;
        for (int e = tid; e < 17 * 34 * 4; e += 512) {
            int sb = e & 3;
            int pos = e >> 2;
            int ys = pos / 34, xs = pos - ys * 34;
            int g = sb ^ ((xs >> 1) & 3);
            int y = 16 * half + ys - 1, x = xs - 1;
            ushort8 v = (ushort8)0;
            if (y >= 0 && x >= 0 && x < 32)
                v = *(const ushort8*)(src + ((y * 32 + x) * 32 + g * 8));
            *(ushort8*)(S + (size_t)e * 8) = v;
        }
        {
            const uint4* wsrc = (const uint4*)(w1b + kt * 18432);
            uint4* wdst = (uint4*)W;
            for (int e = tid; e < 2304; e += 512) wdst[e] = wsrc[e];
        }
        __syncthreads();

        for (int k9 = 0; k9 < 9; ++k9) {
            int ky = k9 / 3, kx = k9 - ky * 3;
            short8 bf[2];
            #pragma unroll
            for (int nt = 0; nt < 2; ++nt) {
                int co = nh * 32 + nt * 16 + l15;
                int blk = (k9 * 64 + co) * 4 + (q ^ (co & 3));
                bf[nt] = *(const short8*)(W + blk * 8);
            }
            short8 af[2];
            #pragma unroll
            for (int mt = 0; mt < 2; ++mt) {
                int oyl = 2 * oyp + mt;
                int ys = 2 * oyl + ky;
                int xs = 2 * l15 + kx;
                int blk = (ys * 34 + xs) * 4 + (q ^ ((xs >> 1) & 3));
                af[mt] = *(const short8*)(S + blk * 8);
            }
            #pragma unroll
            for (int mt = 0; mt < 2; ++mt)
                #pragma unroll
                for (int nt = 0; nt < 2; ++nt)
                    acc[mt][nt] = __builtin_amdgcn_mfma_f32_16x16x32_bf16(
                        af[mt], bf[nt], acc[mt][nt], 0, 0, 0);
        }
    }

    unsigned short* dst = out + (size_t)bt * 4096;
    #pragma unroll
    for (int nt = 0; nt < 2; ++nt) {
        int co = nh * 32 + nt * 16 + l15;
        float bi = bias[co], g = gam[co], be = bet[co];
        #pragma unroll
        for (int j = 0; j < 2; ++j) {
            float m0 = fmaxf(fmaf(g, acc[0][nt][2 * j]     + bi, be), 0.f);
            float m1 = fmaxf(fmaf(g, acc[0][nt][2 * j + 1] + bi, be), 0.f);
            float m2 = fmaxf(fmaf(g, acc[1][nt][2 * j]     + bi, be), 0.f);
            float m3 = fmaxf(fmaf(g, acc[1][nt][2 * j + 1] + bi, be), 0.f);
            float p = fmaxf(fmaxf(m0, m1), fmaxf(m2, m3));
            int px = 2 * q + j, py = half * 4 + oyp;
            dst[(py * 8 + px) * 64 + co] = f2bf(p);
        }
    }
}

// ---------------------------------------------------------------------------
// Stage 2 as MFMA implicit GEMM (verified round 8).
// ---------------------------------------------------------------------------
__global__ __launch_bounds__(384) void conv2_kernel(
    const unsigned short* __restrict__ in, const unsigned short* __restrict__ w2b,
    const float* __restrict__ bias, const float* __restrict__ gam,
    const float* __restrict__ bet, float* __restrict__ out)
{
    int tid  = threadIdx.x;
    int lane = tid & 63;
    int wv   = tid >> 6;
    int q    = lane >> 4;
    int l15  = lane & 15;
    int bt = blockIdx.x;
    int b = bt >> 5, t = bt & 31;

    __shared__ __align__(16) unsigned short W[864 * 5 * 8];
    __shared__ __align__(16) unsigned short S[81 * 5 * 8];

    f32x4 acc = (f32x4)0.f;

    for (int kt = 0; kt < 3; ++kt) {
        int ts = t + kt - 1;
        if (ts < 0 || ts >= Tn) continue;
        for (int h = 0; h < 2; ++h) {
            __syncthreads();
            const unsigned short* wsrc = w2b + (size_t)((kt * 2 + h) * 9) * 96 * 32;
            for (int e = tid; e < 3456; e += 384) {
                int r = e >> 2, qq = e & 3;
                uint4 v = *(const uint4*)(wsrc + r * 32 + qq * 8);
                *(uint4*)(W + (r * 5 + qq) * 8) = v;
            }
            const unsigned short* src = in + (size_t)(b * Tn + ts) * 4096 + h * 32;
            for (int e = tid; e < 81 * 4; e += 384) {
                int cb = e & 3, p = e >> 2;
                int ys = p / 9, xs = p - ys * 9;
                int y = ys - 1, x = xs - 1;
                ushort8 v = (ushort8)0;
                if (y >= 0 && x >= 0 && y < 8 && x < 8)
                    v = *(const ushort8*)(src + ((y * 8 + x) * 64 + cb * 8));
                *(ushort8*)(S + (size_t)(p * 5 + cb) * 8) = v;
            }
            __syncthreads();

            int oy = l15 >> 2, ox = l15 & 3;
            #pragma unroll
            for (int k9 = 0; k9 < 9; ++k9) {
                int ky = k9 / 3, kx = k9 - ky * 3;
                short8 bf = *(const short8*)(W + (size_t)((k9 * 96 + wv * 16 + l15) * 5 + q) * 8);
                int p = (2 * oy + ky) * 9 + (2 * ox + kx);
                short8 af = *(const short8*)(S + (size_t)(p * 5 + q) * 8);
                acc = __builtin_amdgcn_mfma_f32_16x16x32_bf16(af, bf, acc, 0, 0, 0);
            }
        }
    }

    int co = wv * 16 + l15;
    float bi = bias[co], g = gam[co], be = bet[co];
    float v0 = fmaxf(fmaf(g, acc[0] + bi, be), 0.f);
    float v1 = fmaxf(fmaf(g, acc[1] + bi, be), 0.f);
    float v2 = fmaxf(fmaf(g, acc[2] + bi, be), 0.f);
    float v3 = fmaxf(fmaf(g, acc[3] + bi, be), 0.f);
    float p0 = fmaxf(v0, v1);
    float p1 = fmaxf(v2, v3);
    float r0 = fmaxf(p0, __shfl_xor(p0, 16));
    float r1 = fmaxf(p1, __shfl_xor(p1, 16));
    if ((q & 1) == 0) {
        int py = q >> 1;
        float* o = out + (size_t)(bt * 96 + co) * 4 + py * 2;
        o[0] = r0;
        o[1] = r1;
    }
}

// ---------------------------------------------------------------------------
// FUSED: GAP + ep proj + bbox MLP -> u (LDS only) -> in_proj -> xz.
// Grid 256 (token), block 256. Each thread: u[m], then 4 consecutive xz
// outputs via float4 weight loads.
// ---------------------------------------------------------------------------
__global__ __launch_bounds__(256) void fuse_u_inproj(
    const float* __restrict__ buf2, const float* __restrict__ epT,
    const float* __restrict__ ep_b, const float* __restrict__ bb,
    const float* __restrict__ bp1T, const float* __restrict__ bp1_b,
    const float* __restrict__ bp2T, const float* __restrict__ bp2_b,
    const float* __restrict__ ipwT, float* __restrict__ xzb)
{
    int bt = blockIdx.x;
    int m  = threadIdx.x;
    __shared__ float hs[64];
    __shared__ float gap[96];
    __shared__ float u_lds[256];
    if (m < 64) {
        float a = bp1_b[m];
        #pragma unroll
        for (int k = 0; k < 4; ++k) a = fmaf(bp1T[k * 64 + m], bb[bt * 4 + k], a);
        hs[m] = fmaxf(a, 0.f);
    } else if (m < 160) {
        int c = m - 64;
        const float* p = buf2 + ((size_t)bt * 96 + c) * 4;
        gap[c] = 0.25f * (p[0] + p[1] + p[2] + p[3]);
    }
    __syncthreads();
    float ff = ep_b[m];
    for (int c = 0; c < 96; ++c) ff = fmaf(gap[c], epT[c * 256 + m], ff);
    float bfv = bp2_b[m];
    for (int j = 0; j < 64; ++j) bfv = fmaf(hs[j], bp2T[j * 256 + m], bfv);
    u_lds[m] = ff + bfv;
    __syncthreads();

    // in_proj: outputs 4m..4m+3 (no bias)
    const float4* wbase = (const float4*)ipwT + m;    // + k*256 per row
    float4 acc = {0.f, 0.f, 0.f, 0.f};
    for (int k = 0; k < 256; ++k) {
        float uk = u_lds[k];
        float4 w4 = wbase[(size_t)k * 256];
        acc.x = fmaf(uk, w4.x, acc.x);
        acc.y = fmaf(uk, w4.y, acc.y);
        acc.z = fmaf(uk, w4.z, acc.z);
        acc.w = fmaf(uk, w4.w, acc.w);
    }
    *(float4*)(xzb + (size_t)bt * 1024 + 4 * m) = acc;
}

// ---------------------------------------------------------------------------
// FUSED: conv1d+silu -> x_proj -> dt_proj(softplus). Grid 256, block 512.
// xs/xdbl staged in LDS; xs & xdbl & dt also written to global for ssm.
// x_proj uses ORIGINAL (48,512) weights: lane sums k = ln + 64e (bank-free).
// ---------------------------------------------------------------------------
__global__ __launch_bounds__(512) void convxd_kernel(
    const float* __restrict__ xzb, const float* __restrict__ c1w,
    const float* __restrict__ c1b, const float* __restrict__ xpw,
    const float* __restrict__ dtwT, const float* __restrict__ dt_b,
    float* __restrict__ xsb, float* __restrict__ xdb, float* __restrict__ dtbf)
{
    int bt = blockIdx.x;
    int b = bt >> 5, t = bt & 31;
    int tid = threadIdx.x;
    __shared__ float xs_lds[512];
    __shared__ float xd_lds[48];

    // phase 1: depthwise causal conv1d + silu
    {
        float acc = c1b[tid];
        #pragma unroll
        for (int k = 0; k < 4; ++k) {
            int ts = t - 3 + k;
            if (ts >= 0)
                acc = fmaf(c1w[tid * 4 + k], xzb[(size_t)(b * Tn + ts) * 1024 + tid], acc);
        }
        float v = acc / (1.f + expf(-acc));
        xs_lds[tid] = v;
        xsb[(size_t)bt * 512 + tid] = v;
    }
    __syncthreads();

    // phase 2: x_proj (48 outputs), one wave per 6 outputs
    {
        int wv = tid >> 6, ln = tid & 63;
        #pragma unroll
        for (int u = 0; u < 6; ++u) {
            int o = wv * 6 + u;
            const float* wrow = xpw + (size_t)o * 512;
            float acc = 0.f;
            #pragma unroll
            for (int e = 0; e < 8; ++e)
                acc = fmaf(wrow[ln + 64 * e], xs_lds[ln + 64 * e], acc);
            acc += __shfl_xor(acc, 32); acc += __shfl_xor(acc, 16);
            acc += __shfl_xor(acc, 8);  acc += __shfl_xor(acc, 4);
            acc += __shfl_xor(acc, 2);  acc += __shfl_xor(acc, 1);
            if (ln == 0) {
                xd_lds[o] = acc;
                xdb[(size_t)bt * 48 + o] = acc;
            }
        }
    }
    __syncthreads();

    // phase 3: dt_proj + softplus
    {
        float a = dt_b[tid];
        #pragma unroll
        for (int k = 0; k < 16; ++k) a = fmaf(xd_lds[k], dtwT[k * 512 + tid], a);
        a = (a > 20.f) ? a : log1pf(expf(a));
        dtbf[(size_t)bt * 512 + tid] = a;
    }
}

// ---------------------------------------------------------------------------
// Wave-parallel selective scan (verified round 3+).
// ---------------------------------------------------------------------------
__global__ __launch_bounds__(256) void ssm_kernel(
    const float* __restrict__ xdbl, const float* __restrict__ dtb,
    const float* __restrict__ xs, const float* __restrict__ xz,
    const float* __restrict__ A_log, const float* __restrict__ Dp,
    float* __restrict__ y)
{
    int tid = threadIdx.x;
    int lane = tid & 63;
    int s = lane & 15, dsub = lane >> 4;
    int gid = blockIdx.x * 4 + (tid >> 6);
    int b = gid >> 7;
    int d = ((gid & 127) << 2) + dsub;

    float A = -expf(A_log[d * 16 + s]);
    float Dv = Dp[d];
    float h = 0.f;
    for (int t = 0; t < Tn; ++t) {
        int bt = b * Tn + t;
        float dtv = dtb[(size_t)bt * 512 + d];
        float xv  = xs [(size_t)bt * 512 + d];
        float Bs  = xdbl[(size_t)bt * 48 + 16 + s];
        float Cs  = xdbl[(size_t)bt * 48 + 32 + s];
        float dA = expf(dtv * A);
        h = fmaf(dA, h, dtv * Bs * xv);
        float c = h * Cs;
        c += __shfl_xor(c, 8, 16);
        c += __shfl_xor(c, 4, 16);
        c += __shfl_xor(c, 2, 16);
        c += __shfl_xor(c, 1, 16);
        if (s == 0) {
            float zv = xz[(size_t)bt * 1024 + 512 + d];
            float sig = 1.f / (1.f + expf(-zv));
            y[(size_t)bt * 512 + d] = (c + Dv * xv) * (zv * sig);
        }
    }
}

// ---------------------------------------------------------------------------
// FUSED: out_proj -> h1(relu) -> h2(sigmoid) -> meas. Grid 256, block 256.
// ---------------------------------------------------------------------------
__global__ __launch_bounds__(256) void out_head_kernel(
    const float* __restrict__ yb, const float* __restrict__ opwT,
    const float* __restrict__ h1wT, const float* __restrict__ h1_b,
    const float* __restrict__ h2w, const float* __restrict__ h2_b,
    float* __restrict__ meas_out)
{
    int bt = blockIdx.x;
    int m  = threadIdx.x;
    __shared__ float y_lds[512];
    __shared__ float mo_lds[256];
    __shared__ float hid_lds[128];

    y_lds[m]       = yb[(size_t)bt * 512 + m];
    y_lds[m + 256] = yb[(size_t)bt * 512 + m + 256];
    __syncthreads();

    {   // out_proj (no bias)
        float a = 0.f;
        for (int k = 0; k < 512; ++k) a = fmaf(y_lds[k], opwT[k * 256 + m], a);
        mo_lds[m] = a;
    }
    __syncthreads();

    if (m < 128) {  // h1 + relu
        float a = h1_b[m];
        for (int k = 0; k < 256; ++k) a = fmaf(mo_lds[k], h1wT[k * 128 + m], a);
        hid_lds[m] = fmaxf(a, 0.f);
    }
    __syncthreads();

    if (m < 64) {   // h2 + sigmoid: 4 outputs x 16 lanes
        int o2 = m >> 4, l15 = m & 15;
        float acc = 0.f;
        #pragma unroll
        for (int e = 0; e < 8; ++e)
            acc = fmaf(h2w[o2 * 128 + l15 + 16 * e], hid_lds[l15 + 16 * e], acc);
        acc += __shfl_xor(acc, 8, 16);
        acc += __shfl_xor(acc, 4, 16);
        acc += __shfl_xor(acc, 2, 16);
        acc += __shfl_xor(acc, 1, 16);
        if (l15 == 0) {
            float a = acc + h2_b[o2];
            meas_out[bt * 4 + o2] = 1.f / (1.f + expf(-a));
        }
    }
}

// ---------------------------------------------------------------------------
// Wave-parallel Kalman filter: 16 lanes per batch, lane = (i,j) of 4x4.
// All matrix algebra via cross-lane shuffles. Grid 1, block 128 (8 batches).
// ---------------------------------------------------------------------------
__device__ __forceinline__ float kf_mm(float Av, float Bv, int i, int j, int gb) {
    float c = 0.f;
    #pragma unroll
    for (int k = 0; k < 4; ++k)
        c = fmaf(__shfl(Av, gb + i * 4 + k, 64), __shfl(Bv, gb + k * 4 + j, 64), c);
    return c;
}
__device__ __forceinline__ float kf_mmT(float Av, float Bv, int i, int j, int gb) {
    float c = 0.f;
    #pragma unroll
    for (int k = 0; k < 4; ++k)
        c = fmaf(__shfl(Av, gb + i * 4 + k, 64), __shfl(Bv, gb + j * 4 + k, 64), c);
    return c;
}

__global__ __launch_bounds__(128) void kf_kernel(
    const float* __restrict__ meas, const float* __restrict__ bb,
    const float* __restrict__ Fin, const float* __restrict__ Hmin,
    const float* __restrict__ lq, const float* __restrict__ lr,
    float* __restrict__ pred)
{
    int tid = threadIdx.x;
    int b   = tid >> 4;            // 0..7
    int l16 = tid & 15;
    int i = l16 >> 2, j = l16 & 3;
    int gb = tid & 48;             // 16-group base within wave

    float Fv = Fin[l16], Hv = Hmin[l16];
    float R4[4];
    #pragma unroll
    for (int k = 0; k < 4; ++k) R4[k] = expf(lr[k]) + 1e-6f;
    float qi = expf(lq[i]) + 1e-6f;

    float sv = bb[b * 128 + j];            // s[j] replicated across i
    float Pv = (i == j) ? 0.01f : 0.f;

    for (int t = 0; t < Tn; ++t) {
        float mv = meas[(b * Tn + t) * 4 + j];           // m[j]
        // sp[i] = sum_j F[i][j] s[j]
        float tr = Fv * sv;
        tr += __shfl_xor(tr, 1); tr += __shfl_xor(tr, 2);
        float spv = tr;                                   // sp[i] repl over j
        float spj = __shfl(spv, gb + j * 4, 64);          // sp[j]
        // Pp = F P F^T + Q
        float FPv = kf_mm(Fv, Pv, i, j, gb);
        float Ppv = kf_mmT(FPv, Fv, i, j, gb) + ((i == j) ? qi : 0.f);
        // yr[j] = m[j] - (H sp)[j]
        float hsp = Hv * spj;
        hsp += __shfl_xor(hsp, 1); hsp += __shfl_xor(hsp, 2);   // (H sp)[i]
        float yrv = mv - __shfl(hsp, gb + j * 4, 64);
        // S = H Pp H^T + R ; X = S^{-1} H (Gauss-Jordan, SPD no pivot)
        float HPv = kf_mm(Hv, Ppv, i, j, gb);
        float Sv = kf_mmT(HPv, Hv, i, j, gb) + ((i == j) ? R4[i] : 0.f);
        float Xv = Hv;
        #pragma unroll
        for (int c = 0; c < 4; ++c) {
            float piv = __shfl(Sv, gb + c * 5, 64);
            float dinv = 1.f / piv;
            if (i == c) { Sv *= dinv; Xv *= dinv; }
            float Scj = __shfl(Sv, gb + c * 4 + j, 64);
            float Xcj = __shfl(Xv, gb + c * 4 + j, 64);
            float f = __shfl(Sv, gb + i * 4 + c, 64);
            if (i != c) { Sv = fmaf(-f, Scj, Sv); Xv = fmaf(-f, Xcj, Xv); }
        }
        // K[i][j] = sum_k Pp[i][k] X[j][k]
        float Kv = kf_mmT(Ppv, Xv, i, j, gb);
        // sn[i] = sp[i] + sum_j K[i][j] yr[j]
        float t3 = Kv * yrv;
        t3 += __shfl_xor(t3, 1); t3 += __shfl_xor(t3, 2);
        float snv = spv + t3;
        if (j == 0) pred[(b * Tn + t) * 4 + i] = snv;
        // P = IKH Pp IKH^T + K R K^T
        float IKHv = ((i == j) ? 1.f : 0.f) - kf_mm(Kv, Hv, i, j, gb);
        float T1v = kf_mm(IKHv, Ppv, i, j, gb);
        float krk = 0.f;
        #pragma unroll
        for (int k = 0; k < 4; ++k)
            krk = fmaf(__shfl(Kv, gb + i * 4 + k, 64) * R4[k],
                       __shfl(Kv, gb + j * 4 + k, 64), krk);
        Pv = kf_mmT(T1v, IKHv, i, j, gb) + krk;
        sv = __shfl(snv, gb + j * 4, 64);                 // s[j] for next step
    }
}

// ---------------------------------------------------------------------------
extern "C" void kernel_launch(void* const* d_in, const int* in_sizes, int n_in,
                              void* d_out, int out_size, void* d_ws, size_t ws_size,
                              hipStream_t stream)
{
    const float* frames = (const float*)d_in[0];
    const float* bb     = (const float*)d_in[1];
    const float* cw0 = (const float*)d_in[2],  *cb0 = (const float*)d_in[3];
    const float* g0  = (const float*)d_in[4],  *be0 = (const float*)d_in[5];
    const float* cw1 = (const float*)d_in[6],  *cb1 = (const float*)d_in[7];
    const float* g1  = (const float*)d_in[8],  *be1 = (const float*)d_in[9];
    const float* cw2 = (const float*)d_in[10], *cb2 = (const float*)d_in[11];
    const float* g2  = (const float*)d_in[12], *be2 = (const float*)d_in[13];
    const float* ep_w  = (const float*)d_in[14], *ep_b  = (const float*)d_in[15];
    const float* bp1_w = (const float*)d_in[16], *bp1_b = (const float*)d_in[17];
    const float* bp2_w = (const float*)d_in[18], *bp2_b = (const float*)d_in[19];
    const float* in_proj_w = (const float*)d_in[20];
    const float* c1w = (const float*)d_in[21], *c1b = (const float*)d_in[22];
    const float* x_proj_w = (const float*)d_in[23];
    const float* dt_w = (const float*)d_in[24], *dt_b = (const float*)d_in[25];
    const float* A_log = (const float*)d_in[26], *Dp = (const float*)d_in[27];
    const float* out_proj_w = (const float*)d_in[28];
    const float* h1_w = (const float*)d_in[29], *h1_b = (const float*)d_in[30];
    const float* h2_w = (const float*)d_in[31], *h2_b = (const float*)d_in[32];
    const float* kfF = (const float*)d_in[33], *kfH = (const float*)d_in[34];
    const float* kfq = (const float*)d_in[35], *kfr = (const float*)d_in[36];

    // workspace layout
    float* ws   = (float*)d_ws;
    float* buf2 = ws;                        // (256,96,2,2)   98304
    float* xzb  = buf2 + 98304;              // (256,1024)    262144
    float* xsb  = xzb  + 262144;             // (256,512)     131072
    float* xdb  = xsb  + 131072;             // (256,48)       12288
    float* dtbf = xdb  + 12288;              // (256,512)     131072
    float* yb   = dtbf + 131072;             // (256,512)     131072
    float* tW   = yb   + 131072;             // transposed weights 500480
    unsigned short* buf0b = (unsigned short*)(tW + 500480);  // bf16 (256,32,32,32)
    unsigned short* buf1b = buf0b + 8388608;                 // bf16 (256,8,8,64)
    unsigned short* w2b   = buf1b + 131072;
    unsigned short* w1b   = w2b + 165888;
    unsigned short* w0b   = w1b + 55296;

    float* ipwT = tW;
    float* dtwT = tW + 286720;
    float* opwT = tW + 294912;
    float* h1wT = tW + 425984;
    float* epwT = tW + 459264;
    float* bp2T = tW + 483840;
    float* bp1T = tW + 500224;

    float* kf_out   = (float*)d_out;          // (8,32,4)
    float* meas_out = kf_out + Bn * Tn * 4;   // (8,32,4)

    auto nblk = [](int n) { return dim3((unsigned)((n + 255) / 256)); };

    prep_all<<<nblk(730880), 256, 0, stream>>>(cw0, cw1, cw2,
                                               in_proj_w, x_proj_w, dt_w, out_proj_w,
                                               h1_w, h2_w, ep_w, bp2_w, bp1_w,
                                               w0b, w1b, w2b, tW);

    conv0_kernel<<<dim3(4096), 512, 0, stream>>>(frames, w0b, cb0, g0, be0, buf0b);
    conv1_kernel<<<dim3(512), 512, 0, stream>>>(buf0b, w1b, cb1, g1, be1, buf1b);
    conv2_kernel<<<dim3(256), 384, 0, stream>>>(buf1b, w2b, cb2, g2, be2, buf2);

    fuse_u_inproj<<<dim3(256), 256, 0, stream>>>(buf2, epwT, ep_b, bb, bp1T, bp1_b,
                                                 bp2T, bp2_b, ipwT, xzb);
    convxd_kernel<<<dim3(256), 512, 0, stream>>>(xzb, c1w, c1b, x_proj_w,
                                                 dtwT, dt_b, xsb, xdb, dtbf);
    ssm_kernel<<<dim3(256), 256, 0, stream>>>(xdb, dtbf, xsb, xzb, A_log, Dp, yb);
    out_head_kernel<<<dim3(256), 256, 0, stream>>>(yb, opwT, h1wT, h1_b,
                                                   h2_w, h2_b, meas_out);
    kf_kernel<<<dim3(1), 128, 0, stream>>>(meas_out, bb, kfF, kfH, kfq, kfr, kf_out);
}